// Round 3
// baseline (14243.616 us; speedup 1.0000x reference)
//
#include <hip/hip_runtime.h>
#include <math.h>

#define BB 16
#define DD 512
#define HHN 8
#define EEN 64
#define LEN_E 720
#define LEN_D 1080
#define NV 321
#define DFF2 2048

// ---------------- prep kernels ----------------
__global__ void k_extract_x(const float* __restrict__ hist, float* __restrict__ xe) {
  int idx = blockIdx.x * 256 + threadIdx.x;
  if (idx >= BB*LEN_E*NV) return;
  xe[idx] = hist[(size_t)idx * 5];
}

__global__ void k_marks_enc(const float* __restrict__ hist, float* __restrict__ xme) {
  int idx = blockIdx.x * 256 + threadIdx.x;
  if (idx >= BB*LEN_E*4) return;
  int f = idx & 3;
  int r = idx >> 2;              // b*720 + l
  xme[idx] = hist[((size_t)r * NV) * 5 + 1 + f];
}

__global__ void k_marks_dec(const float* __restrict__ fut, const float* __restrict__ xme,
                            float* __restrict__ xmd) {
  int idx = blockIdx.x * 256 + threadIdx.x;
  if (idx >= BB*LEN_D*4) return;
  int f = idx & 3;
  int r = idx >> 2;              // b*1080 + t
  int t = r % LEN_D, b = r / LEN_D;
  float v;
  if (t < 360) v = xme[((b*LEN_E) + 360 + t)*4 + f];
  else v = fut[(((size_t)(b*LEN_E + (t-360))) * NV) * 5 + 1 + f];
  xmd[idx] = v;
}

__global__ void k_mean_series(const float* __restrict__ xe, float* __restrict__ mb) {
  int idx = blockIdx.x * 256 + threadIdx.x;
  if (idx >= BB*NV) return;
  int b = idx / NV, n = idx % NV;
  float s = 0.f;
  for (int l = 0; l < LEN_E; ++l) s += xe[((size_t)b*LEN_E + l)*NV + n];
  mb[idx] = s * (1.f/(float)LEN_E);
}

__global__ void k_init_decomp(const float* __restrict__ xe, const float* __restrict__ mb,
                              float* __restrict__ seas, float* __restrict__ trend) {
  int idx = blockIdx.x * 256 + threadIdx.x;
  if (idx >= BB*LEN_D*NV) return;
  int n = idx % NV; int r = idx / NV; int t = r % LEN_D; int b = r / LEN_D;
  if (t < 360) {
    int l = 360 + t;
    float s = 0.f;
    for (int j = -12; j <= 12; ++j) {
      int lc = l + j; if (lc > LEN_E-1) lc = LEN_E-1; if (lc < 0) lc = 0;
      s += xe[((size_t)b*LEN_E + lc)*NV + n];
    }
    float ma = s * (1.f/25.f);
    trend[idx] = ma;
    seas[idx]  = xe[((size_t)b*LEN_E + l)*NV + n] - ma;
  } else {
    trend[idx] = mb[b*NV + n];
    seas[idx]  = 0.f;
  }
}

__global__ void k_zero(float* __restrict__ p, int n) {
  int i = blockIdx.x*256 + threadIdx.x;
  if (i < n) p[i] = 0.f;
}

// ---------------- weight/DFT builders ----------------
__global__ void k_build_wconv(const float* __restrict__ Wv, float* __restrict__ Wc) {
  int idx = blockIdx.x*256 + threadIdx.x;
  if (idx >= DD*963) return;
  int d = idx / 963, k = idx % 963;
  int c = k / NV, n = k % NV;
  Wc[idx] = Wv[(size_t)d*963 + n*3 + c];
}

__global__ void k_build_wtrc(const float* __restrict__ Wtr, float* __restrict__ Wc) {
  int idx = blockIdx.x*256 + threadIdx.x;
  if (idx >= NV*1536) return;
  int n = idx / 1536, k = idx % 1536;
  int c = k / DD, d = k % DD;
  Wc[idx] = Wtr[(size_t)n*1536 + d*3 + c];
}

__global__ void k_build_dft(float* __restrict__ Wd, int L) {
  int idx = blockIdx.x*256 + threadIdx.x;
  if (idx >= 128*L) return;
  int mr = idx / L, l = idx % L;
  int m = mr & 63;
  int ph = (m * l) % L;                       // exact integer phase reduction
  float th = 6.2831853071795864f * ((float)ph / (float)L);
  Wd[idx] = (mr < 64) ? cosf(th) : -sinf(th);
}

__global__ void k_build_ir(float* __restrict__ Wi, int L) {
  int idx = blockIdx.x*256 + threadIdx.x;
  if (idx >= 128*L) return;
  int l = idx / 128, k = idx % 128;
  int m = k & 63;
  int ph = (m * l) % L;
  float th = 6.2831853071795864f * ((float)ph / (float)L);
  float v;
  if (k < 64) v = (m == 0) ? (1.f/(float)L) : (2.f/(float)L) * cosf(th);
  else        v = (m == 0) ? 0.f            : -(2.f/(float)L) * sinf(th);
  Wi[idx] = v;
}

// ---------------- GEMM ----------------
// C[M,Nc] = A[M,K] @ W^T   (W row-major (Nc, K))
// AMODE: 0 = row-major A (lda=K)
//        1 = circular conv3 gather from (B,Lc,Din), K = 3*Din
//        2 = transposed view: A is (B,Lc,512) row-major, logical row r=(b*512+ch),
//            logical col k=l  ->  A[(b*Lc+k)*512 + ch]
// EPI bits: 1 = +bias[c], 4 = gelu(exact), 2 = +res[r,c]
template<int AMODE, int EPI>
__global__ __launch_bounds__(256)
void k_gemm(const float* __restrict__ A, const float* __restrict__ W,
            const float* __restrict__ bias, const float* __restrict__ res,
            float* __restrict__ C, int M, int Nc, int K, int Lc, int Din)
{
  __shared__ float As[16][65];
  __shared__ float Bs[16][65];
  int tid = threadIdx.x;
  int tx = tid & 15, ty = tid >> 4;
  int row0 = blockIdx.y * 64;
  int col0 = blockIdx.x * 64;
  float acc[4][4] = {};
  for (int k0 = 0; k0 < K; k0 += 16) {
    #pragma unroll
    for (int i = 0; i < 4; ++i) {
      int m = ty + i*16;
      int r = row0 + m;
      int k = k0 + tx;
      float v = 0.f;
      if (r < M && k < K) {
        if (AMODE == 0) v = A[(size_t)r * K + k];
        else if (AMODE == 1) {
          int b = r / Lc, t = r - b * Lc;
          int c = k / Din, n = k - c * Din;
          int tt = t + c - 1;
          if (tt < 0) tt = Lc - 1; else if (tt >= Lc) tt = 0;
          v = A[((size_t)(b * Lc + tt)) * Din + n];
        } else {
          int b = r >> 9, ch = r & 511;
          v = A[((size_t)(b * Lc + k)) * DD + ch];
        }
      }
      As[tx][m] = v;
      int nn = ty + i*16;
      int cc = col0 + nn;
      float w = 0.f;
      if (cc < Nc && k < K) w = W[(size_t)cc * K + k];
      Bs[tx][nn] = w;
    }
    __syncthreads();
    #pragma unroll
    for (int kk = 0; kk < 16; ++kk) {
      float av[4], bv[4];
      #pragma unroll
      for (int i = 0; i < 4; ++i) av[i] = As[kk][ty*4+i];
      #pragma unroll
      for (int j = 0; j < 4; ++j) bv[j] = Bs[kk][tx*4+j];
      #pragma unroll
      for (int i = 0; i < 4; ++i)
        #pragma unroll
        for (int j = 0; j < 4; ++j)
          acc[i][j] += av[i]*bv[j];
    }
    __syncthreads();
  }
  #pragma unroll
  for (int i = 0; i < 4; ++i) {
    int r = row0 + ty*4 + i;
    if (r >= M) continue;
    #pragma unroll
    for (int j = 0; j < 4; ++j) {
      int c = col0 + tx*4 + j;
      if (c >= Nc) continue;
      float v = acc[i][j];
      if (EPI & 1) v += bias[c];
      if (EPI & 4) v = 0.5f * v * (1.f + erff(v * 0.7071067811865476f));
      if (EPI & 2) v += res[(size_t)r * Nc + c];
      C[(size_t)r * Nc + c] = v;
    }
  }
}

// ---------------- mode mix: sel[b,h,o,m] = sum_e ft[b,h,e,m] * (fr+i fi)[h,e,o,m] ----------------
__global__ __launch_bounds__(256)
void k_modemix(const float* __restrict__ ftbuf, const float* __restrict__ fr,
               const float* __restrict__ fi, float* __restrict__ sel, float scale)
{
  int m = blockIdx.x, h = blockIdx.y;
  __shared__ float wr[64][64], wi[64][64];
  __shared__ float qr[BB][64], qi[BB][64];
  int tid = threadIdx.x;
  for (int it = 0; it < 16; ++it) {
    int idx = tid + it*256;
    int e = idx >> 6, o = idx & 63;
    size_t wof = ((((size_t)h*64 + e)*64 + o) << 6) + m;
    wr[e][o] = fr[wof]; wi[e][o] = fi[wof];
  }
  for (int it = 0; it < 4; ++it) {
    int idx = tid + it*256;
    int bb = idx >> 6, e = idx & 63;
    size_t qof = ((size_t)bb*DD + h*64 + e)*128 + m;
    qr[bb][e] = ftbuf[qof]; qi[bb][e] = ftbuf[qof + 64];
  }
  __syncthreads();
  for (int it = 0; it < 4; ++it) {
    int idx = tid + it*256;
    int bb = idx >> 6, o = idx & 63;
    float ar = 0.f, ai = 0.f;
    for (int e = 0; e < 64; ++e) {
      float xr = qr[bb][e], xi = qi[bb][e], yr = wr[e][o], yi = wi[e][o];
      ar += xr*yr - xi*yi;
      ai += xr*yi + xi*yr;
    }
    size_t sof = ((size_t)bb*DD + h*64 + o)*128 + m;
    sel[sof] = ar*scale; sel[sof + 64] = ai*scale;
  }
}

// ---------------- cross: a[b,h,x,y] = tanh_c( sum_e qf[e,x]*kf[e,y] ) ----------------
__global__ __launch_bounds__(256)
void k_cross_qk(const float* __restrict__ qf, const float* __restrict__ kf,
                float* __restrict__ ab)
{
  int bh = blockIdx.x; int b = bh >> 3, h = bh & 7;
  __shared__ float qr[32][64], qi[32][64], kr[32][64], ki[32][64];
  int tid = threadIdx.x;
  int tx = tid & 15, ty = tid >> 4;
  float ar[4][4] = {}, ai[4][4] = {};
  for (int e0 = 0; e0 < 64; e0 += 32) {
    for (int it = 0; it < 8; ++it) {
      int idx = tid + it*256;
      int e = idx >> 6, x = idx & 63;
      size_t rof = ((size_t)b*DD + h*64 + e0 + e)*128;
      qr[e][x] = qf[rof + x]; qi[e][x] = qf[rof + 64 + x];
      kr[e][x] = kf[rof + x]; ki[e][x] = kf[rof + 64 + x];
    }
    __syncthreads();
    for (int e = 0; e < 32; ++e) {
      float xr[4], xi2[4], yr[4], yi[4];
      #pragma unroll
      for (int i = 0; i < 4; ++i) { xr[i] = qr[e][ty*4+i]; xi2[i] = qi[e][ty*4+i]; }
      #pragma unroll
      for (int j = 0; j < 4; ++j) { yr[j] = kr[e][tx*4+j]; yi[j] = ki[e][tx*4+j]; }
      #pragma unroll
      for (int i = 0; i < 4; ++i)
        #pragma unroll
        for (int j = 0; j < 4; ++j) {
          ar[i][j] += xr[i]*yr[j] - xi2[i]*yi[j];
          ai[i][j] += xr[i]*yi[j] + xi2[i]*yr[j];
        }
    }
    __syncthreads();
  }
  #pragma unroll
  for (int i = 0; i < 4; ++i)
    #pragma unroll
    for (int j = 0; j < 4; ++j) {
      // tanh(x+iy) = (tx(1+T^2) + i T(1-tx^2)) / (1 + tx^2 T^2),  T = tan(y)
      float txv = tanhf(ar[i][j]);
      float tyv = tanf(ai[i][j]);
      float den = 1.f + txv*txv*tyv*tyv;
      float re = txv*(1.f + tyv*tyv) / den;
      float im = tyv*(1.f - txv*txv) / den;
      size_t of = ((size_t)bh*64 + (ty*4+i))*128 + tx*4 + j;
      ab[of] = re; ab[of + 64] = im;
    }
}

// v[b,h,e,x] = sum_y a[b,h,x,y] * kf[b,h,e,y]
__global__ __launch_bounds__(256)
void k_cross_v(const float* __restrict__ ab, const float* __restrict__ kf,
               float* __restrict__ v)
{
  int bh = blockIdx.x; int b = bh >> 3, h = bh & 7;
  __shared__ float ar[64][32], ai[64][32], kr[64][32], ki[64][32];
  int tid = threadIdx.x;
  int tx = tid & 15, ty = tid >> 4;
  float vr[4][4] = {}, vi[4][4] = {};
  for (int y0 = 0; y0 < 64; y0 += 32) {
    for (int it = 0; it < 8; ++it) {
      int idx = tid + it*256;
      int r = idx >> 5, y = idx & 31;
      ar[r][y] = ab[((size_t)bh*64 + r)*128 + y0 + y];
      ai[r][y] = ab[((size_t)bh*64 + r)*128 + 64 + y0 + y];
      kr[r][y] = kf[((size_t)b*DD + h*64 + r)*128 + y0 + y];
      ki[r][y] = kf[((size_t)b*DD + h*64 + r)*128 + 64 + y0 + y];
    }
    __syncthreads();
    for (int y = 0; y < 32; ++y) {
      float er[4], ei[4], xr[4], xi2[4];
      #pragma unroll
      for (int i = 0; i < 4; ++i) { er[i] = kr[ty*4+i][y]; ei[i] = ki[ty*4+i][y]; }
      #pragma unroll
      for (int j = 0; j < 4; ++j) { xr[j] = ar[tx*4+j][y]; xi2[j] = ai[tx*4+j][y]; }
      #pragma unroll
      for (int i = 0; i < 4; ++i)
        #pragma unroll
        for (int j = 0; j < 4; ++j) {
          vr[i][j] += xr[j]*er[i] - xi2[j]*ei[i];
          vi[i][j] += xr[j]*ei[i] + xi2[j]*er[i];
        }
    }
    __syncthreads();
  }
  #pragma unroll
  for (int i = 0; i < 4; ++i)
    #pragma unroll
    for (int j = 0; j < 4; ++j) {
      size_t of = ((size_t)b*DD + h*64 + ty*4 + i)*128 + tx*4 + j;
      v[of] = vr[i][j]; v[of + 64] = vi[i][j];
    }
}

// ---------------- LN + column-mean subtract (myln) ----------------
__global__ __launch_bounds__(256)
void k_ln(const float* __restrict__ x, const float* __restrict__ g,
          const float* __restrict__ be, float* __restrict__ out)
{
  int r = blockIdx.x; int tid = threadIdx.x;
  float v1 = x[(size_t)r*DD + tid], v2 = x[(size_t)r*DD + 256 + tid];
  float s = v1 + v2, s2 = v1*v1 + v2*v2;
  #pragma unroll
  for (int off = 32; off; off >>= 1) { s += __shfl_down(s, off, 64); s2 += __shfl_down(s2, off, 64); }
  __shared__ float red[8];
  int wid = tid >> 6, lane = tid & 63;
  if (lane == 0) { red[wid] = s; red[4 + wid] = s2; }
  __syncthreads();
  if (tid == 0) {
    float a = red[0]+red[1]+red[2]+red[3];
    float b2 = red[4]+red[5]+red[6]+red[7];
    float mu = a / 512.f;
    float var = b2 / 512.f - mu*mu;
    red[0] = mu; red[1] = rsqrtf(var + 1e-5f);
  }
  __syncthreads();
  float mu = red[0], inv = red[1];
  out[(size_t)r*DD + tid]       = (v1 - mu)*inv*g[tid]       + be[tid];
  out[(size_t)r*DD + 256 + tid] = (v2 - mu)*inv*g[256 + tid] + be[256 + tid];
}

__global__ void k_colmean_sub(float* __restrict__ x, int L) {
  int b = blockIdx.x;
  int d = blockIdx.y*256 + threadIdx.x;
  float s = 0.f;
  for (int l = 0; l < L; ++l) s += x[((size_t)b*L + l)*DD + d];
  float mu = s / (float)L;
  for (int l = 0; l < L; ++l) x[((size_t)b*L + l)*DD + d] -= mu;
}

// ---------------- series decomp (window 25, edge-clamped) ----------------
template<int ACC>
__global__ void k_decomp(const float* __restrict__ x, float* __restrict__ out,
                         float* __restrict__ tsum, int L)
{
  size_t idx = (size_t)blockIdx.x * 256 + threadIdx.x;
  size_t total = (size_t)BB * L * DD;
  if (idx >= total) return;
  int d = idx & 511;
  size_t rl = idx >> 9;
  int l = (int)(rl % L); int b = (int)(rl / L);
  float s = 0.f;
  for (int j = -12; j <= 12; ++j) {
    int lc = l + j; lc = lc < 0 ? 0 : (lc >= L ? L-1 : lc);
    s += x[(((size_t)b*L + lc) << 9) + d];
  }
  float ma = s * (1.f/25.f);
  out[idx] = x[idx] - ma;
  if (ACC) tsum[idx] += ma;
}

// ---------------- final ----------------
__global__ void k_final(const float* __restrict__ trend, const float* __restrict__ seas,
                        float* __restrict__ out) {
  int idx = blockIdx.x*256 + threadIdx.x;
  if (idx >= BB*LEN_E*NV) return;
  int n = idx % NV; int r = idx / NV; int t = r % LEN_E; int b = r / LEN_E;
  size_t src = ((size_t)b*LEN_D + 360 + t)*NV + n;
  out[idx] = trend[src] + seas[src];
}

// =====================================================================
extern "C" void kernel_launch(void* const* d_in, const int* in_sizes, int n_in,
                              void* d_out, int out_size, void* d_ws, size_t ws_size,
                              hipStream_t stream)
{
  (void)in_sizes; (void)n_in; (void)out_size; (void)ws_size;
  const float* history = (const float*)d_in[0];
  const float* future  = (const float*)d_in[1];
  const float* Wv_enc  = (const float*)d_in[2];
  const float* Wt_enc  = (const float*)d_in[3];
  const float* Wv_dec  = (const float*)d_in[4];
  const float* Wt_dec  = (const float*)d_in[5];
  const float* eWq = (const float*)d_in[6];
  const float* ebq = (const float*)d_in[7];
  const float* efr = (const float*)d_in[8];
  const float* efi = (const float*)d_in[9];
  const float* eWo = (const float*)d_in[10];
  const float* ebo = (const float*)d_in[11];
  const float* eW1 = (const float*)d_in[12];
  const float* eW2 = (const float*)d_in[13];
  const float* g_enc = (const float*)d_in[14];
  const float* b_enc = (const float*)d_in[15];
  const float* dWq = (const float*)d_in[16];
  const float* dbq = (const float*)d_in[17];
  const float* dfr = (const float*)d_in[18];
  const float* dfi = (const float*)d_in[19];
  const float* dWo = (const float*)d_in[20];
  const float* dbo = (const float*)d_in[21];
  const float* cWq = (const float*)d_in[22];
  const float* cbq = (const float*)d_in[23];
  const float* cWk = (const float*)d_in[24];
  const float* cbk = (const float*)d_in[25];
  const float* cfr = (const float*)d_in[26];
  const float* cfi = (const float*)d_in[27];
  const float* cWo = (const float*)d_in[28];
  const float* cbo = (const float*)d_in[29];
  const float* dW1 = (const float*)d_in[30];
  const float* dW2 = (const float*)d_in[31];
  const float* Wtr = (const float*)d_in[32];
  const float* g_dec = (const float*)d_in[33];
  const float* b_dec = (const float*)d_in[34];
  const float* Wp  = (const float*)d_in[35];
  const float* bp  = (const float*)d_in[36];

  float* ws = (float*)d_ws;
  size_t off = 0;
  auto alloc = [&](size_t n) { float* p = ws + off; off += (n + 63) & ~(size_t)63; return p; };

  // ---- workspace plan (~199 MB total) ----
  float* btrend = alloc((size_t)BB*LEN_D*NV);        // persist
  float* bTsum  = alloc((size_t)BB*LEN_D*DD);        // persist (zeroed per call)
  float* bX     = alloc((size_t)BB*LEN_D*DD);        // working
  float* bT     = alloc((size_t)BB*LEN_D*DD);        // working
  float* bencout= alloc((size_t)BB*LEN_E*DD);
  float* bseas  = alloc((size_t)BB*LEN_D*NV);        // aliased by bseasF
  float* bseasF = bseas;
  float* uni    = alloc((size_t)4*1048576);          // union region
  float* bxe = uni;                                  // prep only
  float* bH  = uni;                                  // FFN hidden (CH=2048)
  float* bqf = uni;                                  // fourier/cross only
  float* bkf = uni + 1048576;
  float* bsel= uni + 2097152;
  float* ba  = uni + 3145728;
  float* bv  = bqf;                                  // qf dead by the time v is written
  float* bWce   = alloc((size_t)DD*963);
  float* bWcd   = alloc((size_t)DD*963);
  float* bWtrc  = alloc((size_t)NV*1536);
  float* bD720  = alloc((size_t)128*LEN_E);
  float* bD1080 = alloc((size_t)128*LEN_D);
  float* bI720  = alloc((size_t)128*LEN_E);
  float* bI1080 = alloc((size_t)128*LEN_D);
  float* bxme   = alloc((size_t)BB*LEN_E*4);
  float* bxmd   = alloc((size_t)BB*LEN_D*4);
  float* bmean  = alloc((size_t)BB*NV);

  const int CH = 2048;  // FFN row chunk: CH*2048 floats fits the union

  auto gemm = [&](int amode, int epi, const float* A, const float* W, const float* bias,
                  const float* res, float* C, int M, int Nc, int K, int Lc = 0, int Din = 0) {
    dim3 grid((Nc + 63)/64, (M + 63)/64), blk(256);
    if (amode == 0) {
      switch (epi) {
        case 0: k_gemm<0,0><<<grid,blk,0,stream>>>(A,W,bias,res,C,M,Nc,K,Lc,Din); break;
        case 1: k_gemm<0,1><<<grid,blk,0,stream>>>(A,W,bias,res,C,M,Nc,K,Lc,Din); break;
        case 2: k_gemm<0,2><<<grid,blk,0,stream>>>(A,W,bias,res,C,M,Nc,K,Lc,Din); break;
        case 3: k_gemm<0,3><<<grid,blk,0,stream>>>(A,W,bias,res,C,M,Nc,K,Lc,Din); break;
        case 4: k_gemm<0,4><<<grid,blk,0,stream>>>(A,W,bias,res,C,M,Nc,K,Lc,Din); break;
      }
    } else if (amode == 1) {
      switch (epi) {
        case 0: k_gemm<1,0><<<grid,blk,0,stream>>>(A,W,bias,res,C,M,Nc,K,Lc,Din); break;
        case 2: k_gemm<1,2><<<grid,blk,0,stream>>>(A,W,bias,res,C,M,Nc,K,Lc,Din); break;
      }
    } else {
      k_gemm<2,0><<<grid,blk,0,stream>>>(A,W,bias,res,C,M,Nc,K,Lc,Din);
    }
  };

  auto decomp = [&](const float* in, float* out, int L, bool acc) {
    size_t tot = (size_t)BB * L * DD;
    int g = (int)((tot + 255)/256);
    if (acc) k_decomp<1><<<g,256,0,stream>>>(in, out, bTsum, L);
    else     k_decomp<0><<<g,256,0,stream>>>(in, out, nullptr, L);
  };

  // out = in + gelu(in@W1.T)@W2.T   (chunked so bH fits the union)
  auto ffn = [&](const float* in, float* out, const float* W1, const float* W2, int M) {
    for (int r0 = 0; r0 < M; r0 += CH) {
      int mc = M - r0; if (mc > CH) mc = CH;
      gemm(0, 4, in + (size_t)r0*DD, W1, nullptr, nullptr, bH, mc, DFF2, DD);
      gemm(0, 2, bH, W2, nullptr, in + (size_t)r0*DD, out + (size_t)r0*DD, mc, DD, DFF2);
    }
  };

  // X += fourier_self(X); uses T as scratch
  auto fourier_self = [&](float* X, float* T, int L,
                          const float* Wq, const float* bq, const float* fr, const float* fi,
                          const float* Wo, const float* bo, const float* dftW, const float* irW) {
    int M = BB * L;
    gemm(0, 1, X, Wq, bq, nullptr, T, M, DD, DD);                  // q projection
    gemm(2, 0, T, dftW, nullptr, nullptr, bqf, BB*DD, 128, L, L);  // rfft (transposed-A)
    k_modemix<<<dim3(64,8),256,0,stream>>>(bqf, fr, fi, bsel, 1.0f);
    gemm(0, 0, bsel, irW, nullptr, nullptr, T, BB*DD, L, 128);     // irfft -> (B,512,L) flat
    gemm(0, 3, T, Wo, bo, X, X, M, DD, DD);                        // X += out@Wo.T + bo
  };

  auto myln = [&](const float* in, float* out, const float* g, const float* b, int L) {
    k_ln<<<BB*L,256,0,stream>>>(in, g, b, out);
    k_colmean_sub<<<dim3(BB,2),256,0,stream>>>(out, L);
  };

  // ---------------- prep ----------------
  k_extract_x<<<(BB*LEN_E*NV + 255)/256,256,0,stream>>>(history, bxe);
  k_marks_enc<<<(BB*LEN_E*4 + 255)/256,256,0,stream>>>(history, bxme);
  k_marks_dec<<<(BB*LEN_D*4 + 255)/256,256,0,stream>>>(future, bxme, bxmd);
  k_mean_series<<<(BB*NV + 255)/256,256,0,stream>>>(bxe, bmean);
  k_init_decomp<<<(BB*LEN_D*NV + 255)/256,256,0,stream>>>(bxe, bmean, bseas, btrend);
  k_build_wconv<<<(DD*963 + 255)/256,256,0,stream>>>(Wv_enc, bWce);
  k_build_wconv<<<(DD*963 + 255)/256,256,0,stream>>>(Wv_dec, bWcd);
  k_build_wtrc<<<(NV*1536 + 255)/256,256,0,stream>>>(Wtr, bWtrc);
  k_build_dft<<<(128*LEN_E + 255)/256,256,0,stream>>>(bD720, LEN_E);
  k_build_dft<<<(128*LEN_D + 255)/256,256,0,stream>>>(bD1080, LEN_D);
  k_build_ir<<<(128*LEN_E + 255)/256,256,0,stream>>>(bI720, LEN_E);
  k_build_ir<<<(128*LEN_D + 255)/256,256,0,stream>>>(bI1080, LEN_D);

  // ---------------- encoder ----------------
  int ME = BB * LEN_E;
  gemm(1, 0, bxe, bWce, nullptr, nullptr, bX, ME, DD, 963, LEN_E, NV);   // conv embed (bxe dies here)
  gemm(0, 2, bxme, Wt_enc, nullptr, bX, bX, ME, DD, 4);                  // + marks

  float *X = bX, *T = bT;
  for (int i = 0; i < 2; ++i) {
    const float* Wq = eWq + (size_t)i*DD*DD;
    const float* bq = ebq + (size_t)i*DD;
    const float* fr = efr + (size_t)i*HHN*EEN*EEN*64;
    const float* fi = efi + (size_t)i*HHN*EEN*EEN*64;
    const float* Wo = eWo + (size_t)i*DD*DD;
    const float* bo = ebo + (size_t)i*DD;
    const float* W1 = eW1 + (size_t)i*DFF2*DD;
    const float* W2 = eW2 + (size_t)i*DD*DFF2;
    fourier_self(X, T, LEN_E, Wq, bq, fr, fi, Wo, bo, bD720, bI720);
    decomp(X, T, LEN_E, false);     // x -> T
    ffn(T, X, W1, W2, ME);          // X = x + FFN(x)
    decomp(X, T, LEN_E, false);     // x -> T
    { float* tmp = X; X = T; T = tmp; }   // X holds x
  }
  myln(X, bencout, g_enc, b_enc, LEN_E);

  // ---------------- decoder ----------------
  int MD = BB * LEN_D;
  gemm(1, 0, bseas, bWcd, nullptr, nullptr, X, MD, DD, 963, LEN_D, NV);  // bseas dies here
  gemm(0, 2, bxmd, Wt_dec, nullptr, X, X, MD, DD, 4);

  fourier_self(X, T, LEN_D, dWq, dbq, dfr, dfi, dWo, dbo, bD1080, bI1080);

  k_zero<<<(BB*LEN_D*DD + 255)/256,256,0,stream>>>(bTsum, BB*LEN_D*DD);
  decomp(X, T, LEN_D, true);        // x -> T, t1 accumulated

  // cross attention
  gemm(0, 1, bencout, cWk, cbk, nullptr, X, ME, DD, DD);                 // k proj (X free)
  gemm(2, 0, X, bD720, nullptr, nullptr, bkf, BB*DD, 128, LEN_E, LEN_E); // kf
  gemm(0, 1, T, cWq, cbq, nullptr, X, MD, DD, DD);                       // q proj of x
  gemm(2, 0, X, bD1080, nullptr, nullptr, bqf, BB*DD, 128, LEN_D, LEN_D);// qf
  k_cross_qk<<<BB*HHN,256,0,stream>>>(bqf, bkf, ba);
  k_cross_v<<<BB*HHN,256,0,stream>>>(ba, bkf, bv);                       // bv aliases bqf
  k_modemix<<<dim3(64,8),256,0,stream>>>(bv, cfr, cfi, bsel, 1.0f/262144.0f);
  gemm(0, 0, bsel, bI1080, nullptr, nullptr, X, BB*DD, LEN_D, 128);      // irfft -> X
  gemm(0, 3, X, cWo, cbo, T, T, MD, DD, DD);                             // T = x + cross

  decomp(T, X, LEN_D, true);        // x -> X, t2 accumulated
  ffn(X, T, dW1, dW2, MD);          // T = x + FFN(x)
  decomp(T, X, LEN_D, true);        // x -> X, t3 accumulated

  myln(X, T, g_dec, b_dec, LEN_D);
  gemm(0, 1, T, Wp, bp, nullptr, bseasF, MD, NV, DD);                         // seasonal
  gemm(1, 2, bTsum, bWtrc, nullptr, btrend, btrend, MD, NV, 1536, LEN_D, DD); // trend += conv

  k_final<<<(BB*LEN_E*NV + 255)/256,256,0,stream>>>(btrend, bseasF, (float*)d_out);
}

// Round 4
// 7586.173 us; speedup vs baseline: 1.8776x; 1.8776x over previous
//
#include <hip/hip_runtime.h>
#include <math.h>

#define BB 16
#define DD 512
#define HHN 8
#define EEN 64
#define LEN_E 720
#define LEN_D 1080
#define NV 321
#define DFF2 2048

typedef __attribute__((ext_vector_type(8))) short short8;
typedef __attribute__((ext_vector_type(4))) short short4v;
typedef __attribute__((ext_vector_type(4))) float floatx4;

__device__ __forceinline__ unsigned short f2bf(float v) {
  unsigned u = __builtin_bit_cast(unsigned, v);
  u += 0x7FFFu + ((u >> 16) & 1u);
  return (unsigned short)(u >> 16);
}
__device__ __forceinline__ float bf2f(unsigned short h) {
  unsigned u = ((unsigned)h) << 16;
  return __builtin_bit_cast(float, u);
}

// ---------------- prep kernels ----------------
__global__ void k_extract_x(const float* __restrict__ hist, float* __restrict__ xe) {
  int idx = blockIdx.x * 256 + threadIdx.x;
  if (idx >= BB*LEN_E*NV) return;
  xe[idx] = hist[(size_t)idx * 5];
}

__global__ void k_marks_enc(const float* __restrict__ hist, float* __restrict__ xme) {
  int idx = blockIdx.x * 256 + threadIdx.x;
  if (idx >= BB*LEN_E*4) return;
  int f = idx & 3;
  int r = idx >> 2;
  xme[idx] = hist[((size_t)r * NV) * 5 + 1 + f];
}

__global__ void k_marks_dec(const float* __restrict__ fut, const float* __restrict__ xme,
                            float* __restrict__ xmd) {
  int idx = blockIdx.x * 256 + threadIdx.x;
  if (idx >= BB*LEN_D*4) return;
  int f = idx & 3;
  int r = idx >> 2;
  int t = r % LEN_D, b = r / LEN_D;
  float v;
  if (t < 360) v = xme[((b*LEN_E) + 360 + t)*4 + f];
  else v = fut[(((size_t)(b*LEN_E + (t-360))) * NV) * 5 + 1 + f];
  xmd[idx] = v;
}

__global__ void k_mean_series(const float* __restrict__ xe, float* __restrict__ mb) {
  int idx = blockIdx.x * 256 + threadIdx.x;
  if (idx >= BB*NV) return;
  int b = idx / NV, n = idx % NV;
  float s = 0.f;
  for (int l = 0; l < LEN_E; ++l) s += xe[((size_t)b*LEN_E + l)*NV + n];
  mb[idx] = s * (1.f/(float)LEN_E);
}

__global__ void k_init_decomp(const float* __restrict__ xe, const float* __restrict__ mb,
                              float* __restrict__ seas, float* __restrict__ trend) {
  int idx = blockIdx.x * 256 + threadIdx.x;
  if (idx >= BB*LEN_D*NV) return;
  int n = idx % NV; int r = idx / NV; int t = r % LEN_D; int b = r / LEN_D;
  if (t < 360) {
    int l = 360 + t;
    float s = 0.f;
    for (int j = -12; j <= 12; ++j) {
      int lc = l + j; if (lc > LEN_E-1) lc = LEN_E-1; if (lc < 0) lc = 0;
      s += xe[((size_t)b*LEN_E + lc)*NV + n];
    }
    float ma = s * (1.f/25.f);
    trend[idx] = ma;
    seas[idx]  = xe[((size_t)b*LEN_E + l)*NV + n] - ma;
  } else {
    trend[idx] = mb[b*NV + n];
    seas[idx]  = 0.f;
  }
}

__global__ void k_zero(float* __restrict__ p, int n) {
  int i = blockIdx.x*256 + threadIdx.x;
  if (i < n) p[i] = 0.f;
}

// ---------------- weight/DFT builders ----------------
__global__ void k_build_wconv(const float* __restrict__ Wv, float* __restrict__ Wc) {
  int idx = blockIdx.x*256 + threadIdx.x;
  if (idx >= DD*963) return;
  int d = idx / 963, k = idx % 963;
  int c = k / NV, n = k % NV;
  Wc[idx] = Wv[(size_t)d*963 + n*3 + c];
}

__global__ void k_build_wtrc(const float* __restrict__ Wtr, float* __restrict__ Wc) {
  int idx = blockIdx.x*256 + threadIdx.x;
  if (idx >= NV*1536) return;
  int n = idx / 1536, k = idx % 1536;
  int c = k / DD, d = k % DD;
  Wc[idx] = Wtr[(size_t)n*1536 + d*3 + c];
}

__global__ void k_build_dft(float* __restrict__ Wd, int L) {
  int idx = blockIdx.x*256 + threadIdx.x;
  if (idx >= 128*L) return;
  int mr = idx / L, l = idx % L;
  int m = mr & 63;
  int ph = (m * l) % L;
  float th = 6.2831853071795864f * ((float)ph / (float)L);
  Wd[idx] = (mr < 64) ? cosf(th) : -sinf(th);
}

__global__ void k_build_ir(float* __restrict__ Wi, int L) {
  int idx = blockIdx.x*256 + threadIdx.x;
  if (idx >= 128*L) return;
  int l = idx / 128, k = idx % 128;
  int m = k & 63;
  int ph = (m * l) % L;
  float th = 6.2831853071795864f * ((float)ph / (float)L);
  float v;
  if (k < 64) v = (m == 0) ? (1.f/(float)L) : (2.f/(float)L) * cosf(th);
  else        v = (m == 0) ? 0.f            : -(2.f/(float)L) * sinf(th);
  Wi[idx] = v;
}

// ---------------- MFMA GEMM (fp32 in/out, bf16 hi/lo x3 internally) ----------------
// C[M,Nc] = A[M,K] @ W^T   (W row-major (Nc,K))
// AMODE: 0 plain row-major A; 1 circular conv3 gather from (B,Lc,Din) with K=3*Din;
//        2 transposed view of (B,Lc,512): row r=(b*512+ch), col k=l -> A[(b*Lc+k)*512+ch]
// EPI bits: 1 = +bias[c], 4 = gelu(exact), 2 = +res[r,c]
#define SP 40   // LDS row pitch in shorts (80B: 16B-aligned, 2-way bank alias = free)

template<int AMODE, int EPI>
__global__ __launch_bounds__(256)
void k_mgemm(const float* __restrict__ A, const float* __restrict__ W,
             const float* __restrict__ bias, const float* __restrict__ res,
             float* __restrict__ C, int M, int Nc, int K, int Lc, int Din)
{
  __shared__ short sAh[128][SP];
  __shared__ short sAl[128][SP];
  __shared__ short sBh[128][SP];
  __shared__ short sBl[128][SP];

  const int tid  = threadIdx.x;
  const int lane = tid & 63;
  const int wave = tid >> 6;          // 0..3
  const int wr   = wave >> 1;         // wave row (0..1)
  const int wc   = wave & 1;          // wave col (0..1)
  const int lr   = lane & 15;
  const int kg   = lane >> 4;         // 0..3

  const int row0 = blockIdx.y * 128;
  const int col0 = blockIdx.x * 128;

  // staging assignment: thread t covers tile-row (t>>1), k-halves (t&1)*16 + q*8
  const int srow  = tid >> 1;
  const int khalf = (tid & 1) * 16;
  const bool kvec = ((K & 3) == 0);

  const int ar = row0 + srow;   // global A row
  const int wrow = col0 + srow; // global W row (output col)

  // precompute AMODE indices for the A row
  int gb = 0, gt = 0;
  if (AMODE == 1) { gb = ar / Lc; gt = ar - gb * Lc; }
  int tb = 0, tch = 0;
  if (AMODE == 2) { tb = ar >> 9; tch = ar & 511; }

  floatx4 acc[4][4] = {};

  for (int k0 = 0; k0 < K; k0 += 32) {
    // ---- stage A and B (hi/lo split) ----
    #pragma unroll
    for (int q = 0; q < 2; ++q) {
      int kk = khalf + q*8;
      int kb = k0 + kk;
      float v[8];
      // A
      if (AMODE == 0) {
        if (ar < M && kvec && kb + 7 < K) {
          const float4 p0 = *(const float4*)(A + (size_t)ar*K + kb);
          const float4 p1 = *(const float4*)(A + (size_t)ar*K + kb + 4);
          v[0]=p0.x; v[1]=p0.y; v[2]=p0.z; v[3]=p0.w;
          v[4]=p1.x; v[5]=p1.y; v[6]=p1.z; v[7]=p1.w;
        } else {
          #pragma unroll
          for (int j = 0; j < 8; ++j)
            v[j] = (ar < M && kb + j < K) ? A[(size_t)ar*K + kb + j] : 0.f;
        }
      } else if (AMODE == 1) {
        #pragma unroll
        for (int j = 0; j < 8; ++j) {
          int k = kb + j;
          float x = 0.f;
          if (ar < M && k < K) {
            int c = k / Din, n = k - c * Din;
            int tt = gt + c - 1;
            if (tt < 0) tt = Lc - 1; else if (tt >= Lc) tt = 0;
            x = A[((size_t)(gb * Lc + tt)) * Din + n];
          }
          v[j] = x;
        }
      } else {
        #pragma unroll
        for (int j = 0; j < 8; ++j) {
          int k = kb + j;
          v[j] = (ar < M && k < K) ? A[((size_t)(tb * Lc + k)) * DD + tch] : 0.f;
        }
      }
      short8 h8, l8;
      #pragma unroll
      for (int j = 0; j < 8; ++j) {
        unsigned short h = f2bf(v[j]);
        h8[j] = (short)h;
        l8[j] = (short)f2bf(v[j] - bf2f(h));
      }
      *(short8*)&sAh[srow][kk] = h8;
      *(short8*)&sAl[srow][kk] = l8;

      // B (= W rows)
      if (wrow < Nc && kvec && kb + 7 < K) {
        const float4 p0 = *(const float4*)(W + (size_t)wrow*K + kb);
        const float4 p1 = *(const float4*)(W + (size_t)wrow*K + kb + 4);
        v[0]=p0.x; v[1]=p0.y; v[2]=p0.z; v[3]=p0.w;
        v[4]=p1.x; v[5]=p1.y; v[6]=p1.z; v[7]=p1.w;
      } else {
        #pragma unroll
        for (int j = 0; j < 8; ++j)
          v[j] = (wrow < Nc && kb + j < K) ? W[(size_t)wrow*K + kb + j] : 0.f;
      }
      #pragma unroll
      for (int j = 0; j < 8; ++j) {
        unsigned short h = f2bf(v[j]);
        h8[j] = (short)h;
        l8[j] = (short)f2bf(v[j] - bf2f(h));
      }
      *(short8*)&sBh[srow][kk] = h8;
      *(short8*)&sBl[srow][kk] = l8;
    }
    __syncthreads();

    // ---- fragments + MFMA ----
    short8 ah[4], al[4], bh[4], bl[4];
    #pragma unroll
    for (int f = 0; f < 4; ++f) {
      int ra = wr*64 + f*16 + lr;
      ah[f] = *(const short8*)&sAh[ra][kg*8];
      al[f] = *(const short8*)&sAl[ra][kg*8];
      int rb = wc*64 + f*16 + lr;
      bh[f] = *(const short8*)&sBh[rb][kg*8];
      bl[f] = *(const short8*)&sBl[rb][kg*8];
    }
    #pragma unroll
    for (int mf = 0; mf < 4; ++mf)
      #pragma unroll
      for (int nf = 0; nf < 4; ++nf) {
        acc[mf][nf] = __builtin_amdgcn_mfma_f32_16x16x32_bf16(ah[mf], bh[nf], acc[mf][nf], 0, 0, 0);
        acc[mf][nf] = __builtin_amdgcn_mfma_f32_16x16x32_bf16(ah[mf], bl[nf], acc[mf][nf], 0, 0, 0);
        acc[mf][nf] = __builtin_amdgcn_mfma_f32_16x16x32_bf16(al[mf], bh[nf], acc[mf][nf], 0, 0, 0);
      }
    __syncthreads();
  }

  // ---- epilogue: C/D layout col=lane&15, row=(lane>>4)*4+i ----
  #pragma unroll
  for (int nf = 0; nf < 4; ++nf) {
    int cN = col0 + wc*64 + nf*16 + lr;
    if (cN >= Nc) continue;
    #pragma unroll
    for (int mf = 0; mf < 4; ++mf) {
      #pragma unroll
      for (int i = 0; i < 4; ++i) {
        int rM = row0 + wr*64 + mf*16 + kg*4 + i;
        if (rM >= M) continue;
        float v = acc[mf][nf][i];
        if (EPI & 1) v += bias[cN];
        if (EPI & 4) v = 0.5f * v * (1.f + erff(v * 0.7071067811865476f));
        if (EPI & 2) v += res[(size_t)rM * Nc + cN];
        C[(size_t)rM * Nc + cN] = v;
      }
    }
  }
}

// ---------------- mode mix ----------------
__global__ __launch_bounds__(256)
void k_modemix(const float* __restrict__ ftbuf, const float* __restrict__ fr,
               const float* __restrict__ fi, float* __restrict__ sel, float scale)
{
  int m = blockIdx.x, h = blockIdx.y;
  __shared__ float wr[64][64], wi[64][64];
  __shared__ float qr[BB][64], qi[BB][64];
  int tid = threadIdx.x;
  for (int it = 0; it < 16; ++it) {
    int idx = tid + it*256;
    int e = idx >> 6, o = idx & 63;
    size_t wof = ((((size_t)h*64 + e)*64 + o) << 6) + m;
    wr[e][o] = fr[wof]; wi[e][o] = fi[wof];
  }
  for (int it = 0; it < 4; ++it) {
    int idx = tid + it*256;
    int bb = idx >> 6, e = idx & 63;
    size_t qof = ((size_t)bb*DD + h*64 + e)*128 + m;
    qr[bb][e] = ftbuf[qof]; qi[bb][e] = ftbuf[qof + 64];
  }
  __syncthreads();
  for (int it = 0; it < 4; ++it) {
    int idx = tid + it*256;
    int bb = idx >> 6, o = idx & 63;
    float ar = 0.f, ai = 0.f;
    for (int e = 0; e < 64; ++e) {
      float xr = qr[bb][e], xi = qi[bb][e], yr = wr[e][o], yi = wi[e][o];
      ar += xr*yr - xi*yi;
      ai += xr*yi + xi*yr;
    }
    size_t sof = ((size_t)bb*DD + h*64 + o)*128 + m;
    sel[sof] = ar*scale; sel[sof + 64] = ai*scale;
  }
}

// ---------------- cross attention ----------------
__global__ __launch_bounds__(256)
void k_cross_qk(const float* __restrict__ qf, const float* __restrict__ kf,
                float* __restrict__ ab)
{
  int bh = blockIdx.x; int b = bh >> 3, h = bh & 7;
  __shared__ float qr[32][64], qi[32][64], kr[32][64], ki[32][64];
  int tid = threadIdx.x;
  int tx = tid & 15, ty = tid >> 4;
  float ar[4][4] = {}, ai[4][4] = {};
  for (int e0 = 0; e0 < 64; e0 += 32) {
    for (int it = 0; it < 8; ++it) {
      int idx = tid + it*256;
      int e = idx >> 6, x = idx & 63;
      size_t rof = ((size_t)b*DD + h*64 + e0 + e)*128;
      qr[e][x] = qf[rof + x]; qi[e][x] = qf[rof + 64 + x];
      kr[e][x] = kf[rof + x]; ki[e][x] = kf[rof + 64 + x];
    }
    __syncthreads();
    for (int e = 0; e < 32; ++e) {
      float xr[4], xi2[4], yr[4], yi[4];
      #pragma unroll
      for (int i = 0; i < 4; ++i) { xr[i] = qr[e][ty*4+i]; xi2[i] = qi[e][ty*4+i]; }
      #pragma unroll
      for (int j = 0; j < 4; ++j) { yr[j] = kr[e][tx*4+j]; yi[j] = ki[e][tx*4+j]; }
      #pragma unroll
      for (int i = 0; i < 4; ++i)
        #pragma unroll
        for (int j = 0; j < 4; ++j) {
          ar[i][j] += xr[i]*yr[j] - xi2[i]*yi[j];
          ai[i][j] += xr[i]*yi[j] + xi2[i]*yr[j];
        }
    }
    __syncthreads();
  }
  #pragma unroll
  for (int i = 0; i < 4; ++i)
    #pragma unroll
    for (int j = 0; j < 4; ++j) {
      float txv = tanhf(ar[i][j]);
      float tyv = tanf(ai[i][j]);
      float den = 1.f + txv*txv*tyv*tyv;
      float re = txv*(1.f + tyv*tyv) / den;
      float im = tyv*(1.f - txv*txv) / den;
      size_t of = ((size_t)bh*64 + (ty*4+i))*128 + tx*4 + j;
      ab[of] = re; ab[of + 64] = im;
    }
}

__global__ __launch_bounds__(256)
void k_cross_v(const float* __restrict__ ab, const float* __restrict__ kf,
               float* __restrict__ v)
{
  int bh = blockIdx.x; int b = bh >> 3, h = bh & 7;
  __shared__ float ar[64][32], ai[64][32], kr[64][32], ki[64][32];
  int tid = threadIdx.x;
  int tx = tid & 15, ty = tid >> 4;
  float vr[4][4] = {}, vi[4][4] = {};
  for (int y0 = 0; y0 < 64; y0 += 32) {
    for (int it = 0; it < 8; ++it) {
      int idx = tid + it*256;
      int r = idx >> 5, y = idx & 31;
      ar[r][y] = ab[((size_t)bh*64 + r)*128 + y0 + y];
      ai[r][y] = ab[((size_t)bh*64 + r)*128 + 64 + y0 + y];
      kr[r][y] = kf[((size_t)b*DD + h*64 + r)*128 + y0 + y];
      ki[r][y] = kf[((size_t)b*DD + h*64 + r)*128 + 64 + y0 + y];
    }
    __syncthreads();
    for (int y = 0; y < 32; ++y) {
      float er[4], ei[4], xr[4], xi2[4];
      #pragma unroll
      for (int i = 0; i < 4; ++i) { er[i] = kr[ty*4+i][y]; ei[i] = ki[ty*4+i][y]; }
      #pragma unroll
      for (int j = 0; j < 4; ++j) { xr[j] = ar[tx*4+j][y]; xi2[j] = ai[tx*4+j][y]; }
      #pragma unroll
      for (int i = 0; i < 4; ++i)
        #pragma unroll
        for (int j = 0; j < 4; ++j) {
          vr[i][j] += xr[j]*er[i] - xi2[j]*ei[i];
          vi[i][j] += xr[j]*ei[i] + xi2[j]*er[i];
        }
    }
    __syncthreads();
  }
  #pragma unroll
  for (int i = 0; i < 4; ++i)
    #pragma unroll
    for (int j = 0; j < 4; ++j) {
      size_t of = ((size_t)b*DD + h*64 + ty*4 + i)*128 + tx*4 + j;
      v[of] = vr[i][j]; v[of + 64] = vi[i][j];
    }
}

// ---------------- LN + column-mean subtract ----------------
__global__ __launch_bounds__(256)
void k_ln(const float* __restrict__ x, const float* __restrict__ g,
          const float* __restrict__ be, float* __restrict__ out)
{
  int r = blockIdx.x; int tid = threadIdx.x;
  float v1 = x[(size_t)r*DD + tid], v2 = x[(size_t)r*DD + 256 + tid];
  float s = v1 + v2, s2 = v1*v1 + v2*v2;
  #pragma unroll
  for (int off = 32; off; off >>= 1) { s += __shfl_down(s, off, 64); s2 += __shfl_down(s2, off, 64); }
  __shared__ float red[8];
  int wid = tid >> 6, lane = tid & 63;
  if (lane == 0) { red[wid] = s; red[4 + wid] = s2; }
  __syncthreads();
  if (tid == 0) {
    float a = red[0]+red[1]+red[2]+red[3];
    float b2 = red[4]+red[5]+red[6]+red[7];
    float mu = a / 512.f;
    float var = b2 / 512.f - mu*mu;
    red[0] = mu; red[1] = rsqrtf(var + 1e-5f);
  }
  __syncthreads();
  float mu = red[0], inv = red[1];
  out[(size_t)r*DD + tid]       = (v1 - mu)*inv*g[tid]       + be[tid];
  out[(size_t)r*DD + 256 + tid] = (v2 - mu)*inv*g[256 + tid] + be[256 + tid];
}

__global__ void k_colmean_sub(float* __restrict__ x, int L) {
  int b = blockIdx.x;
  int d = blockIdx.y*256 + threadIdx.x;
  float s = 0.f;
  for (int l = 0; l < L; ++l) s += x[((size_t)b*L + l)*DD + d];
  float mu = s / (float)L;
  for (int l = 0; l < L; ++l) x[((size_t)b*L + l)*DD + d] -= mu;
}

// ---------------- series decomp (window 25, edge-clamped) ----------------
template<int ACC>
__global__ void k_decomp(const float* __restrict__ x, float* __restrict__ out,
                         float* __restrict__ tsum, int L)
{
  size_t idx = (size_t)blockIdx.x * 256 + threadIdx.x;
  size_t total = (size_t)BB * L * DD;
  if (idx >= total) return;
  int d = idx & 511;
  size_t rl = idx >> 9;
  int l = (int)(rl % L); int b = (int)(rl / L);
  float s = 0.f;
  for (int j = -12; j <= 12; ++j) {
    int lc = l + j; lc = lc < 0 ? 0 : (lc >= L ? L-1 : lc);
    s += x[(((size_t)b*L + lc) << 9) + d];
  }
  float ma = s * (1.f/25.f);
  out[idx] = x[idx] - ma;
  if (ACC) tsum[idx] += ma;
}

// ---------------- final ----------------
__global__ void k_final(const float* __restrict__ trend, const float* __restrict__ seas,
                        float* __restrict__ out) {
  int idx = blockIdx.x*256 + threadIdx.x;
  if (idx >= BB*LEN_E*NV) return;
  int n = idx % NV; int r = idx / NV; int t = r % LEN_E; int b = r / LEN_E;
  size_t src = ((size_t)b*LEN_D + 360 + t)*NV + n;
  out[idx] = trend[src] + seas[src];
}

// =====================================================================
extern "C" void kernel_launch(void* const* d_in, const int* in_sizes, int n_in,
                              void* d_out, int out_size, void* d_ws, size_t ws_size,
                              hipStream_t stream)
{
  (void)in_sizes; (void)n_in; (void)out_size; (void)ws_size;
  const float* history = (const float*)d_in[0];
  const float* future  = (const float*)d_in[1];
  const float* Wv_enc  = (const float*)d_in[2];
  const float* Wt_enc  = (const float*)d_in[3];
  const float* Wv_dec  = (const float*)d_in[4];
  const float* Wt_dec  = (const float*)d_in[5];
  const float* eWq = (const float*)d_in[6];
  const float* ebq = (const float*)d_in[7];
  const float* efr = (const float*)d_in[8];
  const float* efi = (const float*)d_in[9];
  const float* eWo = (const float*)d_in[10];
  const float* ebo = (const float*)d_in[11];
  const float* eW1 = (const float*)d_in[12];
  const float* eW2 = (const float*)d_in[13];
  const float* g_enc = (const float*)d_in[14];
  const float* b_enc = (const float*)d_in[15];
  const float* dWq = (const float*)d_in[16];
  const float* dbq = (const float*)d_in[17];
  const float* dfr = (const float*)d_in[18];
  const float* dfi = (const float*)d_in[19];
  const float* dWo = (const float*)d_in[20];
  const float* dbo = (const float*)d_in[21];
  const float* cWq = (const float*)d_in[22];
  const float* cbq = (const float*)d_in[23];
  const float* cWk = (const float*)d_in[24];
  const float* cbk = (const float*)d_in[25];
  const float* cfr = (const float*)d_in[26];
  const float* cfi = (const float*)d_in[27];
  const float* cWo = (const float*)d_in[28];
  const float* cbo = (const float*)d_in[29];
  const float* dW1 = (const float*)d_in[30];
  const float* dW2 = (const float*)d_in[31];
  const float* Wtr = (const float*)d_in[32];
  const float* g_dec = (const float*)d_in[33];
  const float* b_dec = (const float*)d_in[34];
  const float* Wp  = (const float*)d_in[35];
  const float* bp  = (const float*)d_in[36];

  float* ws = (float*)d_ws;
  size_t off = 0;
  auto alloc = [&](size_t n) { float* p = ws + off; off += (n + 63) & ~(size_t)63; return p; };

  // ---- workspace plan (~199 MB, same as round 3) ----
  float* btrend = alloc((size_t)BB*LEN_D*NV);
  float* bTsum  = alloc((size_t)BB*LEN_D*DD);
  float* bX     = alloc((size_t)BB*LEN_D*DD);
  float* bT     = alloc((size_t)BB*LEN_D*DD);
  float* bencout= alloc((size_t)BB*LEN_E*DD);
  float* bseas  = alloc((size_t)BB*LEN_D*NV);
  float* bseasF = bseas;
  float* uni    = alloc((size_t)4*1048576);
  float* bxe = uni;
  float* bH  = uni;
  float* bqf = uni;
  float* bkf = uni + 1048576;
  float* bsel= uni + 2097152;
  float* ba  = uni + 3145728;
  float* bv  = bqf;
  float* bWce   = alloc((size_t)DD*963);
  float* bWcd   = alloc((size_t)DD*963);
  float* bWtrc  = alloc((size_t)NV*1536);
  float* bD720  = alloc((size_t)128*LEN_E);
  float* bD1080 = alloc((size_t)128*LEN_D);
  float* bI720  = alloc((size_t)128*LEN_E);
  float* bI1080 = alloc((size_t)128*LEN_D);
  float* bxme   = alloc((size_t)BB*LEN_E*4);
  float* bxmd   = alloc((size_t)BB*LEN_D*4);
  float* bmean  = alloc((size_t)BB*NV);

  const int CH = 2048;

  auto gemm = [&](int amode, int epi, const float* A, const float* W, const float* bias,
                  const float* res, float* C, int M, int Nc, int K, int Lc = 0, int Din = 0) {
    dim3 grid((Nc + 127)/128, (M + 127)/128), blk(256);
    if (amode == 0) {
      switch (epi) {
        case 0: k_mgemm<0,0><<<grid,blk,0,stream>>>(A,W,bias,res,C,M,Nc,K,Lc,Din); break;
        case 1: k_mgemm<0,1><<<grid,blk,0,stream>>>(A,W,bias,res,C,M,Nc,K,Lc,Din); break;
        case 2: k_mgemm<0,2><<<grid,blk,0,stream>>>(A,W,bias,res,C,M,Nc,K,Lc,Din); break;
        case 3: k_mgemm<0,3><<<grid,blk,0,stream>>>(A,W,bias,res,C,M,Nc,K,Lc,Din); break;
        case 4: k_mgemm<0,4><<<grid,blk,0,stream>>>(A,W,bias,res,C,M,Nc,K,Lc,Din); break;
      }
    } else if (amode == 1) {
      switch (epi) {
        case 0: k_mgemm<1,0><<<grid,blk,0,stream>>>(A,W,bias,res,C,M,Nc,K,Lc,Din); break;
        case 2: k_mgemm<1,2><<<grid,blk,0,stream>>>(A,W,bias,res,C,M,Nc,K,Lc,Din); break;
      }
    } else {
      k_mgemm<2,0><<<grid,blk,0,stream>>>(A,W,bias,res,C,M,Nc,K,Lc,Din);
    }
  };

  auto decomp = [&](const float* in, float* out, int L, bool acc) {
    size_t tot = (size_t)BB * L * DD;
    int g = (int)((tot + 255)/256);
    if (acc) k_decomp<1><<<g,256,0,stream>>>(in, out, bTsum, L);
    else     k_decomp<0><<<g,256,0,stream>>>(in, out, nullptr, L);
  };

  auto ffn = [&](const float* in, float* out, const float* W1, const float* W2, int M) {
    for (int r0 = 0; r0 < M; r0 += CH) {
      int mc = M - r0; if (mc > CH) mc = CH;
      gemm(0, 4, in + (size_t)r0*DD, W1, nullptr, nullptr, bH, mc, DFF2, DD);
      gemm(0, 2, bH, W2, nullptr, in + (size_t)r0*DD, out + (size_t)r0*DD, mc, DD, DFF2);
    }
  };

  auto fourier_self = [&](float* X, float* T, int L,
                          const float* Wq, const float* bq, const float* fr, const float* fi,
                          const float* Wo, const float* bo, const float* dftW, const float* irW) {
    int M = BB * L;
    gemm(0, 1, X, Wq, bq, nullptr, T, M, DD, DD);
    gemm(2, 0, T, dftW, nullptr, nullptr, bqf, BB*DD, 128, L, L);
    k_modemix<<<dim3(64,8),256,0,stream>>>(bqf, fr, fi, bsel, 1.0f);
    gemm(0, 0, bsel, irW, nullptr, nullptr, T, BB*DD, L, 128);
    gemm(0, 3, T, Wo, bo, X, X, M, DD, DD);
  };

  auto myln = [&](const float* in, float* out, const float* g, const float* b, int L) {
    k_ln<<<BB*L,256,0,stream>>>(in, g, b, out);
    k_colmean_sub<<<dim3(BB,2),256,0,stream>>>(out, L);
  };

  // ---------------- prep ----------------
  k_extract_x<<<(BB*LEN_E*NV + 255)/256,256,0,stream>>>(history, bxe);
  k_marks_enc<<<(BB*LEN_E*4 + 255)/256,256,0,stream>>>(history, bxme);
  k_marks_dec<<<(BB*LEN_D*4 + 255)/256,256,0,stream>>>(future, bxme, bxmd);
  k_mean_series<<<(BB*NV + 255)/256,256,0,stream>>>(bxe, bmean);
  k_init_decomp<<<(BB*LEN_D*NV + 255)/256,256,0,stream>>>(bxe, bmean, bseas, btrend);
  k_build_wconv<<<(DD*963 + 255)/256,256,0,stream>>>(Wv_enc, bWce);
  k_build_wconv<<<(DD*963 + 255)/256,256,0,stream>>>(Wv_dec, bWcd);
  k_build_wtrc<<<(NV*1536 + 255)/256,256,0,stream>>>(Wtr, bWtrc);
  k_build_dft<<<(128*LEN_E + 255)/256,256,0,stream>>>(bD720, LEN_E);
  k_build_dft<<<(128*LEN_D + 255)/256,256,0,stream>>>(bD1080, LEN_D);
  k_build_ir<<<(128*LEN_E + 255)/256,256,0,stream>>>(bI720, LEN_E);
  k_build_ir<<<(128*LEN_D + 255)/256,256,0,stream>>>(bI1080, LEN_D);

  // ---------------- encoder ----------------
  int ME = BB * LEN_E;
  gemm(1, 0, bxe, bWce, nullptr, nullptr, bX, ME, DD, 963, LEN_E, NV);
  gemm(0, 2, bxme, Wt_enc, nullptr, bX, bX, ME, DD, 4);

  float *X = bX, *T = bT;
  for (int i = 0; i < 2; ++i) {
    const float* Wq = eWq + (size_t)i*DD*DD;
    const float* bq = ebq + (size_t)i*DD;
    const float* fr = efr + (size_t)i*HHN*EEN*EEN*64;
    const float* fi = efi + (size_t)i*HHN*EEN*EEN*64;
    const float* Wo = eWo + (size_t)i*DD*DD;
    const float* bo = ebo + (size_t)i*DD;
    const float* W1 = eW1 + (size_t)i*DFF2*DD;
    const float* W2 = eW2 + (size_t)i*DD*DFF2;
    fourier_self(X, T, LEN_E, Wq, bq, fr, fi, Wo, bo, bD720, bI720);
    decomp(X, T, LEN_E, false);
    ffn(T, X, W1, W2, ME);
    decomp(X, T, LEN_E, false);
    { float* tmp = X; X = T; T = tmp; }
  }
  myln(X, bencout, g_enc, b_enc, LEN_E);

  // ---------------- decoder ----------------
  int MD = BB * LEN_D;
  gemm(1, 0, bseas, bWcd, nullptr, nullptr, X, MD, DD, 963, LEN_D, NV);
  gemm(0, 2, bxmd, Wt_dec, nullptr, X, X, MD, DD, 4);

  fourier_self(X, T, LEN_D, dWq, dbq, dfr, dfi, dWo, dbo, bD1080, bI1080);

  k_zero<<<(BB*LEN_D*DD + 255)/256,256,0,stream>>>(bTsum, BB*LEN_D*DD);
  decomp(X, T, LEN_D, true);

  // cross attention
  gemm(0, 1, bencout, cWk, cbk, nullptr, X, ME, DD, DD);
  gemm(2, 0, X, bD720, nullptr, nullptr, bkf, BB*DD, 128, LEN_E, LEN_E);
  gemm(0, 1, T, cWq, cbq, nullptr, X, MD, DD, DD);
  gemm(2, 0, X, bD1080, nullptr, nullptr, bqf, BB*DD, 128, LEN_D, LEN_D);
  k_cross_qk<<<BB*HHN,256,0,stream>>>(bqf, bkf, ba);
  k_cross_v<<<BB*HHN,256,0,stream>>>(ba, bkf, bv);
  k_modemix<<<dim3(64,8),256,0,stream>>>(bv, cfr, cfi, bsel, 1.0f/262144.0f);
  gemm(0, 0, bsel, bI1080, nullptr, nullptr, X, BB*DD, LEN_D, 128);
  gemm(0, 3, X, cWo, cbo, T, T, MD, DD, DD);

  decomp(T, X, LEN_D, true);
  ffn(X, T, dW1, dW2, MD);
  decomp(T, X, LEN_D, true);

  myln(X, T, g_dec, b_dec, LEN_D);
  gemm(0, 1, T, Wp, bp, nullptr, bseasF, MD, NV, DD);
  gemm(1, 2, bTsum, bWtrc, nullptr, btrend, btrend, MD, NV, 1536, LEN_D, DD);

  k_final<<<(BB*LEN_E*NV + 255)/256,256,0,stream>>>(btrend, bseasF, (float*)d_out);
}

// Round 5
// 4534.236 us; speedup vs baseline: 3.1413x; 1.6731x over previous
//
#include <hip/hip_runtime.h>
#include <math.h>

#define BB 16
#define DD 512
#define HHN 8
#define LEN_E 720
#define LEN_D 1080
#define NV 321
#define DFF2 2048

typedef __attribute__((ext_vector_type(8))) short short8;
typedef __attribute__((ext_vector_type(4))) float floatx4;
typedef unsigned short u16;

__device__ __forceinline__ u16 f2bf(float v) {
  unsigned u = __builtin_bit_cast(unsigned, v);
  u += 0x7FFFu + ((u >> 16) & 1u);
  return (u16)(u >> 16);
}
__device__ __forceinline__ float bf2f(u16 h) {
  unsigned u = ((unsigned)h) << 16;
  return __builtin_bit_cast(float, u);
}

// ---------------- prep kernels ----------------
__global__ void k_extract_x(const float* __restrict__ hist, float* __restrict__ xe) {
  int idx = blockIdx.x * 256 + threadIdx.x;
  if (idx >= BB*LEN_E*NV) return;
  xe[idx] = hist[(size_t)idx * 5];
}

__global__ void k_marks_enc(const float* __restrict__ hist, float* __restrict__ xme) {
  int idx = blockIdx.x * 256 + threadIdx.x;
  if (idx >= BB*LEN_E*4) return;
  int f = idx & 3;
  int r = idx >> 2;
  xme[idx] = hist[((size_t)r * NV) * 5 + 1 + f];
}

__global__ void k_marks_dec(const float* __restrict__ fut, const float* __restrict__ xme,
                            float* __restrict__ xmd) {
  int idx = blockIdx.x * 256 + threadIdx.x;
  if (idx >= BB*LEN_D*4) return;
  int f = idx & 3;
  int r = idx >> 2;
  int t = r % LEN_D, b = r / LEN_D;
  float v;
  if (t < 360) v = xme[((b*LEN_E) + 360 + t)*4 + f];
  else v = fut[(((size_t)(b*LEN_E + (t-360))) * NV) * 5 + 1 + f];
  xmd[idx] = v;
}

__global__ void k_mean_series(const float* __restrict__ xe, float* __restrict__ mb) {
  int idx = blockIdx.x * 256 + threadIdx.x;
  if (idx >= BB*NV) return;
  int b = idx / NV, n = idx % NV;
  float s = 0.f;
  for (int l = 0; l < LEN_E; ++l) s += xe[((size_t)b*LEN_E + l)*NV + n];
  mb[idx] = s * (1.f/(float)LEN_E);
}

__global__ void k_init_decomp(const float* __restrict__ xe, const float* __restrict__ mb,
                              float* __restrict__ seas, float* __restrict__ trend) {
  int idx = blockIdx.x * 256 + threadIdx.x;
  if (idx >= BB*LEN_D*NV) return;
  int n = idx % NV; int r = idx / NV; int t = r % LEN_D; int b = r / LEN_D;
  if (t < 360) {
    int l = 360 + t;
    float s = 0.f;
    for (int j = -12; j <= 12; ++j) {
      int lc = l + j; if (lc > LEN_E-1) lc = LEN_E-1; if (lc < 0) lc = 0;
      s += xe[((size_t)b*LEN_E + lc)*NV + n];
    }
    float ma = s * (1.f/25.f);
    trend[idx] = ma;
    seas[idx]  = xe[((size_t)b*LEN_E + l)*NV + n] - ma;
  } else {
    trend[idx] = mb[b*NV + n];
    seas[idx]  = 0.f;
  }
}

__global__ void k_zero(float* __restrict__ p, int n) {
  int i = blockIdx.x*256 + threadIdx.x;
  if (i < n) p[i] = 0.f;
}

// marks embedding: X[r][d] += sum_f xm[r][f]*Wt[d][f]   (K=4, pure vector)
__global__ void k_marks_add(float* __restrict__ X, const float* __restrict__ xm,
                            const float* __restrict__ Wt, int M) {
  int idx = blockIdx.x*256 + threadIdx.x;
  if (idx >= M*DD) return;
  int d = idx & 511, r = idx >> 9;
  const float* m4 = xm + (size_t)r*4;
  const float* w4 = Wt + (size_t)d*4;
  X[idx] += m4[0]*w4[0] + m4[1]*w4[1] + m4[2]*w4[2] + m4[3]*w4[3];
}

// ---------------- split builders (fp32 -> bf16 hi/lo, K padded) ----------------
__global__ void k_split_plain(const float* __restrict__ src, u16* __restrict__ h,
                              u16* __restrict__ l, int K, int Kp) {
  int col = blockIdx.x*256 + threadIdx.x;
  if (col >= Kp) return;
  int r = blockIdx.y;
  float v = (col < K) ? src[(size_t)r*K + col] : 0.f;
  u16 hh = f2bf(v);
  size_t o = (size_t)r*Kp + col;
  h[o] = hh; l[o] = f2bf(v - bf2f(hh));
}

// materialize circular conv3 gather: rows r0..r0+Mc of (B,Lc,Din) source, K=3*Din
__global__ void k_split_conv(const float* __restrict__ src, u16* __restrict__ h,
                             u16* __restrict__ l, int r0, int Lc, int Din,
                             int K, int Kp) {
  int col = blockIdx.x*256 + threadIdx.x;
  if (col >= Kp) return;
  int rr = blockIdx.y;
  int r = r0 + rr;
  int b = r / Lc, t = r - b*Lc;
  float v = 0.f;
  if (col < K) {
    int c = (col >= 2*Din) ? 2 : ((col >= Din) ? 1 : 0);
    int n = col - c*Din;
    int tt = t + c - 1;
    if (tt < 0) tt = Lc - 1; else if (tt >= Lc) tt = 0;
    v = src[((size_t)(b*Lc + tt))*Din + n];
  }
  u16 hh = f2bf(v);
  size_t o = (size_t)rr*Kp + col;
  h[o] = hh; l[o] = f2bf(v - bf2f(hh));
}

// materialize transpose of (B,Lc,512): out row (b*512+ch), col l (padded to Kp)
__global__ void k_split_tr(const float* __restrict__ src, u16* __restrict__ h,
                           u16* __restrict__ l, int Lc, int Kp) {
  __shared__ float t[32][33];
  int b = blockIdx.z;
  int l0 = blockIdx.x*32, c0 = blockIdx.y*32;
  int lx = threadIdx.x, ly = threadIdx.y;   // (32,8)
  #pragma unroll
  for (int i = 0; i < 4; ++i) {
    int ll = l0 + ly + i*8;
    t[ly + i*8][lx] = (ll < Lc) ? src[((size_t)b*Lc + ll)*DD + c0 + lx] : 0.f;
  }
  __syncthreads();
  #pragma unroll
  for (int i = 0; i < 4; ++i) {
    int ch = c0 + ly + i*8;
    int ll = l0 + lx;
    float v = t[lx][ly + i*8];
    u16 hh = f2bf(v);
    size_t o = ((size_t)b*DD + ch)*Kp + ll;
    h[o] = hh; l[o] = f2bf(v - bf2f(hh));
  }
}

// conv-embed weight: [512][992] from Wv (512,321,3)
__global__ void k_build_wconvS(const float* __restrict__ Wv, u16* __restrict__ h,
                               u16* __restrict__ l) {
  int col = blockIdx.x*256 + threadIdx.x;
  if (col >= 992) return;
  int d = blockIdx.y;
  float v = 0.f;
  if (col < 963) {
    int c = (col >= 642) ? 2 : ((col >= 321) ? 1 : 0);
    int n = col - c*321;
    v = Wv[(size_t)d*963 + n*3 + c];
  }
  u16 hh = f2bf(v);
  size_t o = (size_t)d*992 + col;
  h[o] = hh; l[o] = f2bf(v - bf2f(hh));
}

// trend conv weight: [321][1536] from Wtr (321,512,3)
__global__ void k_build_wtrcS(const float* __restrict__ Wtr, u16* __restrict__ h,
                              u16* __restrict__ l) {
  int col = blockIdx.x*256 + threadIdx.x;
  if (col >= 1536) return;
  int n = blockIdx.y;
  int c = col >> 9, d = col & 511;
  float v = Wtr[(size_t)n*1536 + d*3 + c];
  u16 hh = f2bf(v);
  size_t o = (size_t)n*1536 + col;
  h[o] = hh; l[o] = f2bf(v - bf2f(hh));
}

// DFT matrix rows: [128][Kp]; rows 0..63 cos, 64..127 -sin
__global__ void k_build_dftS(u16* __restrict__ h, u16* __restrict__ l, int L, int Kp) {
  int col = blockIdx.x*256 + threadIdx.x;
  if (col >= Kp) return;
  int mr = blockIdx.y;
  float v = 0.f;
  if (col < L) {
    int m = mr & 63;
    int ph = (m * col) % L;
    float th = 6.2831853071795864f * ((float)ph / (float)L);
    v = (mr < 64) ? cosf(th) : -sinf(th);
  }
  u16 hh = f2bf(v);
  size_t o = (size_t)mr*Kp + col;
  h[o] = hh; l[o] = f2bf(v - bf2f(hh));
}

// irfft matrix: [L][128]
__global__ void k_build_irS(u16* __restrict__ h, u16* __restrict__ l, int L) {
  int k = threadIdx.x;   // 0..127
  int ll = blockIdx.y;
  int m = k & 63;
  int ph = (m * ll) % L;
  float th = 6.2831853071795864f * ((float)ph / (float)L);
  float v;
  if (k < 64) v = (m == 0) ? (1.f/(float)L) : (2.f/(float)L) * cosf(th);
  else        v = (m == 0) ? 0.f            : -(2.f/(float)L) * sinf(th);
  u16 hh = f2bf(v);
  size_t o = (size_t)ll*128 + k;
  h[o] = hh; l[o] = f2bf(v - bf2f(hh));
}

// ---------------- MFMA GEMM on pre-split bf16 hi/lo ----------------
// C[M,Nc] = A[M,K]@W^T with 3-MFMA hi/lo compensation. K multiple of 32.
// TN: 128 or 64 (output tile is 128 x TN). EPI bits: 1=+bias, 4=gelu, 2=+res.
// WOUT: 0 -> fp32 C; 1 -> write split Ch/Cl (after EPI).
template<int TN, int EPI, int WOUT>
__global__ __launch_bounds__(256)
void k_mg(const u16* __restrict__ Ah, const u16* __restrict__ Al,
          const u16* __restrict__ Bh, const u16* __restrict__ Bl,
          const float* __restrict__ bias, const float* __restrict__ res,
          float* __restrict__ C, u16* __restrict__ Ch, u16* __restrict__ Cl,
          int M, int Nc, int K)
{
  __shared__ short sAh[128][40];
  __shared__ short sAl[128][40];
  __shared__ short sBh[TN][40];
  __shared__ short sBl[TN][40];

  const int tid  = threadIdx.x;
  const int lane = tid & 63;
  const int wave = tid >> 6;
  const int lr   = lane & 15;
  const int kg   = lane >> 4;

  const int row0 = blockIdx.y * 128;
  const int col0 = blockIdx.x * TN;

  const int srow = tid >> 1;
  const int kh   = (tid & 1) * 16;
  const int ar   = row0 + srow;

  constexpr int MF = (TN == 128) ? 4 : 2;
  const int wr = (TN == 128) ? (wave >> 1) : wave;
  const int wc = (TN == 128) ? (wave & 1) : 0;

  floatx4 acc[MF][4] = {};

  for (int k0 = 0; k0 < K; k0 += 32) {
    {
      short8 h0 = {}, h1 = {}, l0 = {}, l1 = {};
      if (ar < M) {
        const u16* pa = Ah + (size_t)ar*K + k0 + kh;
        const u16* pl = Al + (size_t)ar*K + k0 + kh;
        h0 = *(const short8*)pa; h1 = *(const short8*)(pa + 8);
        l0 = *(const short8*)pl; l1 = *(const short8*)(pl + 8);
      }
      *(short8*)&sAh[srow][kh] = h0; *(short8*)&sAh[srow][kh+8] = h1;
      *(short8*)&sAl[srow][kh] = l0; *(short8*)&sAl[srow][kh+8] = l1;
    }
    if (TN == 128 || tid < 128) {
      int brow = col0 + srow;
      short8 h0 = {}, h1 = {}, l0 = {}, l1 = {};
      if (brow < Nc) {
        const u16* pb = Bh + (size_t)brow*K + k0 + kh;
        const u16* pl = Bl + (size_t)brow*K + k0 + kh;
        h0 = *(const short8*)pb; h1 = *(const short8*)(pb + 8);
        l0 = *(const short8*)pl; l1 = *(const short8*)(pl + 8);
      }
      *(short8*)&sBh[srow][kh] = h0; *(short8*)&sBh[srow][kh+8] = h1;
      *(short8*)&sBl[srow][kh] = l0; *(short8*)&sBl[srow][kh+8] = l1;
    }
    __syncthreads();

    short8 ah[MF], al[MF], bh[4], bl[4];
    #pragma unroll
    for (int f = 0; f < MF; ++f) {
      int ra = wr*(MF*16) + f*16 + lr;
      ah[f] = *(const short8*)&sAh[ra][kg*8];
      al[f] = *(const short8*)&sAl[ra][kg*8];
    }
    #pragma unroll
    for (int n = 0; n < 4; ++n) {
      int rb = wc*64 + n*16 + lr;
      bh[n] = *(const short8*)&sBh[rb][kg*8];
      bl[n] = *(const short8*)&sBl[rb][kg*8];
    }
    #pragma unroll
    for (int mf = 0; mf < MF; ++mf)
      #pragma unroll
      for (int nf = 0; nf < 4; ++nf) {
        acc[mf][nf] = __builtin_amdgcn_mfma_f32_16x16x32_bf16(ah[mf], bh[nf], acc[mf][nf], 0, 0, 0);
        acc[mf][nf] = __builtin_amdgcn_mfma_f32_16x16x32_bf16(ah[mf], bl[nf], acc[mf][nf], 0, 0, 0);
        acc[mf][nf] = __builtin_amdgcn_mfma_f32_16x16x32_bf16(al[mf], bh[nf], acc[mf][nf], 0, 0, 0);
      }
    __syncthreads();
  }

  #pragma unroll
  for (int nf = 0; nf < 4; ++nf) {
    int cN = col0 + wc*64 + nf*16 + lr;
    if (cN >= Nc) continue;
    #pragma unroll
    for (int mf = 0; mf < MF; ++mf) {
      #pragma unroll
      for (int i = 0; i < 4; ++i) {
        int rM = row0 + wr*(MF*16) + mf*16 + kg*4 + i;
        if (rM >= M) continue;
        float v = acc[mf][nf][i];
        if (EPI & 1) v += bias[cN];
        if (EPI & 4) v = 0.5f * v * (1.f + erff(v * 0.7071067811865476f));
        if (EPI & 2) v += res[(size_t)rM * Nc + cN];
        if (WOUT) {
          u16 hh = f2bf(v);
          size_t o = (size_t)rM * Nc + cN;
          Ch[o] = hh; Cl[o] = f2bf(v - bf2f(hh));
        } else {
          C[(size_t)rM * Nc + cN] = v;
        }
      }
    }
  }
}

// ---------------- mode mix ----------------
__global__ __launch_bounds__(256)
void k_modemix(const float* __restrict__ ftbuf, const float* __restrict__ fr,
               const float* __restrict__ fi, float* __restrict__ sel, float scale)
{
  int m = blockIdx.x, h = blockIdx.y;
  __shared__ float wr[64][64], wi[64][64];
  __shared__ float qr[BB][64], qi[BB][64];
  int tid = threadIdx.x;
  for (int it = 0; it < 16; ++it) {
    int idx = tid + it*256;
    int e = idx >> 6, o = idx & 63;
    size_t wof = ((((size_t)h*64 + e)*64 + o) << 6) + m;
    wr[e][o] = fr[wof]; wi[e][o] = fi[wof];
  }
  for (int it = 0; it < 4; ++it) {
    int idx = tid + it*256;
    int bb = idx >> 6, e = idx & 63;
    size_t qof = ((size_t)bb*DD + h*64 + e)*128 + m;
    qr[bb][e] = ftbuf[qof]; qi[bb][e] = ftbuf[qof + 64];
  }
  __syncthreads();
  for (int it = 0; it < 4; ++it) {
    int idx = tid + it*256;
    int bb = idx >> 6, o = idx & 63;
    float ar = 0.f, ai = 0.f;
    for (int e = 0; e < 64; ++e) {
      float xr = qr[bb][e], xi = qi[bb][e], yr = wr[e][o], yi = wi[e][o];
      ar += xr*yr - xi*yi;
      ai += xr*yi + xi*yr;
    }
    size_t sof = ((size_t)bb*DD + h*64 + o)*128 + m;
    sel[sof] = ar*scale; sel[sof + 64] = ai*scale;
  }
}

// ---------------- cross attention ----------------
__global__ __launch_bounds__(256)
void k_cross_qk(const float* __restrict__ qf, const float* __restrict__ kf,
                float* __restrict__ ab)
{
  int bh = blockIdx.x; int b = bh >> 3, h = bh & 7;
  __shared__ float qr[32][64], qi[32][64], kr[32][64], ki[32][64];
  int tid = threadIdx.x;
  int tx = tid & 15, ty = tid >> 4;
  float ar[4][4] = {}, ai[4][4] = {};
  for (int e0 = 0; e0 < 64; e0 += 32) {
    for (int it = 0; it < 8; ++it) {
      int idx = tid + it*256;
      int e = idx >> 6, x = idx & 63;
      size_t rof = ((size_t)b*DD + h*64 + e0 + e)*128;
      qr[e][x] = qf[rof + x]; qi[e][x] = qf[rof + 64 + x];
      kr[e][x] = kf[rof + x]; ki[e][x] = kf[rof + 64 + x];
    }
    __syncthreads();
    for (int e = 0; e < 32; ++e) {
      float xr[4], xi2[4], yr[4], yi[4];
      #pragma unroll
      for (int i = 0; i < 4; ++i) { xr[i] = qr[e][ty*4+i]; xi2[i] = qi[e][ty*4+i]; }
      #pragma unroll
      for (int j = 0; j < 4; ++j) { yr[j] = kr[e][tx*4+j]; yi[j] = ki[e][tx*4+j]; }
      #pragma unroll
      for (int i = 0; i < 4; ++i)
        #pragma unroll
        for (int j = 0; j < 4; ++j) {
          ar[i][j] += xr[i]*yr[j] - xi2[i]*yi[j];
          ai[i][j] += xr[i]*yi[j] + xi2[i]*yr[j];
        }
    }
    __syncthreads();
  }
  #pragma unroll
  for (int i = 0; i < 4; ++i)
    #pragma unroll
    for (int j = 0; j < 4; ++j) {
      float txv = tanhf(ar[i][j]);
      float tyv = tanf(ai[i][j]);
      float den = 1.f + txv*txv*tyv*tyv;
      float re = txv*(1.f + tyv*tyv) / den;
      float im = tyv*(1.f - txv*txv) / den;
      size_t of = ((size_t)bh*64 + (ty*4+i))*128 + tx*4 + j;
      ab[of] = re; ab[of + 64] = im;
    }
}

__global__ __launch_bounds__(256)
void k_cross_v(const float* __restrict__ ab, const float* __restrict__ kf,
               float* __restrict__ v)
{
  int bh = blockIdx.x; int b = bh >> 3, h = bh & 7;
  __shared__ float ar[64][32], ai[64][32], kr[64][32], ki[64][32];
  int tid = threadIdx.x;
  int tx = tid & 15, ty = tid >> 4;
  float vr[4][4] = {}, vi[4][4] = {};
  for (int y0 = 0; y0 < 64; y0 += 32) {
    for (int it = 0; it < 8; ++it) {
      int idx = tid + it*256;
      int r = idx >> 5, y = idx & 31;
      ar[r][y] = ab[((size_t)bh*64 + r)*128 + y0 + y];
      ai[r][y] = ab[((size_t)bh*64 + r)*128 + 64 + y0 + y];
      kr[r][y] = kf[((size_t)b*DD + h*64 + r)*128 + y0 + y];
      ki[r][y] = kf[((size_t)b*DD + h*64 + r)*128 + 64 + y0 + y];
    }
    __syncthreads();
    for (int y = 0; y < 32; ++y) {
      float er[4], ei[4], xr[4], xi2[4];
      #pragma unroll
      for (int i = 0; i < 4; ++i) { er[i] = kr[ty*4+i][y]; ei[i] = ki[ty*4+i][y]; }
      #pragma unroll
      for (int j = 0; j < 4; ++j) { xr[j] = ar[tx*4+j][y]; xi2[j] = ai[tx*4+j][y]; }
      #pragma unroll
      for (int i = 0; i < 4; ++i)
        #pragma unroll
        for (int j = 0; j < 4; ++j) {
          vr[i][j] += xr[j]*er[i] - xi2[j]*ei[i];
          vi[i][j] += xr[j]*ei[i] + xi2[j]*er[i];
        }
    }
    __syncthreads();
  }
  #pragma unroll
  for (int i = 0; i < 4; ++i)
    #pragma unroll
    for (int j = 0; j < 4; ++j) {
      size_t of = ((size_t)b*DD + h*64 + ty*4 + i)*128 + tx*4 + j;
      v[of] = vr[i][j]; v[of + 64] = vi[i][j];
    }
}

// ---------------- LN + column-mean subtract ----------------
__global__ __launch_bounds__(256)
void k_ln(const float* __restrict__ x, const float* __restrict__ g,
          const float* __restrict__ be, float* __restrict__ out)
{
  int r = blockIdx.x; int tid = threadIdx.x;
  float v1 = x[(size_t)r*DD + tid], v2 = x[(size_t)r*DD + 256 + tid];
  float s = v1 + v2, s2 = v1*v1 + v2*v2;
  #pragma unroll
  for (int off = 32; off; off >>= 1) { s += __shfl_down(s, off, 64); s2 += __shfl_down(s2, off, 64); }
  __shared__ float red[8];
  int wid = tid >> 6, lane = tid & 63;
  if (lane == 0) { red[wid] = s; red[4 + wid] = s2; }
  __syncthreads();
  if (tid == 0) {
    float a = red[0]+red[1]+red[2]+red[3];
    float b2 = red[4]+red[5]+red[6]+red[7];
    float mu = a / 512.f;
    float var = b2 / 512.f - mu*mu;
    red[0] = mu; red[1] = rsqrtf(var + 1e-5f);
  }
  __syncthreads();
  float mu = red[0], inv = red[1];
  out[(size_t)r*DD + tid]       = (v1 - mu)*inv*g[tid]       + be[tid];
  out[(size_t)r*DD + 256 + tid] = (v2 - mu)*inv*g[256 + tid] + be[256 + tid];
}

__global__ void k_colmean_sub(float* __restrict__ x, int L) {
  int b = blockIdx.x;
  int d = blockIdx.y*256 + threadIdx.x;
  float s = 0.f;
  for (int l = 0; l < L; ++l) s += x[((size_t)b*L + l)*DD + d];
  float mu = s / (float)L;
  for (int l = 0; l < L; ++l) x[((size_t)b*L + l)*DD + d] -= mu;
}

// ---------------- series decomp (window 25, edge-clamped) ----------------
template<int ACC>
__global__ void k_decomp(const float* __restrict__ x, float* __restrict__ out,
                         float* __restrict__ tsum, int L)
{
  size_t idx = (size_t)blockIdx.x * 256 + threadIdx.x;
  size_t total = (size_t)BB * L * DD;
  if (idx >= total) return;
  int d = idx & 511;
  size_t rl = idx >> 9;
  int l = (int)(rl % L); int b = (int)(rl / L);
  float s = 0.f;
  for (int j = -12; j <= 12; ++j) {
    int lc = l + j; lc = lc < 0 ? 0 : (lc >= L ? L-1 : lc);
    s += x[(((size_t)b*L + lc) << 9) + d];
  }
  float ma = s * (1.f/25.f);
  out[idx] = x[idx] - ma;
  if (ACC) tsum[idx] += ma;
}

// ---------------- final ----------------
__global__ void k_final(const float* __restrict__ trend, const float* __restrict__ seas,
                        float* __restrict__ out) {
  int idx = blockIdx.x*256 + threadIdx.x;
  if (idx >= BB*LEN_E*NV) return;
  int n = idx % NV; int r = idx / NV; int t = r % LEN_E; int b = r / LEN_E;
  size_t src = ((size_t)b*LEN_D + 360 + t)*NV + n;
  out[idx] = trend[src] + seas[src];
}

// =====================================================================
extern "C" void kernel_launch(void* const* d_in, const int* in_sizes, int n_in,
                              void* d_out, int out_size, void* d_ws, size_t ws_size,
                              hipStream_t stream)
{
  (void)in_sizes; (void)n_in; (void)out_size; (void)ws_size;
  const float* history = (const float*)d_in[0];
  const float* future  = (const float*)d_in[1];
  const float* Wv_enc  = (const float*)d_in[2];
  const float* Wt_enc  = (const float*)d_in[3];
  const float* Wv_dec  = (const float*)d_in[4];
  const float* Wt_dec  = (const float*)d_in[5];
  const float* eWq = (const float*)d_in[6];
  const float* ebq = (const float*)d_in[7];
  const float* efr = (const float*)d_in[8];
  const float* efi = (const float*)d_in[9];
  const float* eWo = (const float*)d_in[10];
  const float* ebo = (const float*)d_in[11];
  const float* eW1 = (const float*)d_in[12];
  const float* eW2 = (const float*)d_in[13];
  const float* g_enc = (const float*)d_in[14];
  const float* b_enc = (const float*)d_in[15];
  const float* dWq = (const float*)d_in[16];
  const float* dbq = (const float*)d_in[17];
  const float* dfr = (const float*)d_in[18];
  const float* dfi = (const float*)d_in[19];
  const float* dWo = (const float*)d_in[20];
  const float* dbo = (const float*)d_in[21];
  const float* cWq = (const float*)d_in[22];
  const float* cbq = (const float*)d_in[23];
  const float* cWk = (const float*)d_in[24];
  const float* cbk = (const float*)d_in[25];
  const float* cfr = (const float*)d_in[26];
  const float* cfi = (const float*)d_in[27];
  const float* cWo = (const float*)d_in[28];
  const float* cbo = (const float*)d_in[29];
  const float* dW1 = (const float*)d_in[30];
  const float* dW2 = (const float*)d_in[31];
  const float* Wtr = (const float*)d_in[32];
  const float* g_dec = (const float*)d_in[33];
  const float* b_dec = (const float*)d_in[34];
  const float* Wp  = (const float*)d_in[35];
  const float* bp  = (const float*)d_in[36];

  float* ws = (float*)d_ws;
  size_t off = 0;
  auto alloc = [&](size_t n) { float* p = ws + off; off += (n + 63) & ~(size_t)63; return p; };

  const size_t SL = 1048576;

  // persistent fp32
  float* btrend = alloc((size_t)BB*LEN_D*NV);
  float* bTsum  = alloc((size_t)BB*LEN_D*DD);
  float* bX     = alloc((size_t)BB*LEN_D*DD);
  float* bT     = alloc((size_t)BB*LEN_D*DD);
  float* bencout= alloc((size_t)BB*LEN_E*DD);
  float* bseas  = alloc((size_t)BB*LEN_D*NV);
  float* bseasF = bseas;
  // rotating split / fp32-scratch region
  float* R      = alloc((size_t)11600000);
  // weight-split scratch (two 1M-float pairs)
  float* SB     = alloc((size_t)2*SL + 128);
  // persistent small weight splits
  float* WceS   = alloc((size_t)512*992/2*2);      // pair = 512*992 floats
  float* WcdS   = alloc((size_t)512*992);
  float* WtrcS  = alloc((size_t)321*1536);
  float* D720S  = alloc((size_t)128*736);
  float* D1080S = alloc((size_t)128*1088);
  float* I720S  = alloc((size_t)736*128);
  float* I1080S = alloc((size_t)1088*128);
  float* bxme   = alloc((size_t)BB*LEN_E*4);
  float* bxmd   = alloc((size_t)BB*LEN_D*4);
  float* bmean  = alloc((size_t)BB*NV);

  float* bxe = bT;   // bxe aliases bT during prep (dead before encoder writes T)

  // pair helpers
  auto H = [](float* base) { return (u16*)base; };
  auto Lo = [](float* base, size_t M, size_t Kp) { return (u16*)base + M*Kp; };

  auto splitP = [&](const float* src, float* dst, int M, int K, int Kp) {
    dim3 g((Kp + 255)/256, M);
    k_split_plain<<<g,256,0,stream>>>(src, H(dst), Lo(dst, M, Kp), K, Kp);
  };
  auto splitC = [&](const float* src, float* dst, int r0, int Mc, int Lc, int Din, int K, int Kp) {
    dim3 g((Kp + 255)/256, Mc);
    k_split_conv<<<g,256,0,stream>>>(src, H(dst), Lo(dst, Mc, Kp), r0, Lc, Din, K, Kp);
  };
  auto splitT = [&](const float* src, float* dst, int Lc, int Kp) {
    dim3 g(Kp/32, 16, BB), b(32, 8);
    k_split_tr<<<g,b,0,stream>>>(src, H(dst), Lo(dst, (size_t)BB*DD, Kp), Lc, Kp);
  };

  auto mg128 = [&](int epi, float* A, size_t Ma, float* B, size_t Nb,
                   const float* bias, const float* res, float* C,
                   int M, int N, int K) {
    dim3 g((N + 127)/128, (M + 127)/128);
    u16 *ah = H(A), *al = Lo(A, Ma, K), *bh = H(B), *bl = Lo(B, Nb, K);
    switch (epi) {
      case 0: k_mg<128,0,0><<<g,256,0,stream>>>(ah,al,bh,bl,bias,res,C,nullptr,nullptr,M,N,K); break;
      case 1: k_mg<128,1,0><<<g,256,0,stream>>>(ah,al,bh,bl,bias,res,C,nullptr,nullptr,M,N,K); break;
      case 3: k_mg<128,3,0><<<g,256,0,stream>>>(ah,al,bh,bl,bias,res,C,nullptr,nullptr,M,N,K); break;
    }
  };
  auto mg128s = [&](float* A, size_t Ma, float* B, size_t Nb, float* Cs,
                    int M, int N, int K) {   // gelu + split-out
    dim3 g((N + 127)/128, (M + 127)/128);
    k_mg<128,4,1><<<g,256,0,stream>>>(H(A), Lo(A, Ma, K), H(B), Lo(B, Nb, K),
                                      nullptr, nullptr, nullptr,
                                      H(Cs), Lo(Cs, M, N), M, N, K);
  };
  auto mg64 = [&](int epi, float* A, size_t Ma, float* B, size_t Nb,
                  const float* bias, const float* res, float* C,
                  int M, int N, int K) {
    dim3 g((N + 63)/64, (M + 127)/128);
    u16 *ah = H(A), *al = Lo(A, Ma, K), *bh = H(B), *bl = Lo(B, Nb, K);
    switch (epi) {
      case 0: k_mg<64,0,0><<<g,256,0,stream>>>(ah,al,bh,bl,bias,res,C,nullptr,nullptr,M,N,K); break;
      case 1: k_mg<64,1,0><<<g,256,0,stream>>>(ah,al,bh,bl,bias,res,C,nullptr,nullptr,M,N,K); break;
      case 2: k_mg<64,2,0><<<g,256,0,stream>>>(ah,al,bh,bl,bias,res,C,nullptr,nullptr,M,N,K); break;
    }
  };

  auto decomp = [&](const float* in, float* out, int L, bool acc) {
    size_t tot = (size_t)BB * L * DD;
    int g = (int)((tot + 255)/256);
    if (acc) k_decomp<1><<<g,256,0,stream>>>(in, out, bTsum, L);
    else     k_decomp<0><<<g,256,0,stream>>>(in, out, nullptr, L);
  };

  // FFN: out = in + gelu(in@W1.T)@W2.T, chunked
  const int CH = 4320;
  float* SA2 = R + 2359296;
  auto ffn = [&](const float* in, float* out, const float* W1, const float* W2, int M) {
    splitP(W1, SB, DFF2, DD, DD);                 // SB0: W1 pair (1M floats)
    splitP(W2, SB + SL, DD, DFF2, DFF2);          // SB1: W2 pair
    for (int r0 = 0; r0 < M; r0 += CH) {
      int mc = M - r0; if (mc > CH) mc = CH;
      splitP(in + (size_t)r0*DD, R, mc, DD, DD);
      mg128s(R, mc, SB, DFF2, SA2, mc, DFF2, DD);
      mg64(2, SA2, mc, SB + SL, DD, nullptr, in + (size_t)r0*DD,
           out + (size_t)r0*DD, mc, DD, DFF2);
    }
  };

  // X += fourier_self(X); T scratch
  auto fourier_self = [&](float* X, float* T, int L, int KpL, float* DLS, float* ILS,
                          const float* Wq, const float* bq, const float* fr, const float* fi,
                          const float* Wo, const float* bo) {
    int M = BB * L;
    float* bqf  = R + 9*SL;
    float* bsel = R + 10*SL;
    splitP(X, R, M, DD, DD);
    splitP(Wq, SB, DD, DD, DD);
    mg128(1, R, M, SB, DD, bq, nullptr, T, M, DD, DD);
    splitT(T, R, L, KpL);
    mg64(0, R, (size_t)BB*DD, DLS, 128, nullptr, nullptr, bqf, BB*DD, 128, KpL);
    k_modemix<<<dim3(64,8),256,0,stream>>>(bqf, fr, fi, bsel, 1.0f);
    splitP(bsel, R, BB*DD, 128, 128);
    mg128(0, R, (size_t)BB*DD, ILS, L, nullptr, nullptr, T, BB*DD, L, 128);
    splitP(T, R, M, DD, DD);
    splitP(Wo, SB, DD, DD, DD);
    mg128(3, R, M, SB, DD, bo, X, X, M, DD, DD);
  };

  auto myln = [&](const float* in, float* out, const float* g, const float* b, int L) {
    k_ln<<<BB*L,256,0,stream>>>(in, g, b, out);
    k_colmean_sub<<<dim3(BB,2),256,0,stream>>>(out, L);
  };

  // ---------------- prep ----------------
  k_extract_x<<<(BB*LEN_E*NV + 255)/256,256,0,stream>>>(history, bxe);
  k_marks_enc<<<(BB*LEN_E*4 + 255)/256,256,0,stream>>>(history, bxme);
  k_marks_dec<<<(BB*LEN_D*4 + 255)/256,256,0,stream>>>(future, bxme, bxmd);
  k_mean_series<<<(BB*NV + 255)/256,256,0,stream>>>(bxe, bmean);
  k_init_decomp<<<(BB*LEN_D*NV + 255)/256,256,0,stream>>>(bxe, bmean, bseas, btrend);
  k_build_wconvS<<<dim3(4,512),256,0,stream>>>(Wv_enc, H(WceS), Lo(WceS, 512, 992));
  k_build_wconvS<<<dim3(4,512),256,0,stream>>>(Wv_dec, H(WcdS), Lo(WcdS, 512, 992));
  k_build_wtrcS<<<dim3(6,321),256,0,stream>>>(Wtr, H(WtrcS), Lo(WtrcS, 321, 1536));
  k_build_dftS<<<dim3(3,128),256,0,stream>>>(H(D720S), Lo(D720S, 128, 736), LEN_E, 736);
  k_build_dftS<<<dim3(5,128),256,0,stream>>>(H(D1080S), Lo(D1080S, 128, 1088), LEN_D, 1088);
  k_build_irS<<<dim3(1,LEN_E),128,0,stream>>>(H(I720S), Lo(I720S, LEN_E, 128), LEN_E);
  k_build_irS<<<dim3(1,LEN_D),128,0,stream>>>(H(I1080S), Lo(I1080S, LEN_D, 128), LEN_D);

  // ---------------- encoder ----------------
  int ME = BB * LEN_E;
  for (int r0 = 0; r0 < ME; r0 += 5760) {              // conv embed, 2 chunks
    splitC(bxe, R, r0, 5760, LEN_E, NV, 963, 992);
    mg128(0, R, 5760, WceS, DD, nullptr, nullptr, bX + (size_t)r0*DD, 5760, DD, 992);
  }
  k_marks_add<<<(ME*DD + 255)/256,256,0,stream>>>(bX, bxme, Wt_enc, ME);

  float *X = bX, *T = bT;
  for (int i = 0; i < 2; ++i) {
    fourier_self(X, T, LEN_E, 736, D720S, I720S,
                 eWq + (size_t)i*DD*DD, ebq + (size_t)i*DD,
                 efr + (size_t)i*HHN*64*64*64, efi + (size_t)i*HHN*64*64*64,
                 eWo + (size_t)i*DD*DD, ebo + (size_t)i*DD);
    decomp(X, T, LEN_E, false);
    ffn(T, X, eW1 + (size_t)i*DFF2*DD, eW2 + (size_t)i*DD*DFF2, ME);
    decomp(X, T, LEN_E, false);
    { float* tmp = X; X = T; T = tmp; }
  }
  myln(X, bencout, g_enc, b_enc, LEN_E);

  // ---------------- decoder ----------------
  int MD = BB * LEN_D;
  for (int r0 = 0; r0 < MD; r0 += 8640) {              // conv embed, 2 chunks
    splitC(bseas, R, r0, 8640, LEN_D, NV, 963, 992);
    mg128(0, R, 8640, WcdS, DD, nullptr, nullptr, X + (size_t)r0*DD, 8640, DD, 992);
  }
  k_marks_add<<<(MD*DD + 255)/256,256,0,stream>>>(X, bxmd, Wt_dec, MD);

  fourier_self(X, T, LEN_D, 1088, D1080S, I1080S, dWq, dbq, dfr, dfi, dWo, dbo);

  k_zero<<<(BB*LEN_D*DD + 255)/256,256,0,stream>>>(bTsum, BB*LEN_D*DD);
  decomp(X, T, LEN_D, true);          // x -> T, t1 acc

  // cross attention
  {
    float* bkf  = R + 9*SL;
    float* bqf  = R + 10*SL;
    splitP(bencout, R, ME, DD, DD);
    splitP(cWk, SB, DD, DD, DD);
    mg128(1, R, ME, SB, DD, cbk, nullptr, X, ME, DD, DD);
    splitT(X, R, LEN_E, 736);
    mg64(0, R, (size_t)BB*DD, D720S, 128, nullptr, nullptr, bkf, BB*DD, 128, 736);
    splitP(T, R, MD, DD, DD);
    splitP(cWq, SB, DD, DD, DD);
    mg128(1, R, MD, SB, DD, cbq, nullptr, X, MD, DD, DD);
    splitT(X, R, LEN_D, 1088);
    mg64(0, R, (size_t)BB*DD, D1080S, 128, nullptr, nullptr, bqf, BB*DD, 128, 1088);
    float* ba   = R;
    float* bv   = R + SL;
    float* bsel = R + 2*SL;
    float* bss  = R + 3*SL;
    k_cross_qk<<<BB*HHN,256,0,stream>>>(bqf, bkf, ba);
    k_cross_v<<<BB*HHN,256,0,stream>>>(ba, bkf, bv);
    k_modemix<<<dim3(64,8),256,0,stream>>>(bv, cfr, cfi, bsel, 1.0f/262144.0f);
    splitP(bsel, bss, BB*DD, 128, 128);
    mg128(0, bss, (size_t)BB*DD, I1080S, LEN_D, nullptr, nullptr, X, BB*DD, LEN_D, 128);
    splitP(X, R, MD, DD, DD);
    splitP(cWo, SB, DD, DD, DD);
    mg128(3, R, MD, SB, DD, cbo, T, T, MD, DD, DD);
  }

  decomp(T, X, LEN_D, true);          // x -> X, t2 acc
  ffn(X, T, dW1, dW2, MD);            // T = x + FFN(x)
  decomp(T, X, LEN_D, true);          // x -> X, t3 acc

  myln(X, T, g_dec, b_dec, LEN_D);
  splitP(T, R, MD, DD, DD);
  splitP(Wp, SB, NV, DD, DD);
  mg64(1, R, MD, SB, NV, bp, nullptr, bseasF, MD, NV, DD);

  for (int r0 = 0; r0 < MD; r0 += 5760) {              // trend conv, 3 chunks
    splitC(bTsum, R, r0, 5760, LEN_D, DD, 1536, 1536);
    mg64(2, R, 5760, WtrcS, NV, nullptr, btrend + (size_t)r0*NV,
         btrend + (size_t)r0*NV, 5760, NV, 1536);
  }

  k_final<<<(BB*LEN_E*NV + 255)/256,256,0,stream>>>(btrend, bseasF, (float*)d_out);
}

// Round 6
// 3975.557 us; speedup vs baseline: 3.5828x; 1.1405x over previous
//
#include <hip/hip_runtime.h>
#include <math.h>

#define BB 16
#define DD 512
#define HHN 8
#define LEN_E 720
#define LEN_D 1080
#define NV 321
#define DFF2 2048

typedef __attribute__((ext_vector_type(8))) short short8;
typedef __attribute__((ext_vector_type(4))) float floatx4;
typedef unsigned short u16;

__device__ __forceinline__ u16 f2bf(float v) {
  unsigned u = __builtin_bit_cast(unsigned, v);
  u += 0x7FFFu + ((u >> 16) & 1u);
  return (u16)(u >> 16);
}
__device__ __forceinline__ float bf2f(u16 h) {
  unsigned u = ((unsigned)h) << 16;
  return __builtin_bit_cast(float, u);
}

// ---------------- prep kernels ----------------
__global__ void k_extract_x(const float* __restrict__ hist, float* __restrict__ xe) {
  int idx = blockIdx.x * 256 + threadIdx.x;
  if (idx >= BB*LEN_E*NV) return;
  xe[idx] = hist[(size_t)idx * 5];
}

__global__ void k_marks_enc(const float* __restrict__ hist, float* __restrict__ xme) {
  int idx = blockIdx.x * 256 + threadIdx.x;
  if (idx >= BB*LEN_E*4) return;
  int f = idx & 3;
  int r = idx >> 2;
  xme[idx] = hist[((size_t)r * NV) * 5 + 1 + f];
}

__global__ void k_marks_dec(const float* __restrict__ fut, const float* __restrict__ xme,
                            float* __restrict__ xmd) {
  int idx = blockIdx.x * 256 + threadIdx.x;
  if (idx >= BB*LEN_D*4) return;
  int f = idx & 3;
  int r = idx >> 2;
  int t = r % LEN_D, b = r / LEN_D;
  float v;
  if (t < 360) v = xme[((b*LEN_E) + 360 + t)*4 + f];
  else v = fut[(((size_t)(b*LEN_E + (t-360))) * NV) * 5 + 1 + f];
  xmd[idx] = v;
}

// mean over L of encoder series: partial sums (chunks of 72) then finalize
__global__ void k_ms_part(const float* __restrict__ xe, float* __restrict__ part,
                          int chl, int nch) {
  int n = threadIdx.x;            // 384, guard to 321
  if (n >= NV) return;
  int b = blockIdx.x, c = blockIdx.y;
  int l0 = c*chl, l1 = l0 + chl; if (l1 > LEN_E) l1 = LEN_E;
  float s = 0.f;
  for (int l = l0; l < l1; ++l) s += xe[((size_t)b*LEN_E + l)*NV + n];
  part[((size_t)b*nch + c)*NV + n] = s;
}
__global__ void k_ms_fin(const float* __restrict__ part, float* __restrict__ mb, int nch) {
  int i = blockIdx.x*256 + threadIdx.x;
  if (i >= BB*NV) return;
  int b = i / NV, n = i % NV;
  float s = 0.f;
  for (int c = 0; c < nch; ++c) s += part[((size_t)b*nch + c)*NV + n];
  mb[i] = s * (1.f/(float)LEN_E);
}

__global__ void k_init_decomp(const float* __restrict__ xe, const float* __restrict__ mb,
                              float* __restrict__ seas, float* __restrict__ trend) {
  int idx = blockIdx.x * 256 + threadIdx.x;
  if (idx >= BB*LEN_D*NV) return;
  int n = idx % NV; int r = idx / NV; int t = r % LEN_D; int b = r / LEN_D;
  if (t < 360) {
    int l = 360 + t;
    float s = 0.f;
    for (int j = -12; j <= 12; ++j) {
      int lc = l + j; if (lc > LEN_E-1) lc = LEN_E-1; if (lc < 0) lc = 0;
      s += xe[((size_t)b*LEN_E + lc)*NV + n];
    }
    float ma = s * (1.f/25.f);
    trend[idx] = ma;
    seas[idx]  = xe[((size_t)b*LEN_E + l)*NV + n] - ma;
  } else {
    trend[idx] = mb[b*NV + n];
    seas[idx]  = 0.f;
  }
}

__global__ void k_zero(float* __restrict__ p, int n) {
  int i = blockIdx.x*256 + threadIdx.x;
  if (i < n) p[i] = 0.f;
}

// marks embedding: X[r][d] += sum_f xm[r][f]*Wt[d][f]   (K=4, pure vector)
__global__ void k_marks_add(float* __restrict__ X, const float* __restrict__ xm,
                            const float* __restrict__ Wt, int M) {
  int idx = blockIdx.x*256 + threadIdx.x;
  if (idx >= M*DD) return;
  int d = idx & 511, r = idx >> 9;
  const float* m4 = xm + (size_t)r*4;
  const float* w4 = Wt + (size_t)d*4;
  X[idx] += m4[0]*w4[0] + m4[1]*w4[1] + m4[2]*w4[2] + m4[3]*w4[3];
}

// ---------------- split builders (fp32 -> bf16 hi/lo, K padded) ----------------
__global__ void k_split_plain(const float* __restrict__ src, u16* __restrict__ h,
                              u16* __restrict__ l, int K, int Kp) {
  int col = blockIdx.x*256 + threadIdx.x;
  if (col >= Kp) return;
  int r = blockIdx.y;
  float v = (col < K) ? src[(size_t)r*K + col] : 0.f;
  u16 hh = f2bf(v);
  size_t o = (size_t)r*Kp + col;
  h[o] = hh; l[o] = f2bf(v - bf2f(hh));
}

// materialize circular conv3 gather: rows r0..r0+Mc of (B,Lc,Din) source, K=3*Din
__global__ void k_split_conv(const float* __restrict__ src, u16* __restrict__ h,
                             u16* __restrict__ l, int r0, int Lc, int Din,
                             int K, int Kp) {
  int col = blockIdx.x*256 + threadIdx.x;
  if (col >= Kp) return;
  int rr = blockIdx.y;
  int r = r0 + rr;
  int b = r / Lc, t = r - b*Lc;
  float v = 0.f;
  if (col < K) {
    int c = (col >= 2*Din) ? 2 : ((col >= Din) ? 1 : 0);
    int n = col - c*Din;
    int tt = t + c - 1;
    if (tt < 0) tt = Lc - 1; else if (tt >= Lc) tt = 0;
    v = src[((size_t)(b*Lc + tt))*Din + n];
  }
  u16 hh = f2bf(v);
  size_t o = (size_t)rr*Kp + col;
  h[o] = hh; l[o] = f2bf(v - bf2f(hh));
}

// materialize transpose of (B,Lc,512): out row (b*512+ch), col l (padded to Kp)
__global__ void k_split_tr(const float* __restrict__ src, u16* __restrict__ h,
                           u16* __restrict__ l, int Lc, int Kp) {
  __shared__ float t[32][33];
  int b = blockIdx.z;
  int l0 = blockIdx.x*32, c0 = blockIdx.y*32;
  int lx = threadIdx.x, ly = threadIdx.y;   // (32,8)
  #pragma unroll
  for (int i = 0; i < 4; ++i) {
    int ll = l0 + ly + i*8;
    t[ly + i*8][lx] = (ll < Lc) ? src[((size_t)b*Lc + ll)*DD + c0 + lx] : 0.f;
  }
  __syncthreads();
  #pragma unroll
  for (int i = 0; i < 4; ++i) {
    int ch = c0 + ly + i*8;
    int ll = l0 + lx;
    float v = t[lx][ly + i*8];
    u16 hh = f2bf(v);
    size_t o = ((size_t)b*DD + ch)*Kp + ll;
    h[o] = hh; l[o] = f2bf(v - bf2f(hh));
  }
}

// conv-embed weight: [512][992] from Wv (512,321,3)
__global__ void k_build_wconvS(const float* __restrict__ Wv, u16* __restrict__ h,
                               u16* __restrict__ l) {
  int col = blockIdx.x*256 + threadIdx.x;
  if (col >= 992) return;
  int d = blockIdx.y;
  float v = 0.f;
  if (col < 963) {
    int c = (col >= 642) ? 2 : ((col >= 321) ? 1 : 0);
    int n = col - c*321;
    v = Wv[(size_t)d*963 + n*3 + c];
  }
  u16 hh = f2bf(v);
  size_t o = (size_t)d*992 + col;
  h[o] = hh; l[o] = f2bf(v - bf2f(hh));
}

// trend conv weight: [321][1536] from Wtr (321,512,3)
__global__ void k_build_wtrcS(const float* __restrict__ Wtr, u16* __restrict__ h,
                              u16* __restrict__ l) {
  int col = blockIdx.x*256 + threadIdx.x;
  if (col >= 1536) return;
  int n = blockIdx.y;
  int c = col >> 9, d = col & 511;
  float v = Wtr[(size_t)n*1536 + d*3 + c];
  u16 hh = f2bf(v);
  size_t o = (size_t)n*1536 + col;
  h[o] = hh; l[o] = f2bf(v - bf2f(hh));
}

// DFT matrix rows: [128][Kp]; rows 0..63 cos, 64..127 -sin
__global__ void k_build_dftS(u16* __restrict__ h, u16* __restrict__ l, int L, int Kp) {
  int col = blockIdx.x*256 + threadIdx.x;
  if (col >= Kp) return;
  int mr = blockIdx.y;
  float v = 0.f;
  if (col < L) {
    int m = mr & 63;
    int ph = (m * col) % L;
    float th = 6.2831853071795864f * ((float)ph / (float)L);
    v = (mr < 64) ? cosf(th) : -sinf(th);
  }
  u16 hh = f2bf(v);
  size_t o = (size_t)mr*Kp + col;
  h[o] = hh; l[o] = f2bf(v - bf2f(hh));
}

// irfft matrix: [L][128]
__global__ void k_build_irS(u16* __restrict__ h, u16* __restrict__ l, int L) {
  int k = threadIdx.x;   // 0..127
  int ll = blockIdx.y;
  int m = k & 63;
  int ph = (m * ll) % L;
  float th = 6.2831853071795864f * ((float)ph / (float)L);
  float v;
  if (k < 64) v = (m == 0) ? (1.f/(float)L) : (2.f/(float)L) * cosf(th);
  else        v = (m == 0) ? 0.f            : -(2.f/(float)L) * sinf(th);
  u16 hh = f2bf(v);
  size_t o = (size_t)ll*128 + k;
  h[o] = hh; l[o] = f2bf(v - bf2f(hh));
}

// ---------------- MFMA GEMM on pre-split bf16 hi/lo ----------------
template<int TN, int EPI, int WOUT>
__global__ __launch_bounds__(256)
void k_mg(const u16* __restrict__ Ah, const u16* __restrict__ Al,
          const u16* __restrict__ Bh, const u16* __restrict__ Bl,
          const float* __restrict__ bias, const float* __restrict__ res,
          float* __restrict__ C, u16* __restrict__ Ch, u16* __restrict__ Cl,
          int M, int Nc, int K)
{
  __shared__ short sAh[128][40];
  __shared__ short sAl[128][40];
  __shared__ short sBh[TN][40];
  __shared__ short sBl[TN][40];

  const int tid  = threadIdx.x;
  const int lane = tid & 63;
  const int wave = tid >> 6;
  const int lr   = lane & 15;
  const int kg   = lane >> 4;

  const int row0 = blockIdx.y * 128;
  const int col0 = blockIdx.x * TN;

  const int srow = tid >> 1;
  const int kh   = (tid & 1) * 16;
  const int ar   = row0 + srow;

  constexpr int MF = (TN == 128) ? 4 : 2;
  const int wr = (TN == 128) ? (wave >> 1) : wave;
  const int wc = (TN == 128) ? (wave & 1) : 0;

  floatx4 acc[MF][4] = {};

  for (int k0 = 0; k0 < K; k0 += 32) {
    {
      short8 h0 = {}, h1 = {}, l0 = {}, l1 = {};
      if (ar < M) {
        const u16* pa = Ah + (size_t)ar*K + k0 + kh;
        const u16* pl = Al + (size_t)ar*K + k0 + kh;
        h0 = *(const short8*)pa; h1 = *(const short8*)(pa + 8);
        l0 = *(const short8*)pl; l1 = *(const short8*)(pl + 8);
      }
      *(short8*)&sAh[srow][kh] = h0; *(short8*)&sAh[srow][kh+8] = h1;
      *(short8*)&sAl[srow][kh] = l0; *(short8*)&sAl[srow][kh+8] = l1;
    }
    if (TN == 128 || tid < 128) {
      int brow = col0 + srow;
      short8 h0 = {}, h1 = {}, l0 = {}, l1 = {};
      if (brow < Nc) {
        const u16* pb = Bh + (size_t)brow*K + k0 + kh;
        const u16* pl = Bl + (size_t)brow*K + k0 + kh;
        h0 = *(const short8*)pb; h1 = *(const short8*)(pb + 8);
        l0 = *(const short8*)pl; l1 = *(const short8*)(pl + 8);
      }
      *(short8*)&sBh[srow][kh] = h0; *(short8*)&sBh[srow][kh+8] = h1;
      *(short8*)&sBl[srow][kh] = l0; *(short8*)&sBl[srow][kh+8] = l1;
    }
    __syncthreads();

    short8 ah[MF], al[MF], bh[4], bl[4];
    #pragma unroll
    for (int f = 0; f < MF; ++f) {
      int ra = wr*(MF*16) + f*16 + lr;
      ah[f] = *(const short8*)&sAh[ra][kg*8];
      al[f] = *(const short8*)&sAl[ra][kg*8];
    }
    #pragma unroll
    for (int n = 0; n < 4; ++n) {
      int rb = wc*64 + n*16 + lr;
      bh[n] = *(const short8*)&sBh[rb][kg*8];
      bl[n] = *(const short8*)&sBl[rb][kg*8];
    }
    #pragma unroll
    for (int mf = 0; mf < MF; ++mf)
      #pragma unroll
      for (int nf = 0; nf < 4; ++nf) {
        acc[mf][nf] = __builtin_amdgcn_mfma_f32_16x16x32_bf16(ah[mf], bh[nf], acc[mf][nf], 0, 0, 0);
        acc[mf][nf] = __builtin_amdgcn_mfma_f32_16x16x32_bf16(ah[mf], bl[nf], acc[mf][nf], 0, 0, 0);
        acc[mf][nf] = __builtin_amdgcn_mfma_f32_16x16x32_bf16(al[mf], bh[nf], acc[mf][nf], 0, 0, 0);
      }
    __syncthreads();
  }

  #pragma unroll
  for (int nf = 0; nf < 4; ++nf) {
    int cN = col0 + wc*64 + nf*16 + lr;
    if (cN >= Nc) continue;
    #pragma unroll
    for (int mf = 0; mf < MF; ++mf) {
      #pragma unroll
      for (int i = 0; i < 4; ++i) {
        int rM = row0 + wr*(MF*16) + mf*16 + kg*4 + i;
        if (rM >= M) continue;
        float v = acc[mf][nf][i];
        if (EPI & 1) v += bias[cN];
        if (EPI & 4) v = 0.5f * v * (1.f + erff(v * 0.7071067811865476f));
        if (EPI & 2) v += res[(size_t)rM * Nc + cN];
        if (WOUT) {
          u16 hh = f2bf(v);
          size_t o = (size_t)rM * Nc + cN;
          Ch[o] = hh; Cl[o] = f2bf(v - bf2f(hh));
        } else {
          C[(size_t)rM * Nc + cN] = v;
        }
      }
    }
  }
}

// ---------------- mode mix ----------------
__global__ __launch_bounds__(256)
void k_modemix(const float* __restrict__ ftbuf, const float* __restrict__ fr,
               const float* __restrict__ fi, float* __restrict__ sel, float scale)
{
  int m = blockIdx.x, h = blockIdx.y;
  __shared__ float wr[64][64], wi[64][64];
  __shared__ float qr[BB][64], qi[BB][64];
  int tid = threadIdx.x;
  for (int it = 0; it < 16; ++it) {
    int idx = tid + it*256;
    int e = idx >> 6, o = idx & 63;
    size_t wof = ((((size_t)h*64 + e)*64 + o) << 6) + m;
    wr[e][o] = fr[wof]; wi[e][o] = fi[wof];
  }
  for (int it = 0; it < 4; ++it) {
    int idx = tid + it*256;
    int bb = idx >> 6, e = idx & 63;
    size_t qof = ((size_t)bb*DD + h*64 + e)*128 + m;
    qr[bb][e] = ftbuf[qof]; qi[bb][e] = ftbuf[qof + 64];
  }
  __syncthreads();
  for (int it = 0; it < 4; ++it) {
    int idx = tid + it*256;
    int bb = idx >> 6, o = idx & 63;
    float ar = 0.f, ai = 0.f;
    for (int e = 0; e < 64; ++e) {
      float xr = qr[bb][e], xi = qi[bb][e], yr = wr[e][o], yi = wi[e][o];
      ar += xr*yr - xi*yi;
      ai += xr*yi + xi*yr;
    }
    size_t sof = ((size_t)bb*DD + h*64 + o)*128 + m;
    sel[sof] = ar*scale; sel[sof + 64] = ai*scale;
  }
}

// ---------------- cross attention ----------------
__global__ __launch_bounds__(256)
void k_cross_qk(const float* __restrict__ qf, const float* __restrict__ kf,
                float* __restrict__ ab)
{
  int bh = blockIdx.x; int b = bh >> 3, h = bh & 7;
  __shared__ float qr[32][64], qi[32][64], kr[32][64], ki[32][64];
  int tid = threadIdx.x;
  int tx = tid & 15, ty = tid >> 4;
  float ar[4][4] = {}, ai[4][4] = {};
  for (int e0 = 0; e0 < 64; e0 += 32) {
    for (int it = 0; it < 8; ++it) {
      int idx = tid + it*256;
      int e = idx >> 6, x = idx & 63;
      size_t rof = ((size_t)b*DD + h*64 + e0 + e)*128;
      qr[e][x] = qf[rof + x]; qi[e][x] = qf[rof + 64 + x];
      kr[e][x] = kf[rof + x]; ki[e][x] = kf[rof + 64 + x];
    }
    __syncthreads();
    for (int e = 0; e < 32; ++e) {
      float xr[4], xi2[4], yr[4], yi[4];
      #pragma unroll
      for (int i = 0; i < 4; ++i) { xr[i] = qr[e][ty*4+i]; xi2[i] = qi[e][ty*4+i]; }
      #pragma unroll
      for (int j = 0; j < 4; ++j) { yr[j] = kr[e][tx*4+j]; yi[j] = ki[e][tx*4+j]; }
      #pragma unroll
      for (int i = 0; i < 4; ++i)
        #pragma unroll
        for (int j = 0; j < 4; ++j) {
          ar[i][j] += xr[i]*yr[j] - xi2[i]*yi[j];
          ai[i][j] += xr[i]*yi[j] + xi2[i]*yr[j];
        }
    }
    __syncthreads();
  }
  #pragma unroll
  for (int i = 0; i < 4; ++i)
    #pragma unroll
    for (int j = 0; j < 4; ++j) {
      float txv = tanhf(ar[i][j]);
      float tyv = tanf(ai[i][j]);
      float den = 1.f + txv*txv*tyv*tyv;
      float re = txv*(1.f + tyv*tyv) / den;
      float im = tyv*(1.f - txv*txv) / den;
      size_t of = ((size_t)bh*64 + (ty*4+i))*128 + tx*4 + j;
      ab[of] = re; ab[of + 64] = im;
    }
}

__global__ __launch_bounds__(256)
void k_cross_v(const float* __restrict__ ab, const float* __restrict__ kf,
               float* __restrict__ v)
{
  int bh = blockIdx.x; int b = bh >> 3, h = bh & 7;
  __shared__ float ar[64][32], ai[64][32], kr[64][32], ki[64][32];
  int tid = threadIdx.x;
  int tx = tid & 15, ty = tid >> 4;
  float vr[4][4] = {}, vi[4][4] = {};
  for (int y0 = 0; y0 < 64; y0 += 32) {
    for (int it = 0; it < 8; ++it) {
      int idx = tid + it*256;
      int r = idx >> 5, y = idx & 31;
      ar[r][y] = ab[((size_t)bh*64 + r)*128 + y0 + y];
      ai[r][y] = ab[((size_t)bh*64 + r)*128 + 64 + y0 + y];
      kr[r][y] = kf[((size_t)b*DD + h*64 + r)*128 + y0 + y];
      ki[r][y] = kf[((size_t)b*DD + h*64 + r)*128 + 64 + y0 + y];
    }
    __syncthreads();
    for (int y = 0; y < 32; ++y) {
      float er[4], ei[4], xr[4], xi2[4];
      #pragma unroll
      for (int i = 0; i < 4; ++i) { er[i] = kr[ty*4+i][y]; ei[i] = ki[ty*4+i][y]; }
      #pragma unroll
      for (int j = 0; j < 4; ++j) { xr[j] = ar[tx*4+j][y]; xi2[j] = ai[tx*4+j][y]; }
      #pragma unroll
      for (int i = 0; i < 4; ++i)
        #pragma unroll
        for (int j = 0; j < 4; ++j) {
          vr[i][j] += xr[j]*er[i] - xi2[j]*ei[i];
          vi[i][j] += xr[j]*ei[i] + xi2[j]*er[i];
        }
    }
    __syncthreads();
  }
  #pragma unroll
  for (int i = 0; i < 4; ++i)
    #pragma unroll
    for (int j = 0; j < 4; ++j) {
      size_t of = ((size_t)b*DD + h*64 + ty*4 + i)*128 + tx*4 + j;
      v[of] = vr[i][j]; v[of + 64] = vi[i][j];
    }
}

// ---------------- LN + column-mean subtract ----------------
__global__ __launch_bounds__(256)
void k_ln(const float* __restrict__ x, const float* __restrict__ g,
          const float* __restrict__ be, float* __restrict__ out)
{
  int r = blockIdx.x; int tid = threadIdx.x;
  float v1 = x[(size_t)r*DD + tid], v2 = x[(size_t)r*DD + 256 + tid];
  float s = v1 + v2, s2 = v1*v1 + v2*v2;
  #pragma unroll
  for (int off = 32; off; off >>= 1) { s += __shfl_down(s, off, 64); s2 += __shfl_down(s2, off, 64); }
  __shared__ float red[8];
  int wid = tid >> 6, lane = tid & 63;
  if (lane == 0) { red[wid] = s; red[4 + wid] = s2; }
  __syncthreads();
  if (tid == 0) {
    float a = red[0]+red[1]+red[2]+red[3];
    float b2 = red[4]+red[5]+red[6]+red[7];
    float mu = a / 512.f;
    float var = b2 / 512.f - mu*mu;
    red[0] = mu; red[1] = rsqrtf(var + 1e-5f);
  }
  __syncthreads();
  float mu = red[0], inv = red[1];
  out[(size_t)r*DD + tid]       = (v1 - mu)*inv*g[tid]       + be[tid];
  out[(size_t)r*DD + 256 + tid] = (v2 - mu)*inv*g[256 + tid] + be[256 + tid];
}

// column-mean subtract, parallel deterministic tree
__global__ void k_colsum_part(const float* __restrict__ x, float* __restrict__ part,
                              int L, int chl, int nch) {
  int d = threadIdx.x;            // 512
  int b = blockIdx.x, c = blockIdx.y;
  int l0 = c*chl, l1 = l0 + chl; if (l1 > L) l1 = L;
  float s = 0.f;
  for (int l = l0; l < l1; ++l) s += x[(((size_t)b*L + l) << 9) + d];
  part[((size_t)(b*nch + c) << 9) + d] = s;
}
__global__ void k_colsum_fin(const float* __restrict__ part, float* __restrict__ cm,
                             int nch, float inv) {
  int i = blockIdx.x*256 + threadIdx.x;   // b*512+d (8192)
  int b = i >> 9, d = i & 511;
  float s = 0.f;
  for (int c = 0; c < nch; ++c) s += part[((size_t)(b*nch + c) << 9) + d];
  cm[i] = s * inv;
}
__global__ void k_csub(float* __restrict__ x, const float* __restrict__ cm, int L) {
  size_t idx = (size_t)blockIdx.x*256 + threadIdx.x;
  if (idx >= (size_t)BB*L*DD) return;
  int d = (int)(idx & 511);
  int b = (int)((idx >> 9) / (size_t)L);
  x[idx] -= cm[(b << 9) | d];
}

// ---------------- series decomp (window 25, edge-clamped) ----------------
template<int ACC>
__global__ void k_decomp(const float* __restrict__ x, float* __restrict__ out,
                         float* __restrict__ tsum, int L)
{
  size_t idx = (size_t)blockIdx.x * 256 + threadIdx.x;
  size_t total = (size_t)BB * L * DD;
  if (idx >= total) return;
  int d = idx & 511;
  size_t rl = idx >> 9;
  int l = (int)(rl % L); int b = (int)(rl / L);
  float s = 0.f;
  for (int j = -12; j <= 12; ++j) {
    int lc = l + j; lc = lc < 0 ? 0 : (lc >= L ? L-1 : lc);
    s += x[(((size_t)b*L + lc) << 9) + d];
  }
  float ma = s * (1.f/25.f);
  out[idx] = x[idx] - ma;
  if (ACC) tsum[idx] += ma;
}

// ---------------- final ----------------
__global__ void k_final(const float* __restrict__ trend, const float* __restrict__ seas,
                        float* __restrict__ out) {
  int idx = blockIdx.x*256 + threadIdx.x;
  if (idx >= BB*LEN_E*NV) return;
  int n = idx % NV; int r = idx / NV; int t = r % LEN_E; int b = r / LEN_E;
  size_t src = ((size_t)b*LEN_D + 360 + t)*NV + n;
  out[idx] = trend[src] + seas[src];
}

// =====================================================================
extern "C" void kernel_launch(void* const* d_in, const int* in_sizes, int n_in,
                              void* d_out, int out_size, void* d_ws, size_t ws_size,
                              hipStream_t stream)
{
  (void)in_sizes; (void)n_in; (void)out_size; (void)ws_size;
  const float* history = (const float*)d_in[0];
  const float* future  = (const float*)d_in[1];
  const float* Wv_enc  = (const float*)d_in[2];
  const float* Wt_enc  = (const float*)d_in[3];
  const float* Wv_dec  = (const float*)d_in[4];
  const float* Wt_dec  = (const float*)d_in[5];
  const float* eWq = (const float*)d_in[6];
  const float* ebq = (const float*)d_in[7];
  const float* efr = (const float*)d_in[8];
  const float* efi = (const float*)d_in[9];
  const float* eWo = (const float*)d_in[10];
  const float* ebo = (const float*)d_in[11];
  const float* eW1 = (const float*)d_in[12];
  const float* eW2 = (const float*)d_in[13];
  const float* g_enc = (const float*)d_in[14];
  const float* b_enc = (const float*)d_in[15];
  const float* dWq = (const float*)d_in[16];
  const float* dbq = (const float*)d_in[17];
  const float* dfr = (const float*)d_in[18];
  const float* dfi = (const float*)d_in[19];
  const float* dWo = (const float*)d_in[20];
  const float* dbo = (const float*)d_in[21];
  const float* cWq = (const float*)d_in[22];
  const float* cbq = (const float*)d_in[23];
  const float* cWk = (const float*)d_in[24];
  const float* cbk = (const float*)d_in[25];
  const float* cfr = (const float*)d_in[26];
  const float* cfi = (const float*)d_in[27];
  const float* cWo = (const float*)d_in[28];
  const float* cbo = (const float*)d_in[29];
  const float* dW1 = (const float*)d_in[30];
  const float* dW2 = (const float*)d_in[31];
  const float* Wtr = (const float*)d_in[32];
  const float* g_dec = (const float*)d_in[33];
  const float* b_dec = (const float*)d_in[34];
  const float* Wp  = (const float*)d_in[35];
  const float* bp  = (const float*)d_in[36];

  float* ws = (float*)d_ws;
  size_t off = 0;
  auto alloc = [&](size_t n) { float* p = ws + off; off += (n + 63) & ~(size_t)63; return p; };

  const size_t SL = 1048576;

  // persistent fp32
  float* btrend = alloc((size_t)BB*LEN_D*NV);
  float* bTsum  = alloc((size_t)BB*LEN_D*DD);
  float* bX     = alloc((size_t)BB*LEN_D*DD);
  float* bT     = alloc((size_t)BB*LEN_D*DD);
  float* bencout= alloc((size_t)BB*LEN_E*DD);
  float* bseas  = alloc((size_t)BB*LEN_D*NV);
  float* bseasF = bseas;
  // rotating split / fp32-scratch region
  float* R      = alloc((size_t)11600000);
  // weight-split scratch (two 1M-float pairs)
  float* SB     = alloc((size_t)2*SL + 128);
  // persistent small weight splits
  float* WceS   = alloc((size_t)512*992);
  float* WcdS   = alloc((size_t)512*992);
  float* WtrcS  = alloc((size_t)321*1536);
  float* D720S  = alloc((size_t)128*736);
  float* D1080S = alloc((size_t)128*1088);
  float* I720S  = alloc((size_t)736*128);
  float* I1080S = alloc((size_t)1088*128);
  float* bxme   = alloc((size_t)BB*LEN_E*4);
  float* bxmd   = alloc((size_t)BB*LEN_D*4);
  float* bmean  = alloc((size_t)BB*NV);
  float* bpart  = alloc((size_t)BB*9*DD);     // colsum partials
  float* bcm    = alloc((size_t)BB*DD);       // col means
  float* bmsp   = alloc((size_t)BB*10*NV);    // mean_series partials

  float* bxe = bT;   // bxe aliases bT during prep (dead before encoder writes T)

  // pair helpers
  auto H = [](float* base) { return (u16*)base; };
  auto Lo = [](float* base, size_t M, size_t Kp) { return (u16*)base + M*Kp; };

  auto splitP = [&](const float* src, float* dst, int M, int K, int Kp) {
    dim3 g((Kp + 255)/256, M);
    k_split_plain<<<g,256,0,stream>>>(src, H(dst), Lo(dst, M, Kp), K, Kp);
  };
  auto splitC = [&](const float* src, float* dst, int r0, int Mc, int Lc, int Din, int K, int Kp) {
    dim3 g((Kp + 255)/256, Mc);
    k_split_conv<<<g,256,0,stream>>>(src, H(dst), Lo(dst, Mc, Kp), r0, Lc, Din, K, Kp);
  };
  auto splitT = [&](const float* src, float* dst, int Lc, int Kp) {
    dim3 g(Kp/32, 16, BB), b(32, 8);
    k_split_tr<<<g,b,0,stream>>>(src, H(dst), Lo(dst, (size_t)BB*DD, Kp), Lc, Kp);
  };

  auto mg128 = [&](int epi, float* A, size_t Ma, float* B, size_t Nb,
                   const float* bias, const float* res, float* C,
                   int M, int N, int K) {
    dim3 g((N + 127)/128, (M + 127)/128);
    u16 *ah = H(A), *al = Lo(A, Ma, K), *bh = H(B), *bl = Lo(B, Nb, K);
    switch (epi) {
      case 0: k_mg<128,0,0><<<g,256,0,stream>>>(ah,al,bh,bl,bias,res,C,nullptr,nullptr,M,N,K); break;
      case 1: k_mg<128,1,0><<<g,256,0,stream>>>(ah,al,bh,bl,bias,res,C,nullptr,nullptr,M,N,K); break;
      case 3: k_mg<128,3,0><<<g,256,0,stream>>>(ah,al,bh,bl,bias,res,C,nullptr,nullptr,M,N,K); break;
    }
  };
  auto mg128s = [&](float* A, size_t Ma, float* B, size_t Nb, float* Cs,
                    int M, int N, int K) {   // gelu + split-out
    dim3 g((N + 127)/128, (M + 127)/128);
    k_mg<128,4,1><<<g,256,0,stream>>>(H(A), Lo(A, Ma, K), H(B), Lo(B, Nb, K),
                                      nullptr, nullptr, nullptr,
                                      H(Cs), Lo(Cs, M, N), M, N, K);
  };
  auto mg64 = [&](int epi, float* A, size_t Ma, float* B, size_t Nb,
                  const float* bias, const float* res, float* C,
                  int M, int N, int K) {
    dim3 g((N + 63)/64, (M + 127)/128);
    u16 *ah = H(A), *al = Lo(A, Ma, K), *bh = H(B), *bl = Lo(B, Nb, K);
    switch (epi) {
      case 0: k_mg<64,0,0><<<g,256,0,stream>>>(ah,al,bh,bl,bias,res,C,nullptr,nullptr,M,N,K); break;
      case 1: k_mg<64,1,0><<<g,256,0,stream>>>(ah,al,bh,bl,bias,res,C,nullptr,nullptr,M,N,K); break;
      case 2: k_mg<64,2,0><<<g,256,0,stream>>>(ah,al,bh,bl,bias,res,C,nullptr,nullptr,M,N,K); break;
    }
  };

  auto decomp = [&](const float* in, float* out, int L, bool acc) {
    size_t tot = (size_t)BB * L * DD;
    int g = (int)((tot + 255)/256);
    if (acc) k_decomp<1><<<g,256,0,stream>>>(in, out, bTsum, L);
    else     k_decomp<0><<<g,256,0,stream>>>(in, out, nullptr, L);
  };

  // FFN: out = in + gelu(in@W1.T)@W2.T, chunked
  const int CH = 4320;
  float* SA2 = R + 2359296;
  auto ffn = [&](const float* in, float* out, const float* W1, const float* W2, int M) {
    splitP(W1, SB, DFF2, DD, DD);
    splitP(W2, SB + SL, DD, DFF2, DFF2);
    for (int r0 = 0; r0 < M; r0 += CH) {
      int mc = M - r0; if (mc > CH) mc = CH;
      splitP(in + (size_t)r0*DD, R, mc, DD, DD);
      mg128s(R, mc, SB, DFF2, SA2, mc, DFF2, DD);
      mg64(2, SA2, mc, SB + SL, DD, nullptr, in + (size_t)r0*DD,
           out + (size_t)r0*DD, mc, DD, DFF2);
    }
  };

  // X += fourier_self(X); T scratch
  auto fourier_self = [&](float* X, float* T, int L, int KpL, float* DLS, float* ILS,
                          const float* Wq, const float* bq, const float* fr, const float* fi,
                          const float* Wo, const float* bo) {
    int M = BB * L;
    float* bqf  = R + 9*SL;
    float* bsel = R + 10*SL;
    splitP(X, R, M, DD, DD);
    splitP(Wq, SB, DD, DD, DD);
    mg128(1, R, M, SB, DD, bq, nullptr, T, M, DD, DD);
    splitT(T, R, L, KpL);
    mg64(0, R, (size_t)BB*DD, DLS, 128, nullptr, nullptr, bqf, BB*DD, 128, KpL);
    k_modemix<<<dim3(64,8),256,0,stream>>>(bqf, fr, fi, bsel, 1.0f);
    splitP(bsel, R, BB*DD, 128, 128);
    mg128(0, R, (size_t)BB*DD, ILS, L, nullptr, nullptr, T, BB*DD, L, 128);
    splitP(T, R, M, DD, DD);
    splitP(Wo, SB, DD, DD, DD);
    mg128(3, R, M, SB, DD, bo, X, X, M, DD, DD);
  };

  auto myln = [&](const float* in, float* out, const float* g, const float* b, int L) {
    k_ln<<<BB*L,256,0,stream>>>(in, g, b, out);
    int chl = L / 9;
    k_colsum_part<<<dim3(BB,9),512,0,stream>>>(out, bpart, L, chl, 9);
    k_colsum_fin<<<32,256,0,stream>>>(bpart, bcm, 9, 1.f/(float)L);
    k_csub<<<(int)(((size_t)BB*L*DD + 255)/256),256,0,stream>>>(out, bcm, L);
  };

  // ---------------- prep ----------------
  k_extract_x<<<(BB*LEN_E*NV + 255)/256,256,0,stream>>>(history, bxe);
  k_marks_enc<<<(BB*LEN_E*4 + 255)/256,256,0,stream>>>(history, bxme);
  k_marks_dec<<<(BB*LEN_D*4 + 255)/256,256,0,stream>>>(future, bxme, bxmd);
  k_ms_part<<<dim3(BB,10),384,0,stream>>>(bxe, bmsp, 72, 10);
  k_ms_fin<<<(BB*NV + 255)/256,256,0,stream>>>(bmsp, bmean, 10);
  k_init_decomp<<<(BB*LEN_D*NV + 255)/256,256,0,stream>>>(bxe, bmean, bseas, btrend);
  k_build_wconvS<<<dim3(4,512),256,0,stream>>>(Wv_enc, H(WceS), Lo(WceS, 512, 992));
  k_build_wconvS<<<dim3(4,512),256,0,stream>>>(Wv_dec, H(WcdS), Lo(WcdS, 512, 992));
  k_build_wtrcS<<<dim3(6,321),256,0,stream>>>(Wtr, H(WtrcS), Lo(WtrcS, 321, 1536));
  k_build_dftS<<<dim3(3,128),256,0,stream>>>(H(D720S), Lo(D720S, 128, 736), LEN_E, 736);
  k_build_dftS<<<dim3(5,128),256,0,stream>>>(H(D1080S), Lo(D1080S, 128, 1088), LEN_D, 1088);
  k_build_irS<<<dim3(1,LEN_E),128,0,stream>>>(H(I720S), Lo(I720S, LEN_E, 128), LEN_E);
  k_build_irS<<<dim3(1,LEN_D),128,0,stream>>>(H(I1080S), Lo(I1080S, LEN_D, 128), LEN_D);

  // ---------------- encoder ----------------
  int ME = BB * LEN_E;
  for (int r0 = 0; r0 < ME; r0 += 5760) {
    splitC(bxe, R, r0, 5760, LEN_E, NV, 963, 992);
    mg128(0, R, 5760, WceS, DD, nullptr, nullptr, bX + (size_t)r0*DD, 5760, DD, 992);
  }
  k_marks_add<<<(ME*DD + 255)/256,256,0,stream>>>(bX, bxme, Wt_enc, ME);

  float *X = bX, *T = bT;
  for (int i = 0; i < 2; ++i) {
    fourier_self(X, T, LEN_E, 736, D720S, I720S,
                 eWq + (size_t)i*DD*DD, ebq + (size_t)i*DD,
                 efr + (size_t)i*HHN*64*64*64, efi + (size_t)i*HHN*64*64*64,
                 eWo + (size_t)i*DD*DD, ebo + (size_t)i*DD);
    decomp(X, T, LEN_E, false);
    ffn(T, X, eW1 + (size_t)i*DFF2*DD, eW2 + (size_t)i*DD*DFF2, ME);
    decomp(X, T, LEN_E, false);
    { float* tmp = X; X = T; T = tmp; }
  }
  myln(X, bencout, g_enc, b_enc, LEN_E);

  // ---------------- decoder ----------------
  int MD = BB * LEN_D;
  for (int r0 = 0; r0 < MD; r0 += 8640) {
    splitC(bseas, R, r0, 8640, LEN_D, NV, 963, 992);
    mg128(0, R, 8640, WcdS, DD, nullptr, nullptr, X + (size_t)r0*DD, 8640, DD, 992);
  }
  k_marks_add<<<(MD*DD + 255)/256,256,0,stream>>>(X, bxmd, Wt_dec, MD);

  fourier_self(X, T, LEN_D, 1088, D1080S, I1080S, dWq, dbq, dfr, dfi, dWo, dbo);

  k_zero<<<(BB*LEN_D*DD + 255)/256,256,0,stream>>>(bTsum, BB*LEN_D*DD);
  decomp(X, T, LEN_D, true);          // x -> T, t1 acc

  // cross attention
  {
    float* bkf  = R + 9*SL;
    float* bqf  = R + 10*SL;
    splitP(bencout, R, ME, DD, DD);
    splitP(cWk, SB, DD, DD, DD);
    mg128(1, R, ME, SB, DD, cbk, nullptr, X, ME, DD, DD);
    splitT(X, R, LEN_E, 736);
    mg64(0, R, (size_t)BB*DD, D720S, 128, nullptr, nullptr, bkf, BB*DD, 128, 736);
    splitP(T, R, MD, DD, DD);
    splitP(cWq, SB, DD, DD, DD);
    mg128(1, R, MD, SB, DD, cbq, nullptr, X, MD, DD, DD);
    splitT(X, R, LEN_D, 1088);
    mg64(0, R, (size_t)BB*DD, D1080S, 128, nullptr, nullptr, bqf, BB*DD, 128, 1088);
    float* ba   = R;
    float* bv   = R + SL;
    float* bsel = R + 2*SL;
    float* bss  = R + 3*SL;
    k_cross_qk<<<BB*HHN,256,0,stream>>>(bqf, bkf, ba);
    k_cross_v<<<BB*HHN,256,0,stream>>>(ba, bkf, bv);
    k_modemix<<<dim3(64,8),256,0,stream>>>(bv, cfr, cfi, bsel, 1.0f/262144.0f);
    splitP(bsel, bss, BB*DD, 128, 128);
    mg128(0, bss, (size_t)BB*DD, I1080S, LEN_D, nullptr, nullptr, X, BB*DD, LEN_D, 128);
    splitP(X, R, MD, DD, DD);
    splitP(cWo, SB, DD, DD, DD);
    mg128(3, R, MD, SB, DD, cbo, T, T, MD, DD, DD);
  }

  decomp(T, X, LEN_D, true);          // x -> X, t2 acc
  ffn(X, T, dW1, dW2, MD);            // T = x + FFN(x)
  decomp(T, X, LEN_D, true);          // x -> X, t3 acc

  myln(X, T, g_dec, b_dec, LEN_D);
  splitP(T, R, MD, DD, DD);
  splitP(Wp, SB, NV, DD, DD);
  mg64(1, R, MD, SB, NV, bp, nullptr, bseasF, MD, NV, DD);

  for (int r0 = 0; r0 < MD; r0 += 5760) {
    splitC(bTsum, R, r0, 5760, LEN_D, DD, 1536, 1536);
    mg64(2, R, 5760, WtrcS, NV, nullptr, btrend + (size_t)r0*NV,
         btrend + (size_t)r0*NV, 5760, NV, 1536);
  }

  k_final<<<(BB*LEN_E*NV + 255)/256,256,0,stream>>>(btrend, bseasF, (float*)d_out);
}

// Round 7
// 3420.765 us; speedup vs baseline: 4.1639x; 1.1622x over previous
//
#include <hip/hip_runtime.h>
#include <math.h>

#define BB 16
#define DD 512
#define HHN 8
#define LEN_E 720
#define LEN_D 1080
#define NV 321
#define DFF2 2048

typedef __attribute__((ext_vector_type(8))) short short8;
typedef __attribute__((ext_vector_type(4))) float floatx4;
typedef unsigned short u16;

__device__ __forceinline__ u16 f2bf(float v) {
  unsigned u = __builtin_bit_cast(unsigned, v);
  u += 0x7FFFu + ((u >> 16) & 1u);
  return (u16)(u >> 16);
}
__device__ __forceinline__ float bf2f(u16 h) {
  unsigned u = ((unsigned)h) << 16;
  return __builtin_bit_cast(float, u);
}

// ---------------- prep kernels ----------------
__global__ void k_extract_x(const float* __restrict__ hist, float* __restrict__ xe) {
  int idx = blockIdx.x * 256 + threadIdx.x;
  if (idx >= BB*LEN_E*NV) return;
  xe[idx] = hist[(size_t)idx * 5];
}

__global__ void k_marks_enc(const float* __restrict__ hist, float* __restrict__ xme) {
  int idx = blockIdx.x * 256 + threadIdx.x;
  if (idx >= BB*LEN_E*4) return;
  int f = idx & 3;
  int r = idx >> 2;
  xme[idx] = hist[((size_t)r * NV) * 5 + 1 + f];
}

__global__ void k_marks_dec(const float* __restrict__ fut, const float* __restrict__ xme,
                            float* __restrict__ xmd) {
  int idx = blockIdx.x * 256 + threadIdx.x;
  if (idx >= BB*LEN_D*4) return;
  int f = idx & 3;
  int r = idx >> 2;
  int t = r % LEN_D, b = r / LEN_D;
  float v;
  if (t < 360) v = xme[((b*LEN_E) + 360 + t)*4 + f];
  else v = fut[(((size_t)(b*LEN_E + (t-360))) * NV) * 5 + 1 + f];
  xmd[idx] = v;
}

// mean over L of encoder series: partial sums then finalize
__global__ void k_ms_part(const float* __restrict__ xe, float* __restrict__ part,
                          int chl, int nch) {
  int n = threadIdx.x;
  if (n >= NV) return;
  int b = blockIdx.x, c = blockIdx.y;
  int l0 = c*chl, l1 = l0 + chl; if (l1 > LEN_E) l1 = LEN_E;
  float s = 0.f;
  for (int l = l0; l < l1; ++l) s += xe[((size_t)b*LEN_E + l)*NV + n];
  part[((size_t)b*nch + c)*NV + n] = s;
}
__global__ void k_ms_fin(const float* __restrict__ part, float* __restrict__ mb, int nch) {
  int i = blockIdx.x*256 + threadIdx.x;
  if (i >= BB*NV) return;
  int b = i / NV, n = i % NV;
  float s = 0.f;
  for (int c = 0; c < nch; ++c) s += part[((size_t)b*nch + c)*NV + n];
  mb[i] = s * (1.f/(float)LEN_E);
}

__global__ void k_init_decomp(const float* __restrict__ xe, const float* __restrict__ mb,
                              float* __restrict__ seas, float* __restrict__ trend) {
  int idx = blockIdx.x * 256 + threadIdx.x;
  if (idx >= BB*LEN_D*NV) return;
  int n = idx % NV; int r = idx / NV; int t = r % LEN_D; int b = r / LEN_D;
  if (t < 360) {
    int l = 360 + t;
    float s = 0.f;
    for (int j = -12; j <= 12; ++j) {
      int lc = l + j; if (lc > LEN_E-1) lc = LEN_E-1; if (lc < 0) lc = 0;
      s += xe[((size_t)b*LEN_E + lc)*NV + n];
    }
    float ma = s * (1.f/25.f);
    trend[idx] = ma;
    seas[idx]  = xe[((size_t)b*LEN_E + l)*NV + n] - ma;
  } else {
    trend[idx] = mb[b*NV + n];
    seas[idx]  = 0.f;
  }
}

__global__ void k_zero(float* __restrict__ p, int n) {
  int i = blockIdx.x*256 + threadIdx.x;
  if (i < n) p[i] = 0.f;
}

// marks embedding: X[r][d] += sum_f xm[r][f]*Wt[d][f]   (K=4, pure vector)
__global__ void k_marks_add(float* __restrict__ X, const float* __restrict__ xm,
                            const float* __restrict__ Wt, int M) {
  int idx = blockIdx.x*256 + threadIdx.x;
  if (idx >= M*DD) return;
  int d = idx & 511, r = idx >> 9;
  const float* m4 = xm + (size_t)r*4;
  const float* w4 = Wt + (size_t)d*4;
  X[idx] += m4[0]*w4[0] + m4[1]*w4[1] + m4[2]*w4[2] + m4[3]*w4[3];
}

// ---------------- split builders (fp32 -> bf16 hi/lo, K padded) ----------------
__global__ void k_split_plain(const float* __restrict__ src, u16* __restrict__ h,
                              u16* __restrict__ l, int K, int Kp) {
  int col = blockIdx.x*256 + threadIdx.x;
  if (col >= Kp) return;
  int r = blockIdx.y;
  float v = (col < K) ? src[(size_t)r*K + col] : 0.f;
  u16 hh = f2bf(v);
  size_t o = (size_t)r*Kp + col;
  h[o] = hh; l[o] = f2bf(v - bf2f(hh));
}

// materialize circular conv3 gather: rows r0..r0+Mc of (B,Lc,Din) source, K=3*Din
__global__ void k_split_conv(const float* __restrict__ src, u16* __restrict__ h,
                             u16* __restrict__ l, int r0, int Lc, int Din,
                             int K, int Kp) {
  int col = blockIdx.x*256 + threadIdx.x;
  if (col >= Kp) return;
  int rr = blockIdx.y;
  int r = r0 + rr;
  int b = r / Lc, t = r - b*Lc;
  float v = 0.f;
  if (col < K) {
    int c = (col >= 2*Din) ? 2 : ((col >= Din) ? 1 : 0);
    int n = col - c*Din;
    int tt = t + c - 1;
    if (tt < 0) tt = Lc - 1; else if (tt >= Lc) tt = 0;
    v = src[((size_t)(b*Lc + tt))*Din + n];
  }
  u16 hh = f2bf(v);
  size_t o = (size_t)rr*Kp + col;
  h[o] = hh; l[o] = f2bf(v - bf2f(hh));
}

// materialize transpose of (B,Lc,512): out row (b*512+ch), col l (padded to Kp)
__global__ void k_split_tr(const float* __restrict__ src, u16* __restrict__ h,
                           u16* __restrict__ l, int Lc, int Kp) {
  __shared__ float t[32][33];
  int b = blockIdx.z;
  int l0 = blockIdx.x*32, c0 = blockIdx.y*32;
  int lx = threadIdx.x, ly = threadIdx.y;   // (32,8)
  #pragma unroll
  for (int i = 0; i < 4; ++i) {
    int ll = l0 + ly + i*8;
    t[ly + i*8][lx] = (ll < Lc) ? src[((size_t)b*Lc + ll)*DD + c0 + lx] : 0.f;
  }
  __syncthreads();
  #pragma unroll
  for (int i = 0; i < 4; ++i) {
    int ch = c0 + ly + i*8;
    int ll = l0 + lx;
    float v = t[lx][ly + i*8];
    u16 hh = f2bf(v);
    size_t o = ((size_t)b*DD + ch)*Kp + ll;
    h[o] = hh; l[o] = f2bf(v - bf2f(hh));
  }
}

// conv-embed weight: [512][992] from Wv (512,321,3)
__global__ void k_build_wconvS(const float* __restrict__ Wv, u16* __restrict__ h,
                               u16* __restrict__ l) {
  int col = blockIdx.x*256 + threadIdx.x;
  if (col >= 992) return;
  int d = blockIdx.y;
  float v = 0.f;
  if (col < 963) {
    int c = (col >= 642) ? 2 : ((col >= 321) ? 1 : 0);
    int n = col - c*321;
    v = Wv[(size_t)d*963 + n*3 + c];
  }
  u16 hh = f2bf(v);
  size_t o = (size_t)d*992 + col;
  h[o] = hh; l[o] = f2bf(v - bf2f(hh));
}

// trend conv weight: [321][1536] from Wtr (321,512,3)
__global__ void k_build_wtrcS(const float* __restrict__ Wtr, u16* __restrict__ h,
                              u16* __restrict__ l) {
  int col = blockIdx.x*256 + threadIdx.x;
  if (col >= 1536) return;
  int n = blockIdx.y;
  int c = col >> 9, d = col & 511;
  float v = Wtr[(size_t)n*1536 + d*3 + c];
  u16 hh = f2bf(v);
  size_t o = (size_t)n*1536 + col;
  h[o] = hh; l[o] = f2bf(v - bf2f(hh));
}

// DFT matrix rows: [128][Kp]; rows 0..63 cos, 64..127 -sin
__global__ void k_build_dftS(u16* __restrict__ h, u16* __restrict__ l, int L, int Kp) {
  int col = blockIdx.x*256 + threadIdx.x;
  if (col >= Kp) return;
  int mr = blockIdx.y;
  float v = 0.f;
  if (col < L) {
    int m = mr & 63;
    int ph = (m * col) % L;
    float th = 6.2831853071795864f * ((float)ph / (float)L);
    v = (mr < 64) ? cosf(th) : -sinf(th);
  }
  u16 hh = f2bf(v);
  size_t o = (size_t)mr*Kp + col;
  h[o] = hh; l[o] = f2bf(v - bf2f(hh));
}

// irfft matrix: [L][128]
__global__ void k_build_irS(u16* __restrict__ h, u16* __restrict__ l, int L) {
  int k = threadIdx.x;   // 0..127
  int ll = blockIdx.y;
  int m = k & 63;
  int ph = (m * ll) % L;
  float th = 6.2831853071795864f * ((float)ph / (float)L);
  float v;
  if (k < 64) v = (m == 0) ? (1.f/(float)L) : (2.f/(float)L) * cosf(th);
  else        v = (m == 0) ? 0.f            : -(2.f/(float)L) * sinf(th);
  u16 hh = f2bf(v);
  size_t o = (size_t)ll*128 + k;
  h[o] = hh; l[o] = f2bf(v - bf2f(hh));
}

// ---------------- MFMA GEMM on pre-split bf16 hi/lo ----------------
// XCD-chunked swizzle + register-prefetch pipeline.
template<int TN, int EPI, int WOUT>
__global__ __launch_bounds__(256)
void k_mg(const u16* __restrict__ Ah, const u16* __restrict__ Al,
          const u16* __restrict__ Bh, const u16* __restrict__ Bl,
          const float* __restrict__ bias, const float* __restrict__ res,
          float* __restrict__ C, u16* __restrict__ Ch, u16* __restrict__ Cl,
          int M, int Nc, int K)
{
  __shared__ short sAh[128][40];
  __shared__ short sAl[128][40];
  __shared__ short sBh[TN][40];
  __shared__ short sBl[TN][40];

  const int tid  = threadIdx.x;
  const int lane = tid & 63;
  const int wave = tid >> 6;
  const int lr   = lane & 15;
  const int kg   = lane >> 4;

  // bijective XCD-chunked swizzle: each XCD gets a contiguous x-major band
  const int gx  = gridDim.x;
  const int nwg = gx * gridDim.y;
  const int lid = blockIdx.y * gx + blockIdx.x;
  const int q8  = nwg >> 3, r8 = nwg & 7;
  const int xcd = lid & 7, i8 = lid >> 3;
  const int swz = (xcd < r8 ? xcd*(q8+1) : r8*(q8+1) + (xcd - r8)*q8) + i8;
  const int row0 = (swz / gx) * 128;
  const int col0 = (swz % gx) * TN;

  const int srow = tid >> 1;
  const int kh   = (tid & 1) * 16;
  const int ar   = row0 + srow;

  constexpr int MF = (TN == 128) ? 4 : 2;
  const int wr = (TN == 128) ? (wave >> 1) : wave;
  const int wc = (TN == 128) ? (wave & 1) : 0;

  floatx4 acc[MF][4] = {};

  const bool aok  = (ar < M);
  const int  brow = col0 + srow;
  const bool bact = (TN == 128) || (tid < 128);
  const bool bok  = bact && (brow < Nc);

  short8 pa0{}, pa1{}, pal0{}, pal1{}, pb0{}, pb1{}, pbl0{}, pbl1{};
  if (aok) {
    const u16* pa = Ah + (size_t)ar*K + kh;
    const u16* pl = Al + (size_t)ar*K + kh;
    pa0 = *(const short8*)pa;  pa1 = *(const short8*)(pa + 8);
    pal0 = *(const short8*)pl; pal1 = *(const short8*)(pl + 8);
  }
  if (bok) {
    const u16* pb = Bh + (size_t)brow*K + kh;
    const u16* pl = Bl + (size_t)brow*K + kh;
    pb0 = *(const short8*)pb;  pb1 = *(const short8*)(pb + 8);
    pbl0 = *(const short8*)pl; pbl1 = *(const short8*)(pl + 8);
  }

  for (int k0 = 0; k0 < K; k0 += 32) {
    *(short8*)&sAh[srow][kh]   = pa0;  *(short8*)&sAh[srow][kh+8] = pa1;
    *(short8*)&sAl[srow][kh]   = pal0; *(short8*)&sAl[srow][kh+8] = pal1;
    if (bact) {
      *(short8*)&sBh[srow][kh]   = pb0;  *(short8*)&sBh[srow][kh+8] = pb1;
      *(short8*)&sBl[srow][kh]   = pbl0; *(short8*)&sBl[srow][kh+8] = pbl1;
    }
    __syncthreads();

    const int kn = k0 + 32;
    if (kn < K) {
      if (aok) {
        const u16* pa = Ah + (size_t)ar*K + kn + kh;
        const u16* pl = Al + (size_t)ar*K + kn + kh;
        pa0 = *(const short8*)pa;  pa1 = *(const short8*)(pa + 8);
        pal0 = *(const short8*)pl; pal1 = *(const short8*)(pl + 8);
      }
      if (bok) {
        const u16* pb = Bh + (size_t)brow*K + kn + kh;
        const u16* pl = Bl + (size_t)brow*K + kn + kh;
        pb0 = *(const short8*)pb;  pb1 = *(const short8*)(pb + 8);
        pbl0 = *(const short8*)pl; pbl1 = *(const short8*)(pl + 8);
      }
    }

    short8 ahf[MF], alf[MF], bhf[4], blf[4];
    #pragma unroll
    for (int f = 0; f < MF; ++f) {
      int ra = wr*(MF*16) + f*16 + lr;
      ahf[f] = *(const short8*)&sAh[ra][kg*8];
      alf[f] = *(const short8*)&sAl[ra][kg*8];
    }
    #pragma unroll
    for (int n = 0; n < 4; ++n) {
      int rb = wc*64 + n*16 + lr;
      bhf[n] = *(const short8*)&sBh[rb][kg*8];
      blf[n] = *(const short8*)&sBl[rb][kg*8];
    }
    #pragma unroll
    for (int mf = 0; mf < MF; ++mf)
      #pragma unroll
      for (int nf = 0; nf < 4; ++nf) {
        acc[mf][nf] = __builtin_amdgcn_mfma_f32_16x16x32_bf16(ahf[mf], bhf[nf], acc[mf][nf], 0, 0, 0);
        acc[mf][nf] = __builtin_amdgcn_mfma_f32_16x16x32_bf16(ahf[mf], blf[nf], acc[mf][nf], 0, 0, 0);
        acc[mf][nf] = __builtin_amdgcn_mfma_f32_16x16x32_bf16(alf[mf], bhf[nf], acc[mf][nf], 0, 0, 0);
      }
    __syncthreads();
  }

  #pragma unroll
  for (int nf = 0; nf < 4; ++nf) {
    int cN = col0 + wc*64 + nf*16 + lr;
    if (cN >= Nc) continue;
    #pragma unroll
    for (int mf = 0; mf < MF; ++mf) {
      #pragma unroll
      for (int i = 0; i < 4; ++i) {
        int rM = row0 + wr*(MF*16) + mf*16 + kg*4 + i;
        if (rM >= M) continue;
        float v = acc[mf][nf][i];
        if (EPI & 1) v += bias[cN];
        if (EPI & 4) v = 0.5f * v * (1.f + erff(v * 0.7071067811865476f));
        if (EPI & 2) v += res[(size_t)rM * Nc + cN];
        if (WOUT) {
          u16 hh = f2bf(v);
          size_t o = (size_t)rM * Nc + cN;
          Ch[o] = hh; Cl[o] = f2bf(v - bf2f(hh));
        } else {
          C[(size_t)rM * Nc + cN] = v;
        }
      }
    }
  }
}

// ---------------- mode mix ----------------
__global__ __launch_bounds__(256)
void k_modemix(const float* __restrict__ ftbuf, const float* __restrict__ fr,
               const float* __restrict__ fi, float* __restrict__ sel, float scale)
{
  int m = blockIdx.x, h = blockIdx.y;
  __shared__ float wr[64][64], wi[64][64];
  __shared__ float qr[BB][64], qi[BB][64];
  int tid = threadIdx.x;
  for (int it = 0; it < 16; ++it) {
    int idx = tid + it*256;
    int e = idx >> 6, o = idx & 63;
    size_t wof = ((((size_t)h*64 + e)*64 + o) << 6) + m;
    wr[e][o] = fr[wof]; wi[e][o] = fi[wof];
  }
  for (int it = 0; it < 4; ++it) {
    int idx = tid + it*256;
    int bb = idx >> 6, e = idx & 63;
    size_t qof = ((size_t)bb*DD + h*64 + e)*128 + m;
    qr[bb][e] = ftbuf[qof]; qi[bb][e] = ftbuf[qof + 64];
  }
  __syncthreads();
  for (int it = 0; it < 4; ++it) {
    int idx = tid + it*256;
    int bb = idx >> 6, o = idx & 63;
    float ar = 0.f, ai = 0.f;
    for (int e = 0; e < 64; ++e) {
      float xr = qr[bb][e], xi = qi[bb][e], yr = wr[e][o], yi = wi[e][o];
      ar += xr*yr - xi*yi;
      ai += xr*yi + xi*yr;
    }
    size_t sof = ((size_t)bb*DD + h*64 + o)*128 + m;
    sel[sof] = ar*scale; sel[sof + 64] = ai*scale;
  }
}

// ---------------- cross attention ----------------
__global__ __launch_bounds__(256)
void k_cross_qk(const float* __restrict__ qf, const float* __restrict__ kf,
                float* __restrict__ ab)
{
  int bh = blockIdx.x; int b = bh >> 3, h = bh & 7;
  __shared__ float qr[32][64], qi[32][64], kr[32][64], ki[32][64];
  int tid = threadIdx.x;
  int tx = tid & 15, ty = tid >> 4;
  float ar[4][4] = {}, ai[4][4] = {};
  for (int e0 = 0; e0 < 64; e0 += 32) {
    for (int it = 0; it < 8; ++it) {
      int idx = tid + it*256;
      int e = idx >> 6, x = idx & 63;
      size_t rof = ((size_t)b*DD + h*64 + e0 + e)*128;
      qr[e][x] = qf[rof + x]; qi[e][x] = qf[rof + 64 + x];
      kr[e][x] = kf[rof + x]; ki[e][x] = kf[rof + 64 + x];
    }
    __syncthreads();
    for (int e = 0; e < 32; ++e) {
      float xr[4], xi2[4], yr[4], yi[4];
      #pragma unroll
      for (int i = 0; i < 4; ++i) { xr[i] = qr[e][ty*4+i]; xi2[i] = qi[e][ty*4+i]; }
      #pragma unroll
      for (int j = 0; j < 4; ++j) { yr[j] = kr[e][tx*4+j]; yi[j] = ki[e][tx*4+j]; }
      #pragma unroll
      for (int i = 0; i < 4; ++i)
        #pragma unroll
        for (int j = 0; j < 4; ++j) {
          ar[i][j] += xr[i]*yr[j] - xi2[i]*yi[j];
          ai[i][j] += xr[i]*yi[j] + xi2[i]*yr[j];
        }
    }
    __syncthreads();
  }
  #pragma unroll
  for (int i = 0; i < 4; ++i)
    #pragma unroll
    for (int j = 0; j < 4; ++j) {
      float txv = tanhf(ar[i][j]);
      float tyv = tanf(ai[i][j]);
      float den = 1.f + txv*txv*tyv*tyv;
      float re = txv*(1.f + tyv*tyv) / den;
      float im = tyv*(1.f - txv*txv) / den;
      size_t of = ((size_t)bh*64 + (ty*4+i))*128 + tx*4 + j;
      ab[of] = re; ab[of + 64] = im;
    }
}

__global__ __launch_bounds__(256)
void k_cross_v(const float* __restrict__ ab, const float* __restrict__ kf,
               float* __restrict__ v)
{
  int bh = blockIdx.x; int b = bh >> 3, h = bh & 7;
  __shared__ float ar[64][32], ai[64][32], kr[64][32], ki[64][32];
  int tid = threadIdx.x;
  int tx = tid & 15, ty = tid >> 4;
  float vr[4][4] = {}, vi[4][4] = {};
  for (int y0 = 0; y0 < 64; y0 += 32) {
    for (int it = 0; it < 8; ++it) {
      int idx = tid + it*256;
      int r = idx >> 5, y = idx & 31;
      ar[r][y] = ab[((size_t)bh*64 + r)*128 + y0 + y];
      ai[r][y] = ab[((size_t)bh*64 + r)*128 + 64 + y0 + y];
      kr[r][y] = kf[((size_t)b*DD + h*64 + r)*128 + y0 + y];
      ki[r][y] = kf[((size_t)b*DD + h*64 + r)*128 + 64 + y0 + y];
    }
    __syncthreads();
    for (int y = 0; y < 32; ++y) {
      float er[4], ei[4], xr[4], xi2[4];
      #pragma unroll
      for (int i = 0; i < 4; ++i) { er[i] = kr[ty*4+i][y]; ei[i] = ki[ty*4+i][y]; }
      #pragma unroll
      for (int j = 0; j < 4; ++j) { xr[j] = ar[tx*4+j][y]; xi2[j] = ai[tx*4+j][y]; }
      #pragma unroll
      for (int i = 0; i < 4; ++i)
        #pragma unroll
        for (int j = 0; j < 4; ++j) {
          vr[i][j] += xr[j]*er[i] - xi2[j]*ei[i];
          vi[i][j] += xr[j]*ei[i] + xi2[j]*er[i];
        }
    }
    __syncthreads();
  }
  #pragma unroll
  for (int i = 0; i < 4; ++i)
    #pragma unroll
    for (int j = 0; j < 4; ++j) {
      size_t of = ((size_t)b*DD + h*64 + ty*4 + i)*128 + tx*4 + j;
      v[of] = vr[i][j]; v[of + 64] = vi[i][j];
    }
}

// ---------------- LN + column-mean subtract ----------------
__global__ __launch_bounds__(256)
void k_ln(const float* __restrict__ x, const float* __restrict__ g,
          const float* __restrict__ be, float* __restrict__ out)
{
  int r = blockIdx.x; int tid = threadIdx.x;
  float v1 = x[(size_t)r*DD + tid], v2 = x[(size_t)r*DD + 256 + tid];
  float s = v1 + v2, s2 = v1*v1 + v2*v2;
  #pragma unroll
  for (int off = 32; off; off >>= 1) { s += __shfl_down(s, off, 64); s2 += __shfl_down(s2, off, 64); }
  __shared__ float red[8];
  int wid = tid >> 6, lane = tid & 63;
  if (lane == 0) { red[wid] = s; red[4 + wid] = s2; }
  __syncthreads();
  if (tid == 0) {
    float a = red[0]+red[1]+red[2]+red[3];
    float b2 = red[4]+red[5]+red[6]+red[7];
    float mu = a / 512.f;
    float var = b2 / 512.f - mu*mu;
    red[0] = mu; red[1] = rsqrtf(var + 1e-5f);
  }
  __syncthreads();
  float mu = red[0], inv = red[1];
  out[(size_t)r*DD + tid]       = (v1 - mu)*inv*g[tid]       + be[tid];
  out[(size_t)r*DD + 256 + tid] = (v2 - mu)*inv*g[256 + tid] + be[256 + tid];
}

// column-mean subtract, parallel deterministic tree
__global__ void k_colsum_part(const float* __restrict__ x, float* __restrict__ part,
                              int L, int chl, int nch) {
  int d = threadIdx.x;            // 512
  int b = blockIdx.x, c = blockIdx.y;
  int l0 = c*chl, l1 = l0 + chl; if (l1 > L) l1 = L;
  float s = 0.f;
  for (int l = l0; l < l1; ++l) s += x[(((size_t)b*L + l) << 9) + d];
  part[((size_t)(b*nch + c) << 9) + d] = s;
}
__global__ void k_colsum_fin(const float* __restrict__ part, float* __restrict__ cm,
                             int nch, float inv) {
  int i = blockIdx.x*256 + threadIdx.x;   // b*512+d (8192)
  int b = i >> 9, d = i & 511;
  float s = 0.f;
  for (int c = 0; c < nch; ++c) s += part[((size_t)(b*nch + c) << 9) + d];
  cm[i] = s * inv;
}
__global__ void k_csub(float* __restrict__ x, const float* __restrict__ cm, int L) {
  size_t idx = (size_t)blockIdx.x*256 + threadIdx.x;
  if (idx >= (size_t)BB*L*DD) return;
  int d = (int)(idx & 511);
  int b = (int)((idx >> 9) / (size_t)L);
  x[idx] -= cm[(b << 9) | d];
}

// ---------------- series decomp (window 25, edge-clamped) ----------------
template<int ACC>
__global__ void k_decomp(const float* __restrict__ x, float* __restrict__ out,
                         float* __restrict__ tsum, int L)
{
  size_t idx = (size_t)blockIdx.x * 256 + threadIdx.x;
  size_t total = (size_t)BB * L * DD;
  if (idx >= total) return;
  int d = idx & 511;
  size_t rl = idx >> 9;
  int l = (int)(rl % L); int b = (int)(rl / L);
  float s = 0.f;
  for (int j = -12; j <= 12; ++j) {
    int lc = l + j; lc = lc < 0 ? 0 : (lc >= L ? L-1 : lc);
    s += x[(((size_t)b*L + lc) << 9) + d];
  }
  float ma = s * (1.f/25.f);
  out[idx] = x[idx] - ma;
  if (ACC) tsum[idx] += ma;
}

// ---------------- final ----------------
__global__ void k_final(const float* __restrict__ trend, const float* __restrict__ seas,
                        float* __restrict__ out) {
  int idx = blockIdx.x*256 + threadIdx.x;
  if (idx >= BB*LEN_E*NV) return;
  int n = idx % NV; int r = idx / NV; int t = r % LEN_E; int b = r / LEN_E;
  size_t src = ((size_t)b*LEN_D + 360 + t)*NV + n;
  out[idx] = trend[src] + seas[src];
}

// =====================================================================
extern "C" void kernel_launch(void* const* d_in, const int* in_sizes, int n_in,
                              void* d_out, int out_size, void* d_ws, size_t ws_size,
                              hipStream_t stream)
{
  (void)in_sizes; (void)n_in; (void)out_size;
  const float* history = (const float*)d_in[0];
  const float* future  = (const float*)d_in[1];
  const float* Wv_enc  = (const float*)d_in[2];
  const float* Wt_enc  = (const float*)d_in[3];
  const float* Wv_dec  = (const float*)d_in[4];
  const float* Wt_dec  = (const float*)d_in[5];
  const float* eWq = (const float*)d_in[6];
  const float* ebq = (const float*)d_in[7];
  const float* efr = (const float*)d_in[8];
  const float* efi = (const float*)d_in[9];
  const float* eWo = (const float*)d_in[10];
  const float* ebo = (const float*)d_in[11];
  const float* eW1 = (const float*)d_in[12];
  const float* eW2 = (const float*)d_in[13];
  const float* g_enc = (const float*)d_in[14];
  const float* b_enc = (const float*)d_in[15];
  const float* dWq = (const float*)d_in[16];
  const float* dbq = (const float*)d_in[17];
  const float* dfr = (const float*)d_in[18];
  const float* dfi = (const float*)d_in[19];
  const float* dWo = (const float*)d_in[20];
  const float* dbo = (const float*)d_in[21];
  const float* cWq = (const float*)d_in[22];
  const float* cbq = (const float*)d_in[23];
  const float* cWk = (const float*)d_in[24];
  const float* cbk = (const float*)d_in[25];
  const float* cfr = (const float*)d_in[26];
  const float* cfi = (const float*)d_in[27];
  const float* cWo = (const float*)d_in[28];
  const float* cbo = (const float*)d_in[29];
  const float* dW1 = (const float*)d_in[30];
  const float* dW2 = (const float*)d_in[31];
  const float* Wtr = (const float*)d_in[32];
  const float* g_dec = (const float*)d_in[33];
  const float* b_dec = (const float*)d_in[34];
  const float* Wp  = (const float*)d_in[35];
  const float* bp  = (const float*)d_in[36];

  float* ws = (float*)d_ws;
  size_t off = 0;
  auto alloc = [&](size_t n) { float* p = ws + off; off += (n + 63) & ~(size_t)63; return p; };

  const size_t SL = 1048576;

  // FFN chunk: big plan needs ~281 MB of workspace; pick at runtime.
  const int CH = (ws_size >= (size_t)300*1024*1024) ? 8640 : 4320;
  size_t Rsz = (size_t)CH*2560 + 1024;
  if (Rsz < 11600000) Rsz = 11600000;

  // persistent fp32
  float* btrend = alloc((size_t)BB*LEN_D*NV);
  float* bTsum  = alloc((size_t)BB*LEN_D*DD);
  float* bX     = alloc((size_t)BB*LEN_D*DD);
  float* bT     = alloc((size_t)BB*LEN_D*DD);
  float* bencout= alloc((size_t)BB*LEN_E*DD);
  float* bseas  = alloc((size_t)BB*LEN_D*NV);
  float* bseasF = bseas;
  // rotating split / fp32-scratch region
  float* R      = alloc(Rsz);
  // weight-split scratch (two 1M-float pairs)
  float* SB     = alloc((size_t)2*SL + 128);
  // persistent small weight splits
  float* WceS   = alloc((size_t)512*992);
  float* WcdS   = alloc((size_t)512*992);
  float* WtrcS  = alloc((size_t)321*1536);
  float* D720S  = alloc((size_t)128*736);
  float* D1080S = alloc((size_t)128*1088);
  float* I720S  = alloc((size_t)736*128);
  float* I1080S = alloc((size_t)1088*128);
  float* bxme   = alloc((size_t)BB*LEN_E*4);
  float* bxmd   = alloc((size_t)BB*LEN_D*4);
  float* bmean  = alloc((size_t)BB*NV);
  float* bpart  = alloc((size_t)BB*9*DD);
  float* bcm    = alloc((size_t)BB*DD);
  float* bmsp   = alloc((size_t)BB*10*NV);

  float* bxe = bT;   // bxe aliases bT during prep (dead before encoder writes T)

  // pair helpers
  auto H = [](float* base) { return (u16*)base; };
  auto Lo = [](float* base, size_t M, size_t Kp) { return (u16*)base + M*Kp; };

  auto splitP = [&](const float* src, float* dst, int M, int K, int Kp) {
    dim3 g((Kp + 255)/256, M);
    k_split_plain<<<g,256,0,stream>>>(src, H(dst), Lo(dst, M, Kp), K, Kp);
  };
  auto splitC = [&](const float* src, float* dst, int r0, int Mc, int Lc, int Din, int K, int Kp) {
    dim3 g((Kp + 255)/256, Mc);
    k_split_conv<<<g,256,0,stream>>>(src, H(dst), Lo(dst, Mc, Kp), r0, Lc, Din, K, Kp);
  };
  auto splitT = [&](const float* src, float* dst, int Lc, int Kp) {
    dim3 g(Kp/32, 16, BB), b(32, 8);
    k_split_tr<<<g,b,0,stream>>>(src, H(dst), Lo(dst, (size_t)BB*DD, Kp), Lc, Kp);
  };

  auto mg128 = [&](int epi, float* A, size_t Ma, float* B, size_t Nb,
                   const float* bias, const float* res, float* C,
                   int M, int N, int K) {
    dim3 g((N + 127)/128, (M + 127)/128);
    u16 *ah = H(A), *al = Lo(A, Ma, K), *bh = H(B), *bl = Lo(B, Nb, K);
    switch (epi) {
      case 0: k_mg<128,0,0><<<g,256,0,stream>>>(ah,al,bh,bl,bias,res,C,nullptr,nullptr,M,N,K); break;
      case 1: k_mg<128,1,0><<<g,256,0,stream>>>(ah,al,bh,bl,bias,res,C,nullptr,nullptr,M,N,K); break;
      case 3: k_mg<128,3,0><<<g,256,0,stream>>>(ah,al,bh,bl,bias,res,C,nullptr,nullptr,M,N,K); break;
    }
  };
  auto mg128s = [&](float* A, size_t Ma, float* B, size_t Nb, float* Cs,
                    int M, int N, int K) {   // gelu + split-out
    dim3 g((N + 127)/128, (M + 127)/128);
    k_mg<128,4,1><<<g,256,0,stream>>>(H(A), Lo(A, Ma, K), H(B), Lo(B, Nb, K),
                                      nullptr, nullptr, nullptr,
                                      H(Cs), Lo(Cs, M, N), M, N, K);
  };
  auto mg64 = [&](int epi, float* A, size_t Ma, float* B, size_t Nb,
                  const float* bias, const float* res, float* C,
                  int M, int N, int K) {
    dim3 g((N + 63)/64, (M + 127)/128);
    u16 *ah = H(A), *al = Lo(A, Ma, K), *bh = H(B), *bl = Lo(B, Nb, K);
    switch (epi) {
      case 0: k_mg<64,0,0><<<g,256,0,stream>>>(ah,al,bh,bl,bias,res,C,nullptr,nullptr,M,N,K); break;
      case 1: k_mg<64,1,0><<<g,256,0,stream>>>(ah,al,bh,bl,bias,res,C,nullptr,nullptr,M,N,K); break;
      case 2: k_mg<64,2,0><<<g,256,0,stream>>>(ah,al,bh,bl,bias,res,C,nullptr,nullptr,M,N,K); break;
    }
  };

  auto decomp = [&](const float* in, float* out, int L, bool acc) {
    size_t tot = (size_t)BB * L * DD;
    int g = (int)((tot + 255)/256);
    if (acc) k_decomp<1><<<g,256,0,stream>>>(in, out, bTsum, L);
    else     k_decomp<0><<<g,256,0,stream>>>(in, out, nullptr, L);
  };

  // FFN: out = in + gelu(in@W1.T)@W2.T, chunked
  float* SA2 = R + ((size_t)CH*512 + 256);
  auto ffn = [&](const float* in, float* out, const float* W1, const float* W2, int M) {
    splitP(W1, SB, DFF2, DD, DD);
    splitP(W2, SB + SL, DD, DFF2, DFF2);
    for (int r0 = 0; r0 < M; r0 += CH) {
      int mc = M - r0; if (mc > CH) mc = CH;
      splitP(in + (size_t)r0*DD, R, mc, DD, DD);
      mg128s(R, mc, SB, DFF2, SA2, mc, DFF2, DD);
      mg64(2, SA2, mc, SB + SL, DD, nullptr, in + (size_t)r0*DD,
           out + (size_t)r0*DD, mc, DD, DFF2);
    }
  };

  // X += fourier_self(X); T scratch
  auto fourier_self = [&](float* X, float* T, int L, int KpL, float* DLS, float* ILS,
                          const float* Wq, const float* bq, const float* fr, const float* fi,
                          const float* Wo, const float* bo) {
    int M = BB * L;
    float* bqf  = R + 9*SL;
    float* bsel = R + 10*SL;
    splitP(X, R, M, DD, DD);
    splitP(Wq, SB, DD, DD, DD);
    mg128(1, R, M, SB, DD, bq, nullptr, T, M, DD, DD);
    splitT(T, R, L, KpL);
    mg64(0, R, (size_t)BB*DD, DLS, 128, nullptr, nullptr, bqf, BB*DD, 128, KpL);
    k_modemix<<<dim3(64,8),256,0,stream>>>(bqf, fr, fi, bsel, 1.0f);
    splitP(bsel, R, BB*DD, 128, 128);
    mg128(0, R, (size_t)BB*DD, ILS, L, nullptr, nullptr, T, BB*DD, L, 128);
    splitP(T, R, M, DD, DD);
    splitP(Wo, SB, DD, DD, DD);
    mg128(3, R, M, SB, DD, bo, X, X, M, DD, DD);
  };

  auto myln = [&](const float* in, float* out, const float* g, const float* b, int L) {
    k_ln<<<BB*L,256,0,stream>>>(in, g, b, out);
    int chl = L / 9;
    k_colsum_part<<<dim3(BB,9),512,0,stream>>>(out, bpart, L, chl, 9);
    k_colsum_fin<<<32,256,0,stream>>>(bpart, bcm, 9, 1.f/(float)L);
    k_csub<<<(int)(((size_t)BB*L*DD + 255)/256),256,0,stream>>>(out, bcm, L);
  };

  // ---------------- prep ----------------
  k_extract_x<<<(BB*LEN_E*NV + 255)/256,256,0,stream>>>(history, bxe);
  k_marks_enc<<<(BB*LEN_E*4 + 255)/256,256,0,stream>>>(history, bxme);
  k_marks_dec<<<(BB*LEN_D*4 + 255)/256,256,0,stream>>>(future, bxme, bxmd);
  k_ms_part<<<dim3(BB,10),384,0,stream>>>(bxe, bmsp, 72, 10);
  k_ms_fin<<<(BB*NV + 255)/256,256,0,stream>>>(bmsp, bmean, 10);
  k_init_decomp<<<(BB*LEN_D*NV + 255)/256,256,0,stream>>>(bxe, bmean, bseas, btrend);
  k_build_wconvS<<<dim3(4,512),256,0,stream>>>(Wv_enc, H(WceS), Lo(WceS, 512, 992));
  k_build_wconvS<<<dim3(4,512),256,0,stream>>>(Wv_dec, H(WcdS), Lo(WcdS, 512, 992));
  k_build_wtrcS<<<dim3(6,321),256,0,stream>>>(Wtr, H(WtrcS), Lo(WtrcS, 321, 1536));
  k_build_dftS<<<dim3(3,128),256,0,stream>>>(H(D720S), Lo(D720S, 128, 736), LEN_E, 736);
  k_build_dftS<<<dim3(5,128),256,0,stream>>>(H(D1080S), Lo(D1080S, 128, 1088), LEN_D, 1088);
  k_build_irS<<<dim3(1,LEN_E),128,0,stream>>>(H(I720S), Lo(I720S, LEN_E, 128), LEN_E);
  k_build_irS<<<dim3(1,LEN_D),128,0,stream>>>(H(I1080S), Lo(I1080S, LEN_D, 128), LEN_D);

  // ---------------- encoder ----------------
  int ME = BB * LEN_E;
  for (int r0 = 0; r0 < ME; r0 += 5760) {
    splitC(bxe, R, r0, 5760, LEN_E, NV, 963, 992);
    mg128(0, R, 5760, WceS, DD, nullptr, nullptr, bX + (size_t)r0*DD, 5760, DD, 992);
  }
  k_marks_add<<<(ME*DD + 255)/256,256,0,stream>>>(bX, bxme, Wt_enc, ME);

  float *X = bX, *T = bT;
  for (int i = 0; i < 2; ++i) {
    fourier_self(X, T, LEN_E, 736, D720S, I720S,
                 eWq + (size_t)i*DD*DD, ebq + (size_t)i*DD,
                 efr + (size_t)i*HHN*64*64*64, efi + (size_t)i*HHN*64*64*64,
                 eWo + (size_t)i*DD*DD, ebo + (size_t)i*DD);
    decomp(X, T, LEN_E, false);
    ffn(T, X, eW1 + (size_t)i*DFF2*DD, eW2 + (size_t)i*DD*DFF2, ME);
    decomp(X, T, LEN_E, false);
    { float* tmp = X; X = T; T = tmp; }
  }
  myln(X, bencout, g_enc, b_enc, LEN_E);

  // ---------------- decoder ----------------
  int MD = BB * LEN_D;
  for (int r0 = 0; r0 < MD; r0 += 8640) {
    splitC(bseas, R, r0, 8640, LEN_D, NV, 963, 992);
    mg128(0, R, 8640, WcdS, DD, nullptr, nullptr, X + (size_t)r0*DD, 8640, DD, 992);
  }
  k_marks_add<<<(MD*DD + 255)/256,256,0,stream>>>(X, bxmd, Wt_dec, MD);

  fourier_self(X, T, LEN_D, 1088, D1080S, I1080S, dWq, dbq, dfr, dfi, dWo, dbo);

  k_zero<<<(BB*LEN_D*DD + 255)/256,256,0,stream>>>(bTsum, BB*LEN_D*DD);
  decomp(X, T, LEN_D, true);          // x -> T, t1 acc

  // cross attention
  {
    float* bkf  = R + 9*SL;
    float* bqf  = R + 10*SL;
    splitP(bencout, R, ME, DD, DD);
    splitP(cWk, SB, DD, DD, DD);
    mg128(1, R, ME, SB, DD, cbk, nullptr, X, ME, DD, DD);
    splitT(X, R, LEN_E, 736);
    mg64(0, R, (size_t)BB*DD, D720S, 128, nullptr, nullptr, bkf, BB*DD, 128, 736);
    splitP(T, R, MD, DD, DD);
    splitP(cWq, SB, DD, DD, DD);
    mg128(1, R, MD, SB, DD, cbq, nullptr, X, MD, DD, DD);
    splitT(X, R, LEN_D, 1088);
    mg64(0, R, (size_t)BB*DD, D1080S, 128, nullptr, nullptr, bqf, BB*DD, 128, 1088);
    float* ba   = R;
    float* bv   = R + SL;
    float* bsel = R + 2*SL;
    float* bss  = R + 3*SL;
    k_cross_qk<<<BB*HHN,256,0,stream>>>(bqf, bkf, ba);
    k_cross_v<<<BB*HHN,256,0,stream>>>(ba, bkf, bv);
    k_modemix<<<dim3(64,8),256,0,stream>>>(bv, cfr, cfi, bsel, 1.0f/262144.0f);
    splitP(bsel, bss, BB*DD, 128, 128);
    mg128(0, bss, (size_t)BB*DD, I1080S, LEN_D, nullptr, nullptr, X, BB*DD, LEN_D, 128);
    splitP(X, R, MD, DD, DD);
    splitP(cWo, SB, DD, DD, DD);
    mg128(3, R, MD, SB, DD, cbo, T, T, MD, DD, DD);
  }

  decomp(T, X, LEN_D, true);          // x -> X, t2 acc
  ffn(X, T, dW1, dW2, MD);            // T = x + FFN(x)
  decomp(T, X, LEN_D, true);          // x -> X, t3 acc

  myln(X, T, g_dec, b_dec, LEN_D);
  splitP(T, R, MD, DD, DD);
  splitP(Wp, SB, NV, DD, DD);
  mg64(1, R, MD, SB, NV, bp, nullptr, bseasF, MD, NV, DD);

  for (int r0 = 0; r0 < MD; r0 += 5760) {
    splitC(bTsum, R, r0, 5760, LEN_D, DD, 1536, 1536);
    mg64(2, R, 5760, WtrcS, NV, nullptr, btrend + (size_t)r0*NV,
         btrend + (size_t)r0*NV, 5760, NV, 1536);
  }

  k_final<<<(BB*LEN_E*NV + 255)/256,256,0,stream>>>(btrend, bseasF, (float*)d_out);
}

// Round 8
// 3167.993 us; speedup vs baseline: 4.4961x; 1.0798x over previous
//
#include <hip/hip_runtime.h>
#include <math.h>

#define BB 16
#define DD 512
#define HHN 8
#define LEN_E 720
#define LEN_D 1080
#define NV 321
#define DFF2 2048

typedef __attribute__((ext_vector_type(8))) short short8;
typedef __attribute__((ext_vector_type(4))) float floatx4;
typedef unsigned short u16;

__device__ __forceinline__ u16 f2bf(float v) {
  unsigned u = __builtin_bit_cast(unsigned, v);
  u += 0x7FFFu + ((u >> 16) & 1u);
  return (u16)(u >> 16);
}
__device__ __forceinline__ float bf2f(u16 h) {
  unsigned u = ((unsigned)h) << 16;
  return __builtin_bit_cast(float, u);
}

// ---------------- prep kernels ----------------
__global__ void k_extract_x(const float* __restrict__ hist, float* __restrict__ xe) {
  int idx = blockIdx.x * 256 + threadIdx.x;
  if (idx >= BB*LEN_E*NV) return;
  xe[idx] = hist[(size_t)idx * 5];
}

__global__ void k_marks_enc(const float* __restrict__ hist, float* __restrict__ xme) {
  int idx = blockIdx.x * 256 + threadIdx.x;
  if (idx >= BB*LEN_E*4) return;
  int f = idx & 3;
  int r = idx >> 2;
  xme[idx] = hist[((size_t)r * NV) * 5 + 1 + f];
}

__global__ void k_marks_dec(const float* __restrict__ fut, const float* __restrict__ xme,
                            float* __restrict__ xmd) {
  int idx = blockIdx.x * 256 + threadIdx.x;
  if (idx >= BB*LEN_D*4) return;
  int f = idx & 3;
  int r = idx >> 2;
  int t = r % LEN_D, b = r / LEN_D;
  float v;
  if (t < 360) v = xme[((b*LEN_E) + 360 + t)*4 + f];
  else v = fut[(((size_t)(b*LEN_E + (t-360))) * NV) * 5 + 1 + f];
  xmd[idx] = v;
}

__global__ void k_ms_part(const float* __restrict__ xe, float* __restrict__ part,
                          int chl, int nch) {
  int n = threadIdx.x;
  if (n >= NV) return;
  int b = blockIdx.x, c = blockIdx.y;
  int l0 = c*chl, l1 = l0 + chl; if (l1 > LEN_E) l1 = LEN_E;
  float s = 0.f;
  for (int l = l0; l < l1; ++l) s += xe[((size_t)b*LEN_E + l)*NV + n];
  part[((size_t)b*nch + c)*NV + n] = s;
}
__global__ void k_ms_fin(const float* __restrict__ part, float* __restrict__ mb, int nch) {
  int i = blockIdx.x*256 + threadIdx.x;
  if (i >= BB*NV) return;
  int b = i / NV, n = i % NV;
  float s = 0.f;
  for (int c = 0; c < nch; ++c) s += part[((size_t)b*nch + c)*NV + n];
  mb[i] = s * (1.f/(float)LEN_E);
}

__global__ void k_init_decomp(const float* __restrict__ xe, const float* __restrict__ mb,
                              float* __restrict__ seas, float* __restrict__ trend) {
  int idx = blockIdx.x * 256 + threadIdx.x;
  if (idx >= BB*LEN_D*NV) return;
  int n = idx % NV; int r = idx / NV; int t = r % LEN_D; int b = r / LEN_D;
  if (t < 360) {
    int l = 360 + t;
    float s = 0.f;
    for (int j = -12; j <= 12; ++j) {
      int lc = l + j; if (lc > LEN_E-1) lc = LEN_E-1; if (lc < 0) lc = 0;
      s += xe[((size_t)b*LEN_E + lc)*NV + n];
    }
    float ma = s * (1.f/25.f);
    trend[idx] = ma;
    seas[idx]  = xe[((size_t)b*LEN_E + l)*NV + n] - ma;
  } else {
    trend[idx] = mb[b*NV + n];
    seas[idx]  = 0.f;
  }
}

__global__ void k_zero(float* __restrict__ p, int n) {
  int i = blockIdx.x*256 + threadIdx.x;
  if (i < n) p[i] = 0.f;
}

__global__ void k_marks_add(float* __restrict__ X, const float* __restrict__ xm,
                            const float* __restrict__ Wt, int M) {
  int idx = blockIdx.x*256 + threadIdx.x;
  if (idx >= M*DD) return;
  int d = idx & 511, r = idx >> 9;
  const float* m4 = xm + (size_t)r*4;
  const float* w4 = Wt + (size_t)d*4;
  X[idx] += m4[0]*w4[0] + m4[1]*w4[1] + m4[2]*w4[2] + m4[3]*w4[3];
}

// ---------------- split builders ----------------
__global__ void k_split_plain(const float* __restrict__ src, u16* __restrict__ h,
                              u16* __restrict__ l, int K, int Kp) {
  int col = blockIdx.x*256 + threadIdx.x;
  if (col >= Kp) return;
  int r = blockIdx.y;
  float v = (col < K) ? src[(size_t)r*K + col] : 0.f;
  u16 hh = f2bf(v);
  size_t o = (size_t)r*Kp + col;
  h[o] = hh; l[o] = f2bf(v - bf2f(hh));
}

__global__ void k_split_conv(const float* __restrict__ src, u16* __restrict__ h,
                             u16* __restrict__ l, int r0, int Lc, int Din,
                             int K, int Kp) {
  int col = blockIdx.x*256 + threadIdx.x;
  if (col >= Kp) return;
  int rr = blockIdx.y;
  int r = r0 + rr;
  int b = r / Lc, t = r - b*Lc;
  float v = 0.f;
  if (col < K) {
    int c = (col >= 2*Din) ? 2 : ((col >= Din) ? 1 : 0);
    int n = col - c*Din;
    int tt = t + c - 1;
    if (tt < 0) tt = Lc - 1; else if (tt >= Lc) tt = 0;
    v = src[((size_t)(b*Lc + tt))*Din + n];
  }
  u16 hh = f2bf(v);
  size_t o = (size_t)rr*Kp + col;
  h[o] = hh; l[o] = f2bf(v - bf2f(hh));
}

__global__ void k_split_tr(const float* __restrict__ src, u16* __restrict__ h,
                           u16* __restrict__ l, int Lc, int Kp) {
  __shared__ float t[32][33];
  int b = blockIdx.z;
  int l0 = blockIdx.x*32, c0 = blockIdx.y*32;
  int lx = threadIdx.x, ly = threadIdx.y;   // (32,8)
  #pragma unroll
  for (int i = 0; i < 4; ++i) {
    int ll = l0 + ly + i*8;
    t[ly + i*8][lx] = (ll < Lc) ? src[((size_t)b*Lc + ll)*DD + c0 + lx] : 0.f;
  }
  __syncthreads();
  #pragma unroll
  for (int i = 0; i < 4; ++i) {
    int ch = c0 + ly + i*8;
    int ll = l0 + lx;
    float v = t[lx][ly + i*8];
    u16 hh = f2bf(v);
    size_t o = ((size_t)b*DD + ch)*Kp + ll;
    h[o] = hh; l[o] = f2bf(v - bf2f(hh));
  }
}

__global__ void k_build_wconvS(const float* __restrict__ Wv, u16* __restrict__ h,
                               u16* __restrict__ l) {
  int col = blockIdx.x*256 + threadIdx.x;
  if (col >= 992) return;
  int d = blockIdx.y;
  float v = 0.f;
  if (col < 963) {
    int c = (col >= 642) ? 2 : ((col >= 321) ? 1 : 0);
    int n = col - c*321;
    v = Wv[(size_t)d*963 + n*3 + c];
  }
  u16 hh = f2bf(v);
  size_t o = (size_t)d*992 + col;
  h[o] = hh; l[o] = f2bf(v - bf2f(hh));
}

__global__ void k_build_wtrcS(const float* __restrict__ Wtr, u16* __restrict__ h,
                              u16* __restrict__ l) {
  int col = blockIdx.x*256 + threadIdx.x;
  if (col >= 1536) return;
  int n = blockIdx.y;
  int c = col >> 9, d = col & 511;
  float v = Wtr[(size_t)n*1536 + d*3 + c];
  u16 hh = f2bf(v);
  size_t o = (size_t)n*1536 + col;
  h[o] = hh; l[o] = f2bf(v - bf2f(hh));
}

__global__ void k_build_dftS(u16* __restrict__ h, u16* __restrict__ l, int L, int Kp) {
  int col = blockIdx.x*256 + threadIdx.x;
  if (col >= Kp) return;
  int mr = blockIdx.y;
  float v = 0.f;
  if (col < L) {
    int m = mr & 63;
    int ph = (m * col) % L;
    float th = 6.2831853071795864f * ((float)ph / (float)L);
    v = (mr < 64) ? cosf(th) : -sinf(th);
  }
  u16 hh = f2bf(v);
  size_t o = (size_t)mr*Kp + col;
  h[o] = hh; l[o] = f2bf(v - bf2f(hh));
}

__global__ void k_build_irS(u16* __restrict__ h, u16* __restrict__ l, int L) {
  int k = threadIdx.x;   // 0..127
  int ll = blockIdx.y;
  int m = k & 63;
  int ph = (m * ll) % L;
  float th = 6.2831853071795864f * ((float)ph / (float)L);
  float v;
  if (k < 64) v = (m == 0) ? (1.f/(float)L) : (2.f/(float)L) * cosf(th);
  else        v = (m == 0) ? 0.f            : -(2.f/(float)L) * sinf(th);
  u16 hh = f2bf(v);
  size_t o = (size_t)ll*128 + k;
  h[o] = hh; l[o] = f2bf(v - bf2f(hh));
}

// ---------------- MFMA GEMM on pre-split bf16 hi/lo ----------------
// KS>1: split-K over blockIdx.z, writes raw fp32 partials to C + z*M*Nc.
template<int TN, int EPI, int WOUT, int KS>
__global__ __launch_bounds__(256)
void k_mg(const u16* __restrict__ Ah, const u16* __restrict__ Al,
          const u16* __restrict__ Bh, const u16* __restrict__ Bl,
          const float* __restrict__ bias, const float* __restrict__ res,
          float* __restrict__ C, u16* __restrict__ Ch, u16* __restrict__ Cl,
          int M, int Nc, int K)
{
  __shared__ short sAh[128][40];
  __shared__ short sAl[128][40];
  __shared__ short sBh[TN][40];
  __shared__ short sBl[TN][40];

  const int tid  = threadIdx.x;
  const int lane = tid & 63;
  const int wave = tid >> 6;
  const int lr   = lane & 15;
  const int kg   = lane >> 4;

  const int gx  = gridDim.x;
  const int nwg = gx * gridDim.y;
  const int lid = blockIdx.y * gx + blockIdx.x;
  const int q8  = nwg >> 3, r8 = nwg & 7;
  const int xcd = lid & 7, i8 = lid >> 3;
  const int swz = (xcd < r8 ? xcd*(q8+1) : r8*(q8+1) + (xcd - r8)*q8) + i8;
  const int row0 = (swz / gx) * 128;
  const int col0 = (swz % gx) * TN;

  const int srow = tid >> 1;
  const int kh   = (tid & 1) * 16;
  const int ar   = row0 + srow;

  constexpr int MF = (TN == 128) ? 4 : 2;
  const int wr = (TN == 128) ? (wave >> 1) : wave;
  const int wc = (TN == 128) ? (wave & 1) : 0;

  floatx4 acc[MF][4] = {};

  const bool aok  = (ar < M);
  const int  brow = col0 + srow;
  const bool bact = (TN == 128) || (tid < 128);
  const bool bok  = bact && (brow < Nc);

  const int zz = (KS > 1) ? (int)blockIdx.z : 0;
  const int steps = K >> 5;
  const int s0 = (KS > 1) ? (int)(((long long)steps * zz) / KS) : 0;
  const int s1 = (KS > 1) ? (int)(((long long)steps * (zz + 1)) / KS) : steps;

  short8 pa0{}, pa1{}, pal0{}, pal1{}, pb0{}, pb1{}, pbl0{}, pbl1{};
  {
    const int kb = s0*32 + kh;
    if (aok) {
      const u16* pa = Ah + (size_t)ar*K + kb;
      const u16* pl = Al + (size_t)ar*K + kb;
      pa0 = *(const short8*)pa;  pa1 = *(const short8*)(pa + 8);
      pal0 = *(const short8*)pl; pal1 = *(const short8*)(pl + 8);
    }
    if (bok) {
      const u16* pb = Bh + (size_t)brow*K + kb;
      const u16* pl = Bl + (size_t)brow*K + kb;
      pb0 = *(const short8*)pb;  pb1 = *(const short8*)(pb + 8);
      pbl0 = *(const short8*)pl; pbl1 = *(const short8*)(pl + 8);
    }
  }

  for (int ks = s0; ks < s1; ++ks) {
    *(short8*)&sAh[srow][kh]   = pa0;  *(short8*)&sAh[srow][kh+8] = pa1;
    *(short8*)&sAl[srow][kh]   = pal0; *(short8*)&sAl[srow][kh+8] = pal1;
    if (bact) {
      *(short8*)&sBh[srow][kh]   = pb0;  *(short8*)&sBh[srow][kh+8] = pb1;
      *(short8*)&sBl[srow][kh]   = pbl0; *(short8*)&sBl[srow][kh+8] = pbl1;
    }
    __syncthreads();

    if (ks + 1 < s1) {
      const int kb = (ks + 1)*32 + kh;
      if (aok) {
        const u16* pa = Ah + (size_t)ar*K + kb;
        const u16* pl = Al + (size_t)ar*K + kb;
        pa0 = *(const short8*)pa;  pa1 = *(const short8*)(pa + 8);
        pal0 = *(const short8*)pl; pal1 = *(const short8*)(pl + 8);
      }
      if (bok) {
        const u16* pb = Bh + (size_t)brow*K + kb;
        const u16* pl = Bl + (size_t)brow*K + kb;
        pb0 = *(const short8*)pb;  pb1 = *(const short8*)(pb + 8);
        pbl0 = *(const short8*)pl; pbl1 = *(const short8*)(pl + 8);
      }
    }

    short8 ahf[MF], alf[MF], bhf[4], blf[4];
    #pragma unroll
    for (int f = 0; f < MF; ++f) {
      int ra = wr*(MF*16) + f*16 + lr;
      ahf[f] = *(const short8*)&sAh[ra][kg*8];
      alf[f] = *(const short8*)&sAl[ra][kg*8];
    }
    #pragma unroll
    for (int n = 0; n < 4; ++n) {
      int rb = wc*64 + n*16 + lr;
      bhf[n] = *(const short8*)&sBh[rb][kg*8];
      blf[n] = *(const short8*)&sBl[rb][kg*8];
    }
    #pragma unroll
    for (int mf = 0; mf < MF; ++mf)
      #pragma unroll
      for (int nf = 0; nf < 4; ++nf) {
        acc[mf][nf] = __builtin_amdgcn_mfma_f32_16x16x32_bf16(ahf[mf], bhf[nf], acc[mf][nf], 0, 0, 0);
        acc[mf][nf] = __builtin_amdgcn_mfma_f32_16x16x32_bf16(ahf[mf], blf[nf], acc[mf][nf], 0, 0, 0);
        acc[mf][nf] = __builtin_amdgcn_mfma_f32_16x16x32_bf16(alf[mf], bhf[nf], acc[mf][nf], 0, 0, 0);
      }
    __syncthreads();
  }

  if (KS > 1) {
    float* Cp = C + (size_t)zz * ((size_t)M * Nc);
    #pragma unroll
    for (int nf = 0; nf < 4; ++nf) {
      int cN = col0 + wc*64 + nf*16 + lr;
      if (cN >= Nc) continue;
      #pragma unroll
      for (int mf = 0; mf < MF; ++mf)
        #pragma unroll
        for (int i = 0; i < 4; ++i) {
          int rM = row0 + wr*(MF*16) + mf*16 + kg*4 + i;
          if (rM >= M) continue;
          Cp[(size_t)rM * Nc + cN] = acc[mf][nf][i];
        }
    }
  } else {
    #pragma unroll
    for (int nf = 0; nf < 4; ++nf) {
      int cN = col0 + wc*64 + nf*16 + lr;
      if (cN >= Nc) continue;
      #pragma unroll
      for (int mf = 0; mf < MF; ++mf) {
        #pragma unroll
        for (int i = 0; i < 4; ++i) {
          int rM = row0 + wr*(MF*16) + mf*16 + kg*4 + i;
          if (rM >= M) continue;
          float v = acc[mf][nf][i];
          if (EPI & 1) v += bias[cN];
          if (EPI & 4) v = 0.5f * v * (1.f + erff(v * 0.7071067811865476f));
          if (EPI & 2) v += res[(size_t)rM * Nc + cN];
          if (WOUT) {
            u16 hh = f2bf(v);
            size_t o = (size_t)rM * Nc + cN;
            Ch[o] = hh; Cl[o] = f2bf(v - bf2f(hh));
          } else {
            C[(size_t)rM * Nc + cN] = v;
          }
        }
      }
    }
  }
}

// ---------------- split-K reduce (fixed order, deterministic) ----------------
__global__ void k_red(const float* __restrict__ p, int parts, size_t stride,
                      const float* __restrict__ res, float* __restrict__ out, size_t n) {
  size_t i = (size_t)blockIdx.x*256 + threadIdx.x;
  if (i >= n) return;
  float s = res ? res[i] : 0.f;
  for (int z = 0; z < parts; ++z) s += p[(size_t)z*stride + i];
  out[i] = s;
}

// ---------------- mode mix (emits bf16 hi/lo pair) ----------------
__global__ __launch_bounds__(256)
void k_modemix(const float* __restrict__ ftbuf, const float* __restrict__ fr,
               const float* __restrict__ fi, u16* __restrict__ sh,
               u16* __restrict__ sl, float scale)
{
  int m = blockIdx.x, h = blockIdx.y;
  __shared__ float wr[64][64], wi[64][64];
  __shared__ float qr[BB][64], qi[BB][64];
  int tid = threadIdx.x;
  for (int it = 0; it < 16; ++it) {
    int idx = tid + it*256;
    int e = idx >> 6, o = idx & 63;
    size_t wof = ((((size_t)h*64 + e)*64 + o) << 6) + m;
    wr[e][o] = fr[wof]; wi[e][o] = fi[wof];
  }
  for (int it = 0; it < 4; ++it) {
    int idx = tid + it*256;
    int bb = idx >> 6, e = idx & 63;
    size_t qof = ((size_t)bb*DD + h*64 + e)*128 + m;
    qr[bb][e] = ftbuf[qof]; qi[bb][e] = ftbuf[qof + 64];
  }
  __syncthreads();
  for (int it = 0; it < 4; ++it) {
    int idx = tid + it*256;
    int bb = idx >> 6, o = idx & 63;
    float ar = 0.f, ai = 0.f;
    for (int e = 0; e < 64; ++e) {
      float xr = qr[bb][e], xi = qi[bb][e], yr = wr[e][o], yi = wi[e][o];
      ar += xr*yr - xi*yi;
      ai += xr*yi + xi*yr;
    }
    size_t sof = ((size_t)bb*DD + h*64 + o)*128 + m;
    float vr = ar*scale, vi2 = ai*scale;
    u16 hr = f2bf(vr);
    sh[sof] = hr; sl[sof] = f2bf(vr - bf2f(hr));
    u16 hi2 = f2bf(vi2);
    sh[sof + 64] = hi2; sl[sof + 64] = f2bf(vi2 - bf2f(hi2));
  }
}

// ---------------- cross attention ----------------
__global__ __launch_bounds__(256)
void k_cross_qk(const float* __restrict__ qf, const float* __restrict__ kf,
                float* __restrict__ ab)
{
  int bh = blockIdx.x; int b = bh >> 3, h = bh & 7;
  __shared__ float qr[32][64], qi[32][64], kr[32][64], ki[32][64];
  int tid = threadIdx.x;
  int tx = tid & 15, ty = tid >> 4;
  float ar[4][4] = {}, ai[4][4] = {};
  for (int e0 = 0; e0 < 64; e0 += 32) {
    for (int it = 0; it < 8; ++it) {
      int idx = tid + it*256;
      int e = idx >> 6, x = idx & 63;
      size_t rof = ((size_t)b*DD + h*64 + e0 + e)*128;
      qr[e][x] = qf[rof + x]; qi[e][x] = qf[rof + 64 + x];
      kr[e][x] = kf[rof + x]; ki[e][x] = kf[rof + 64 + x];
    }
    __syncthreads();
    for (int e = 0; e < 32; ++e) {
      float xr[4], xi2[4], yr[4], yi[4];
      #pragma unroll
      for (int i = 0; i < 4; ++i) { xr[i] = qr[e][ty*4+i]; xi2[i] = qi[e][ty*4+i]; }
      #pragma unroll
      for (int j = 0; j < 4; ++j) { yr[j] = kr[e][tx*4+j]; yi[j] = ki[e][tx*4+j]; }
      #pragma unroll
      for (int i = 0; i < 4; ++i)
        #pragma unroll
        for (int j = 0; j < 4; ++j) {
          ar[i][j] += xr[i]*yr[j] - xi2[i]*yi[j];
          ai[i][j] += xr[i]*yi[j] + xi2[i]*yr[j];
        }
    }
    __syncthreads();
  }
  #pragma unroll
  for (int i = 0; i < 4; ++i)
    #pragma unroll
    for (int j = 0; j < 4; ++j) {
      float txv = tanhf(ar[i][j]);
      float tyv = tanf(ai[i][j]);
      float den = 1.f + txv*txv*tyv*tyv;
      float re = txv*(1.f + tyv*tyv) / den;
      float im = tyv*(1.f - txv*txv) / den;
      size_t of = ((size_t)bh*64 + (ty*4+i))*128 + tx*4 + j;
      ab[of] = re; ab[of + 64] = im;
    }
}

__global__ __launch_bounds__(256)
void k_cross_v(const float* __restrict__ ab, const float* __restrict__ kf,
               float* __restrict__ v)
{
  int bh = blockIdx.x; int b = bh >> 3, h = bh & 7;
  __shared__ float ar[64][32], ai[64][32], kr[64][32], ki[64][32];
  int tid = threadIdx.x;
  int tx = tid & 15, ty = tid >> 4;
  float vr[4][4] = {}, vi[4][4] = {};
  for (int y0 = 0; y0 < 64; y0 += 32) {
    for (int it = 0; it < 8; ++it) {
      int idx = tid + it*256;
      int r = idx >> 5, y = idx & 31;
      ar[r][y] = ab[((size_t)bh*64 + r)*128 + y0 + y];
      ai[r][y] = ab[((size_t)bh*64 + r)*128 + 64 + y0 + y];
      kr[r][y] = kf[((size_t)b*DD + h*64 + r)*128 + y0 + y];
      ki[r][y] = kf[((size_t)b*DD + h*64 + r)*128 + 64 + y0 + y];
    }
    __syncthreads();
    for (int y = 0; y < 32; ++y) {
      float er[4], ei[4], xr[4], xi2[4];
      #pragma unroll
      for (int i = 0; i < 4; ++i) { er[i] = kr[ty*4+i][y]; ei[i] = ki[ty*4+i][y]; }
      #pragma unroll
      for (int j = 0; j < 4; ++j) { xr[j] = ar[tx*4+j][y]; xi2[j] = ai[tx*4+j][y]; }
      #pragma unroll
      for (int i = 0; i < 4; ++i)
        #pragma unroll
        for (int j = 0; j < 4; ++j) {
          vr[i][j] += xr[j]*er[i] - xi2[j]*ei[i];
          vi[i][j] += xr[j]*ei[i] + xi2[j]*er[i];
        }
    }
    __syncthreads();
  }
  #pragma unroll
  for (int i = 0; i < 4; ++i)
    #pragma unroll
    for (int j = 0; j < 4; ++j) {
      size_t of = ((size_t)b*DD + h*64 + ty*4 + i)*128 + tx*4 + j;
      v[of] = vr[i][j]; v[of + 64] = vi[i][j];
    }
}

// ---------------- LN + column-mean subtract ----------------
__global__ __launch_bounds__(256)
void k_ln(const float* __restrict__ x, const float* __restrict__ g,
          const float* __restrict__ be, float* __restrict__ out)
{
  int r = blockIdx.x; int tid = threadIdx.x;
  float v1 = x[(size_t)r*DD + tid], v2 = x[(size_t)r*DD + 256 + tid];
  float s = v1 + v2, s2 = v1*v1 + v2*v2;
  #pragma unroll
  for (int off = 32; off; off >>= 1) { s += __shfl_down(s, off, 64); s2 += __shfl_down(s2, off, 64); }
  __shared__ float red[8];
  int wid = tid >> 6, lane = tid & 63;
  if (lane == 0) { red[wid] = s; red[4 + wid] = s2; }
  __syncthreads();
  if (tid == 0) {
    float a = red[0]+red[1]+red[2]+red[3];
    float b2 = red[4]+red[5]+red[6]+red[7];
    float mu = a / 512.f;
    float var = b2 / 512.f - mu*mu;
    red[0] = mu; red[1] = rsqrtf(var + 1e-5f);
  }
  __syncthreads();
  float mu = red[0], inv = red[1];
  out[(size_t)r*DD + tid]       = (v1 - mu)*inv*g[tid]       + be[tid];
  out[(size_t)r*DD + 256 + tid] = (v2 - mu)*inv*g[256 + tid] + be[256 + tid];
}

__global__ void k_colsum_part(const float* __restrict__ x, float* __restrict__ part,
                              int L, int chl, int nch) {
  int d = threadIdx.x;
  int b = blockIdx.x, c = blockIdx.y;
  int l0 = c*chl, l1 = l0 + chl; if (l1 > L) l1 = L;
  float s = 0.f;
  for (int l = l0; l < l1; ++l) s += x[(((size_t)b*L + l) << 9) + d];
  part[((size_t)(b*nch + c) << 9) + d] = s;
}
__global__ void k_colsum_fin(const float* __restrict__ part, float* __restrict__ cm,
                             int nch, float inv) {
  int i = blockIdx.x*256 + threadIdx.x;
  int b = i >> 9, d = i & 511;
  float s = 0.f;
  for (int c = 0; c < nch; ++c) s += part[((size_t)(b*nch + c) << 9) + d];
  cm[i] = s * inv;
}
// subtract col-mean and emit bf16 hi/lo pair
__global__ void k_csub_pair(const float* __restrict__ x, const float* __restrict__ cm,
                            u16* __restrict__ h, u16* __restrict__ l, int L) {
  size_t idx = (size_t)blockIdx.x*256 + threadIdx.x;
  if (idx >= (size_t)BB*L*DD) return;
  int d = (int)(idx & 511);
  int b = (int)((idx >> 9) / (size_t)L);
  float v = x[idx] - cm[(b << 9) | d];
  u16 hh = f2bf(v);
  h[idx] = hh; l[idx] = f2bf(v - bf2f(hh));
}

// ---------------- series decomp (window 25, edge-clamped) ----------------
template<int ACC>
__global__ void k_decomp(const float* __restrict__ x, float* __restrict__ out,
                         float* __restrict__ tsum, int L)
{
  size_t idx = (size_t)blockIdx.x * 256 + threadIdx.x;
  size_t total = (size_t)BB * L * DD;
  if (idx >= total) return;
  int d = idx & 511;
  size_t rl = idx >> 9;
  int l = (int)(rl % L); int b = (int)(rl / L);
  float s = 0.f;
  for (int j = -12; j <= 12; ++j) {
    int lc = l + j; lc = lc < 0 ? 0 : (lc >= L ? L-1 : lc);
    s += x[(((size_t)b*L + lc) << 9) + d];
  }
  float ma = s * (1.f/25.f);
  out[idx] = x[idx] - ma;
  if (ACC) tsum[idx] += ma;
}

// ---------------- final ----------------
__global__ void k_final(const float* __restrict__ trend, const float* __restrict__ seas,
                        float* __restrict__ out) {
  int idx = blockIdx.x*256 + threadIdx.x;
  if (idx >= BB*LEN_E*NV) return;
  int n = idx % NV; int r = idx / NV; int t = r % LEN_E; int b = r / LEN_E;
  size_t src = ((size_t)b*LEN_D + 360 + t)*NV + n;
  out[idx] = trend[src] + seas[src];
}

// =====================================================================
extern "C" void kernel_launch(void* const* d_in, const int* in_sizes, int n_in,
                              void* d_out, int out_size, void* d_ws, size_t ws_size,
                              hipStream_t stream)
{
  (void)in_sizes; (void)n_in; (void)out_size; (void)ws_size;
  const float* history = (const float*)d_in[0];
  const float* future  = (const float*)d_in[1];
  const float* Wv_enc  = (const float*)d_in[2];
  const float* Wt_enc  = (const float*)d_in[3];
  const float* Wv_dec  = (const float*)d_in[4];
  const float* Wt_dec  = (const float*)d_in[5];
  const float* eWq = (const float*)d_in[6];
  const float* ebq = (const float*)d_in[7];
  const float* efr = (const float*)d_in[8];
  const float* efi = (const float*)d_in[9];
  const float* eWo = (const float*)d_in[10];
  const float* ebo = (const float*)d_in[11];
  const float* eW1 = (const float*)d_in[12];
  const float* eW2 = (const float*)d_in[13];
  const float* g_enc = (const float*)d_in[14];
  const float* b_enc = (const float*)d_in[15];
  const float* dWq = (const float*)d_in[16];
  const float* dbq = (const float*)d_in[17];
  const float* dfr = (const float*)d_in[18];
  const float* dfi = (const float*)d_in[19];
  const float* dWo = (const float*)d_in[20];
  const float* dbo = (const float*)d_in[21];
  const float* cWq = (const float*)d_in[22];
  const float* cbq = (const float*)d_in[23];
  const float* cWk = (const float*)d_in[24];
  const float* cbk = (const float*)d_in[25];
  const float* cfr = (const float*)d_in[26];
  const float* cfi = (const float*)d_in[27];
  const float* cWo = (const float*)d_in[28];
  const float* cbo = (const float*)d_in[29];
  const float* dW1 = (const float*)d_in[30];
  const float* dW2 = (const float*)d_in[31];
  const float* Wtr = (const float*)d_in[32];
  const float* g_dec = (const float*)d_in[33];
  const float* b_dec = (const float*)d_in[34];
  const float* Wp  = (const float*)d_in[35];
  const float* bp  = (const float*)d_in[36];

  float* ws = (float*)d_ws;
  size_t off = 0;
  auto alloc = [&](size_t n) { float* p = ws + off; off += (n + 63) & ~(size_t)63; return p; };

  const size_t SL = 1048576;
  const int CH = 4320;

  float* btrend = alloc((size_t)BB*LEN_D*NV);
  float* bTsum  = alloc((size_t)BB*LEN_D*DD);
  float* bX     = alloc((size_t)BB*LEN_D*DD);
  float* bT     = alloc((size_t)BB*LEN_D*DD);
  float* bencout= alloc((size_t)BB*LEN_E*DD);
  float* bseas  = alloc((size_t)BB*LEN_D*NV);
  float* bseasF = bseas;
  float* R      = alloc((size_t)11600000);
  float* SB     = alloc((size_t)2*SL + 128);
  float* WceS   = alloc((size_t)512*992);
  float* WcdS   = alloc((size_t)512*992);
  float* WtrcS  = alloc((size_t)321*1536);
  float* D720S  = alloc((size_t)128*736);
  float* D1080S = alloc((size_t)128*1088);
  float* I720S  = alloc((size_t)736*128);
  float* I1080S = alloc((size_t)1088*128);
  float* bxme   = alloc((size_t)BB*LEN_E*4);
  float* bxmd   = alloc((size_t)BB*LEN_D*4);
  float* bmean  = alloc((size_t)BB*NV);
  float* bpart  = alloc((size_t)BB*9*DD);
  float* bcm    = alloc((size_t)BB*DD);
  float* bmsp   = alloc((size_t)BB*10*NV);

  float* bxe = bT;   // prep alias (dead before T written)

  auto PH = [](float* p) { return (u16*)p; };
  auto PL = [](float* p, size_t n) { return (u16*)p + n; };

  auto splitP = [&](const float* src, float* dst, int M, int K, int Kp) {
    dim3 g((Kp + 255)/256, M);
    k_split_plain<<<g,256,0,stream>>>(src, PH(dst), PL(dst, (size_t)M*Kp), K, Kp);
  };
  auto splitC = [&](const float* src, float* dst, int r0, int Mc, int Lc, int Din, int K, int Kp) {
    dim3 g((Kp + 255)/256, Mc);
    k_split_conv<<<g,256,0,stream>>>(src, PH(dst), PL(dst, (size_t)Mc*Kp), r0, Lc, Din, K, Kp);
  };
  auto splitT = [&](const float* src, float* dst, int Lc, int Kp) {
    dim3 g(Kp/32, 16, BB), b(32, 8);
    k_split_tr<<<g,b,0,stream>>>(src, PH(dst), PL(dst, (size_t)BB*DD*Kp), Lc, Kp);
  };
  auto red = [&](const float* p, int parts, size_t stride, const float* res,
                 float* out, size_t n) {
    k_red<<<(int)((n + 255)/256),256,0,stream>>>(p, parts, stride, res, out, n);
  };

  auto decomp = [&](const float* in, float* out, int L, bool acc) {
    size_t tot = (size_t)BB * L * DD;
    int g = (int)((tot + 255)/256);
    if (acc) k_decomp<1><<<g,256,0,stream>>>(in, out, bTsum, L);
    else     k_decomp<0><<<g,256,0,stream>>>(in, out, nullptr, L);
  };

  // FFN: out = in + gelu(in@W1.T)@W2.T ; GEMM2 split-K=2, partials in `scratch`
  float* SA2 = R + 2211904;   // hidden pair (CH*2048 elements)
  auto ffn = [&](const float* in, float* out, const float* W1, const float* W2,
                 int M, float* scratch) {
    splitP(W1, SB, DFF2, DD, DD);
    splitP(W2, SB + SL, DD, DFF2, DFF2);
    for (int r0 = 0; r0 < M; r0 += CH) {
      int mc = M - r0; if (mc > CH) mc = CH;
      splitP(in + (size_t)r0*DD, R, mc, DD, DD);
      k_mg<128,4,1,1><<<dim3(16,(mc+127)/128,1),256,0,stream>>>(
          PH(R), PL(R,(size_t)mc*DD), PH(SB), PL(SB,(size_t)DFF2*DD),
          nullptr, nullptr, nullptr, PH(SA2), PL(SA2,(size_t)mc*DFF2), mc, DFF2, DD);
      k_mg<64,0,0,2><<<dim3(8,(mc+127)/128,2),256,0,stream>>>(
          PH(SA2), PL(SA2,(size_t)mc*DFF2), PH(SB+SL), PL(SB+SL,(size_t)DD*DFF2),
          nullptr, nullptr, scratch, nullptr, nullptr, mc, DD, DFF2);
      red(scratch, 2, (size_t)mc*DD, in + (size_t)r0*DD, out + (size_t)r0*DD, (size_t)mc*DD);
    }
  };

  // X += fourier_self(X); T used as fp32 temp + DFT partial scratch
  auto fourier_self = [&](float* X, float* T, int L, int KpL, float* DLS, float* ILS,
                          const float* Wq, const float* bq, const float* fr, const float* fi,
                          const float* Wo, const float* bo) {
    int M = BB * L;
    size_t MK = (size_t)M*DD;
    size_t MN8 = (size_t)8192*128;
    float* bqf   = R + 9*SL;
    float* bselp = R + 10*SL;
    splitP(X, R, M, DD, DD);
    splitP(Wq, SB, DD, DD, DD);
    k_mg<128,1,0,1><<<dim3(4,(M+127)/128,1),256,0,stream>>>(
        PH(R), PL(R,MK), PH(SB), PL(SB,(size_t)DD*DD),
        bq, nullptr, T, nullptr, nullptr, M, DD, DD);
    splitT(T, R, L, KpL);                                  // T now dead
    k_mg<64,0,0,4><<<dim3(2,64,4),256,0,stream>>>(         // DFT, partials in T
        PH(R), PL(R,(size_t)BB*DD*KpL), PH(DLS), PL(DLS,(size_t)128*KpL),
        nullptr, nullptr, T, nullptr, nullptr, BB*DD, 128, KpL);
    red(T, 4, MN8, nullptr, bqf, MN8);
    k_modemix<<<dim3(64,8),256,0,stream>>>(bqf, fr, fi, PH(bselp), PL(bselp,MN8), 1.0f);
    k_mg<128,0,1,1><<<dim3((L+127)/128,64,1),256,0,stream>>>(   // irfft -> pair @R0
        PH(bselp), PL(bselp,MN8), PH(ILS), PL(ILS,(size_t)L*128),
        nullptr, nullptr, nullptr, PH(R), PL(R,MK), BB*DD, L, 128);
    splitP(Wo, SB, DD, DD, DD);
    k_mg<128,3,0,1><<<dim3(4,(M+127)/128,1),256,0,stream>>>(
        PH(R), PL(R,MK), PH(SB), PL(SB,(size_t)DD*DD),
        bo, X, X, nullptr, nullptr, M, DD, DD);
  };

  // myln: LN -> tmp, col-mean subtract -> bf16 pair @pairdst
  auto myln_pair = [&](const float* in, float* tmp, float* pairdst,
                       const float* g, const float* b, int L) {
    k_ln<<<BB*L,256,0,stream>>>(in, g, b, tmp);
    int chl = L / 9;
    k_colsum_part<<<dim3(BB,9),512,0,stream>>>(tmp, bpart, L, chl, 9);
    k_colsum_fin<<<32,256,0,stream>>>(bpart, bcm, 9, 1.f/(float)L);
    size_t n = (size_t)BB*L*DD;
    k_csub_pair<<<(int)((n+255)/256),256,0,stream>>>(tmp, bcm, PH(pairdst), PL(pairdst,n), L);
  };

  // ---------------- prep ----------------
  k_extract_x<<<(BB*LEN_E*NV + 255)/256,256,0,stream>>>(history, bxe);
  k_marks_enc<<<(BB*LEN_E*4 + 255)/256,256,0,stream>>>(history, bxme);
  k_marks_dec<<<(BB*LEN_D*4 + 255)/256,256,0,stream>>>(future, bxme, bxmd);
  k_ms_part<<<dim3(BB,10),384,0,stream>>>(bxe, bmsp, 72, 10);
  k_ms_fin<<<(BB*NV + 255)/256,256,0,stream>>>(bmsp, bmean, 10);
  k_init_decomp<<<(BB*LEN_D*NV + 255)/256,256,0,stream>>>(bxe, bmean, bseas, btrend);
  k_build_wconvS<<<dim3(4,512),256,0,stream>>>(Wv_enc, PH(WceS), PL(WceS,(size_t)512*992));
  k_build_wconvS<<<dim3(4,512),256,0,stream>>>(Wv_dec, PH(WcdS), PL(WcdS,(size_t)512*992));
  k_build_wtrcS<<<dim3(6,321),256,0,stream>>>(Wtr, PH(WtrcS), PL(WtrcS,(size_t)321*1536));
  k_build_dftS<<<dim3(3,128),256,0,stream>>>(PH(D720S), PL(D720S,(size_t)128*736), LEN_E, 736);
  k_build_dftS<<<dim3(5,128),256,0,stream>>>(PH(D1080S), PL(D1080S,(size_t)128*1088), LEN_D, 1088);
  k_build_irS<<<dim3(1,LEN_E),128,0,stream>>>(PH(I720S), PL(I720S,(size_t)LEN_E*128), LEN_E);
  k_build_irS<<<dim3(1,LEN_D),128,0,stream>>>(PH(I1080S), PL(I1080S,(size_t)LEN_D*128), LEN_D);

  // ---------------- encoder ----------------
  int ME = BB * LEN_E;
  for (int r0 = 0; r0 < ME; r0 += 5760) {     // conv embed, split-K=2, partials @bencout
    splitC(bxe, R, r0, 5760, LEN_E, NV, 963, 992);
    k_mg<128,0,0,2><<<dim3(4,45,2),256,0,stream>>>(
        PH(R), PL(R,(size_t)5760*992), PH(WceS), PL(WceS,(size_t)512*992),
        nullptr, nullptr, bencout, nullptr, nullptr, 5760, DD, 992);
    red(bencout, 2, (size_t)5760*DD, nullptr, bX + (size_t)r0*DD, (size_t)5760*DD);
  }
  k_marks_add<<<(ME*DD + 255)/256,256,0,stream>>>(bX, bxme, Wt_enc, ME);

  float *X = bX, *T = bT;
  for (int i = 0; i < 2; ++i) {
    fourier_self(X, T, LEN_E, 736, D720S, I720S,
                 eWq + (size_t)i*DD*DD, ebq + (size_t)i*DD,
                 efr + (size_t)i*HHN*64*64*64, efi + (size_t)i*HHN*64*64*64,
                 eWo + (size_t)i*DD*DD, ebo + (size_t)i*DD);
    decomp(X, T, LEN_E, false);
    ffn(T, X, eW1 + (size_t)i*DFF2*DD, eW2 + (size_t)i*DD*DFF2, ME, bencout);
    decomp(X, T, LEN_E, false);
    { float* tmp = X; X = T; T = tmp; }
  }
  myln_pair(X, T, bencout, g_enc, b_enc, LEN_E);   // bencout now holds bf16 pair

  // ---------------- decoder ----------------
  int MD = BB * LEN_D;
  for (int r0 = 0; r0 < MD; r0 += 8640) {     // conv embed, split-K=2, partials @T
    splitC(bseas, R, r0, 8640, LEN_D, NV, 963, 992);
    k_mg<128,0,0,2><<<dim3(4,68,2),256,0,stream>>>(
        PH(R), PL(R,(size_t)8640*992), PH(WcdS), PL(WcdS,(size_t)512*992),
        nullptr, nullptr, T, nullptr, nullptr, 8640, DD, 992);
    red(T, 2, (size_t)8640*DD, nullptr, X + (size_t)r0*DD, (size_t)8640*DD);
  }
  k_marks_add<<<(MD*DD + 255)/256,256,0,stream>>>(X, bxmd, Wt_dec, MD);

  fourier_self(X, T, LEN_D, 1088, D1080S, I1080S, dWq, dbq, dfr, dfi, dWo, dbo);

  k_zero<<<(BB*LEN_D*DD + 255)/256,256,0,stream>>>(bTsum, BB*LEN_D*DD);
  decomp(X, T, LEN_D, true);          // x -> T, t1 acc

  // cross attention
  {
    size_t MN8 = (size_t)8192*128;
    float* bkf = R + 9*SL;
    float* bqf = R + 10*SL;
    // k projection from bencout PAIR
    k_mg<128,1,0,1><<<dim3(4,90,1),256,0,stream>>>(
        PH(bencout), PL(bencout,(size_t)ME*DD), PH(SB), PL(SB,(size_t)DD*DD),
        cbk, nullptr, X, nullptr, nullptr, ME, DD, DD);
    // NOTE: SB must hold cWk split BEFORE the call above
    // (ordered below via explicit sequencing)
    (void)0;
  }
  {
    size_t MN8 = (size_t)8192*128;
    float* bkf = R + 9*SL;
    float* bqf = R + 10*SL;
    // --- proper ordering: split cWk first (redo sequence cleanly) ---
    splitP(cWk, SB, DD, DD, DD);
    k_mg<128,1,0,1><<<dim3(4,90,1),256,0,stream>>>(
        PH(bencout), PL(bencout,(size_t)ME*DD), PH(SB), PL(SB,(size_t)DD*DD),
        cbk, nullptr, X, nullptr, nullptr, ME, DD, DD);
    splitT(X, R, LEN_E, 736);
    k_mg<64,0,0,4><<<dim3(2,64,4),256,0,stream>>>(     // DFT-k, partials @X
        PH(R), PL(R,(size_t)BB*DD*736), PH(D720S), PL(D720S,(size_t)128*736),
        nullptr, nullptr, X, nullptr, nullptr, BB*DD, 128, 736);
    red(X, 4, MN8, nullptr, bkf, MN8);
    splitP(T, R, MD, DD, DD);
    splitP(cWq, SB, DD, DD, DD);
    k_mg<128,1,0,1><<<dim3(4,135,1),256,0,stream>>>(
        PH(R), PL(R,(size_t)MD*DD), PH(SB), PL(SB,(size_t)DD*DD),
        cbq, nullptr, X, nullptr, nullptr, MD, DD, DD);
    splitT(X, R, LEN_D, 1088);
    k_mg<64,0,0,4><<<dim3(2,64,4),256,0,stream>>>(     // DFT-q, partials @X
        PH(R), PL(R,(size_t)BB*DD*1088), PH(D1080S), PL(D1080S,(size_t)128*1088),
        nullptr, nullptr, X, nullptr, nullptr, BB*DD, 128, 1088);
    red(X, 4, MN8, nullptr, bqf, MN8);
    float* ba = R;
    float* bv = R + SL;
    k_cross_qk<<<BB*HHN,256,0,stream>>>(bqf, bkf, ba);
    k_cross_v<<<BB*HHN,256,0,stream>>>(ba, bkf, bv);
    float* bselp = R + 9*SL;                           // bkf dead
    k_modemix<<<dim3(64,8),256,0,stream>>>(bv, cfr, cfi, PH(bselp), PL(bselp,MN8),
                                           1.0f/262144.0f);
    k_mg<128,0,1,1><<<dim3(9,64,1),256,0,stream>>>(    // irfft -> pair @R0
        PH(bselp), PL(bselp,MN8), PH(I1080S), PL(I1080S,(size_t)LEN_D*128),
        nullptr, nullptr, nullptr, PH(R), PL(R,(size_t)MD*DD), BB*DD, LEN_D, 128);
    splitP(cWo, SB, DD, DD, DD);
    k_mg<128,3,0,1><<<dim3(4,135,1),256,0,stream>>>(
        PH(R), PL(R,(size_t)MD*DD), PH(SB), PL(SB,(size_t)DD*DD),
        cbo, T, T, nullptr, nullptr, MD, DD, DD);
  }

  decomp(T, X, LEN_D, true);          // x -> X, t2 acc
  ffn(X, T, dW1, dW2, MD, bencout);   // T = x + FFN(x)  (bencout pair dead)
  decomp(T, X, LEN_D, true);          // x -> X, t3 acc

  myln_pair(X, T, R, g_dec, b_dec, LEN_D);   // pair @R0
  splitP(Wp, SB, NV, DD, DD);
  k_mg<64,1,0,1><<<dim3(6,135,1),256,0,stream>>>(
      PH(R), PL(R,(size_t)MD*DD), PH(SB), PL(SB,(size_t)NV*DD),
      bp, nullptr, bseasF, nullptr, nullptr, MD, NV, DD);

  for (int r0 = 0; r0 < MD; r0 += 5760) {    // trend conv, split-K=2, partials @bX
    splitC(bTsum, R, r0, 5760, LEN_D, DD, 1536, 1536);
    k_mg<64,0,0,2><<<dim3(6,45,2),256,0,stream>>>(
        PH(R), PL(R,(size_t)5760*1536), PH(WtrcS), PL(WtrcS,(size_t)NV*1536),
        nullptr, nullptr, bX, nullptr, nullptr, 5760, NV, 1536);
    red(bX, 2, (size_t)5760*NV, btrend + (size_t)r0*NV, btrend + (size_t)r0*NV,
        (size_t)5760*NV);
  }

  k_final<<<(BB*LEN_E*NV + 255)/256,256,0,stream>>>(btrend, bseasF, (float*)d_out);
}

// Round 9
// 2858.687 us; speedup vs baseline: 4.9826x; 1.1082x over previous
//
#include <hip/hip_runtime.h>
#include <math.h>

#define BB 16
#define DD 512
#define HHN 8
#define LEN_E 720
#define LEN_D 1080
#define NV 321
#define DFF2 2048

typedef __attribute__((ext_vector_type(8))) short short8;
typedef __attribute__((ext_vector_type(4))) float floatx4;
typedef unsigned short u16;

__device__ __forceinline__ u16 f2bf(float v) {
  unsigned u = __builtin_bit_cast(unsigned, v);
  u += 0x7FFFu + ((u >> 16) & 1u);
  return (u16)(u >> 16);
}
__device__ __forceinline__ float bf2f(u16 h) {
  unsigned u = ((unsigned)h) << 16;
  return __builtin_bit_cast(float, u);
}

// element offset (u16) of (r,k) in tiled pair buffer; lo at +4096.
// tile = 128 rows x 32 cols, 8192 u16 (hi 4096 + lo 4096), XOR-swizzled slots.
__device__ __forceinline__ size_t toff(int r, int k, int ktn) {
  int rt = r >> 7, rr = r & 127;
  int kt = k >> 5, kk = k & 31;
  int sw = (kk >> 3) ^ (rr & 3) ^ ((rr >> 2) & 3);
  return (((size_t)(rt * ktn + kt)) << 13) + (rr << 5) + (sw << 3) + (kk & 7);
}

__device__ __forceinline__ void gload_lds(const void* g, void* l) {
  __builtin_amdgcn_global_load_lds(
      (const __attribute__((address_space(1))) unsigned int*)g,
      (__attribute__((address_space(3))) unsigned int*)l, 16, 0, 0);
}

// ---------------- prep kernels ----------------
__global__ void k_extract_x(const float* __restrict__ hist, float* __restrict__ xe) {
  int idx = blockIdx.x * 256 + threadIdx.x;
  if (idx >= BB*LEN_E*NV) return;
  xe[idx] = hist[(size_t)idx * 5];
}

__global__ void k_marks_enc(const float* __restrict__ hist, float* __restrict__ xme) {
  int idx = blockIdx.x * 256 + threadIdx.x;
  if (idx >= BB*LEN_E*4) return;
  int f = idx & 3;
  int r = idx >> 2;
  xme[idx] = hist[((size_t)r * NV) * 5 + 1 + f];
}

__global__ void k_marks_dec(const float* __restrict__ fut, const float* __restrict__ xme,
                            float* __restrict__ xmd) {
  int idx = blockIdx.x * 256 + threadIdx.x;
  if (idx >= BB*LEN_D*4) return;
  int f = idx & 3;
  int r = idx >> 2;
  int t = r % LEN_D, b = r / LEN_D;
  float v;
  if (t < 360) v = xme[((b*LEN_E) + 360 + t)*4 + f];
  else v = fut[(((size_t)(b*LEN_E + (t-360))) * NV) * 5 + 1 + f];
  xmd[idx] = v;
}

__global__ void k_ms_part(const float* __restrict__ xe, float* __restrict__ part,
                          int chl, int nch) {
  int n = threadIdx.x;
  if (n >= NV) return;
  int b = blockIdx.x, c = blockIdx.y;
  int l0 = c*chl, l1 = l0 + chl; if (l1 > LEN_E) l1 = LEN_E;
  float s = 0.f;
  for (int l = l0; l < l1; ++l) s += xe[((size_t)b*LEN_E + l)*NV + n];
  part[((size_t)b*nch + c)*NV + n] = s;
}
__global__ void k_ms_fin(const float* __restrict__ part, float* __restrict__ mb, int nch) {
  int i = blockIdx.x*256 + threadIdx.x;
  if (i >= BB*NV) return;
  int b = i / NV, n = i % NV;
  float s = 0.f;
  for (int c = 0; c < nch; ++c) s += part[((size_t)b*nch + c)*NV + n];
  mb[i] = s * (1.f/(float)LEN_E);
}

__global__ void k_init_decomp(const float* __restrict__ xe, const float* __restrict__ mb,
                              float* __restrict__ seas, float* __restrict__ trend) {
  int idx = blockIdx.x * 256 + threadIdx.x;
  if (idx >= BB*LEN_D*NV) return;
  int n = idx % NV; int r = idx / NV; int t = r % LEN_D; int b = r / LEN_D;
  if (t < 360) {
    int l = 360 + t;
    float s = 0.f;
    for (int j = -12; j <= 12; ++j) {
      int lc = l + j; if (lc > LEN_E-1) lc = LEN_E-1; if (lc < 0) lc = 0;
      s += xe[((size_t)b*LEN_E + lc)*NV + n];
    }
    float ma = s * (1.f/25.f);
    trend[idx] = ma;
    seas[idx]  = xe[((size_t)b*LEN_E + l)*NV + n] - ma;
  } else {
    trend[idx] = mb[b*NV + n];
    seas[idx]  = 0.f;
  }
}

__global__ void k_zero(float* __restrict__ p, int n) {
  int i = blockIdx.x*256 + threadIdx.x;
  if (i < n) p[i] = 0.f;
}

__global__ void k_marks_add(float* __restrict__ X, const float* __restrict__ xm,
                            const float* __restrict__ Wt, int M) {
  int idx = blockIdx.x*256 + threadIdx.x;
  if (idx >= M*DD) return;
  int d = idx & 511, r = idx >> 9;
  const float* m4 = xm + (size_t)r*4;
  const float* w4 = Wt + (size_t)d*4;
  X[idx] += m4[0]*w4[0] + m4[1]*w4[1] + m4[2]*w4[2] + m4[3]*w4[3];
}

// ---------------- split builders (tiled pair output) ----------------
__global__ void k_split_plain(const float* __restrict__ src, u16* __restrict__ dst,
                              int K, int Kp) {
  int col = blockIdx.x*256 + threadIdx.x;
  if (col >= Kp) return;
  int r = blockIdx.y;
  float v = (col < K) ? src[(size_t)r*K + col] : 0.f;
  u16 hh = f2bf(v);
  size_t o = toff(r, col, Kp >> 5);
  dst[o] = hh; dst[o + 4096] = f2bf(v - bf2f(hh));
}

__global__ void k_split_conv(const float* __restrict__ src, u16* __restrict__ dst,
                             int r0, int Lc, int Din, int K, int Kp) {
  int col = blockIdx.x*256 + threadIdx.x;
  if (col >= Kp) return;
  int rr = blockIdx.y;
  int r = r0 + rr;
  int b = r / Lc, t = r - b*Lc;
  float v = 0.f;
  if (col < K) {
    int c = (col >= 2*Din) ? 2 : ((col >= Din) ? 1 : 0);
    int n = col - c*Din;
    int tt = t + c - 1;
    if (tt < 0) tt = Lc - 1; else if (tt >= Lc) tt = 0;
    v = src[((size_t)(b*Lc + tt))*Din + n];
  }
  u16 hh = f2bf(v);
  size_t o = toff(rr, col, Kp >> 5);
  dst[o] = hh; dst[o + 4096] = f2bf(v - bf2f(hh));
}

__global__ void k_split_tr(const float* __restrict__ src, u16* __restrict__ dst,
                           int Lc, int Kp) {
  __shared__ float t[32][33];
  int b = blockIdx.z;
  int l0 = blockIdx.x*32, c0 = blockIdx.y*32;
  int lx = threadIdx.x, ly = threadIdx.y;   // (32,8)
  #pragma unroll
  for (int i = 0; i < 4; ++i) {
    int ll = l0 + ly + i*8;
    t[ly + i*8][lx] = (ll < Lc) ? src[((size_t)b*Lc + ll)*DD + c0 + lx] : 0.f;
  }
  __syncthreads();
  int ktn = Kp >> 5;
  #pragma unroll
  for (int i = 0; i < 4; ++i) {
    int ch = c0 + ly + i*8;
    int ll = l0 + lx;
    float v = t[lx][ly + i*8];
    u16 hh = f2bf(v);
    size_t o = toff(b*DD + ch, ll, ktn);
    dst[o] = hh; dst[o + 4096] = f2bf(v - bf2f(hh));
  }
}

__global__ void k_build_wconvS(const float* __restrict__ Wv, u16* __restrict__ dst) {
  int col = blockIdx.x*256 + threadIdx.x;
  if (col >= 992) return;
  int d = blockIdx.y;
  float v = 0.f;
  if (col < 963) {
    int c = (col >= 642) ? 2 : ((col >= 321) ? 1 : 0);
    int n = col - c*321;
    v = Wv[(size_t)d*963 + n*3 + c];
  }
  u16 hh = f2bf(v);
  size_t o = toff(d, col, 31);
  dst[o] = hh; dst[o + 4096] = f2bf(v - bf2f(hh));
}

__global__ void k_build_wtrcS(const float* __restrict__ Wtr, u16* __restrict__ dst) {
  int col = blockIdx.x*256 + threadIdx.x;
  if (col >= 1536) return;
  int n = blockIdx.y;
  int c = col >> 9, d = col & 511;
  float v = Wtr[(size_t)n*1536 + d*3 + c];
  u16 hh = f2bf(v);
  size_t o = toff(n, col, 48);
  dst[o] = hh; dst[o + 4096] = f2bf(v - bf2f(hh));
}

__global__ void k_build_dftS(u16* __restrict__ dst, int L, int Kp) {
  int col = blockIdx.x*256 + threadIdx.x;
  if (col >= Kp) return;
  int mr = blockIdx.y;
  float v = 0.f;
  if (col < L) {
    int m = mr & 63;
    int ph = (m * col) % L;
    float th = 6.2831853071795864f * ((float)ph / (float)L);
    v = (mr < 64) ? cosf(th) : -sinf(th);
  }
  u16 hh = f2bf(v);
  size_t o = toff(mr, col, Kp >> 5);
  dst[o] = hh; dst[o + 4096] = f2bf(v - bf2f(hh));
}

__global__ void k_build_irS(u16* __restrict__ dst, int L) {
  int k = threadIdx.x;   // 0..127
  int ll = blockIdx.y;
  int m = k & 63;
  int ph = (m * ll) % L;
  float th = 6.2831853071795864f * ((float)ph / (float)L);
  float v;
  if (k < 64) v = (m == 0) ? (1.f/(float)L) : (2.f/(float)L) * cosf(th);
  else        v = (m == 0) ? 0.f            : -(2.f/(float)L) * sinf(th);
  u16 hh = f2bf(v);
  size_t o = toff(ll, k, 4);
  dst[o] = hh; dst[o + 4096] = f2bf(v - bf2f(hh));
}

// ---------------- MFMA GEMM: global_load_lds staging of pre-tiled operands ----
// WOUT: 0 fp32 C; 1 tiled pair Cout (cols Nc); 2 tiled pair under (B,512,L)->(B*L,512)
//       flat reinterpretation (Lout = L).
template<int TN, int EPI, int WOUT, int KS>
__global__ __launch_bounds__(256)
void k_mg(const u16* __restrict__ A, const u16* __restrict__ B,
          const float* __restrict__ bias, const float* __restrict__ res,
          float* __restrict__ C, u16* __restrict__ Cout,
          int M, int Nc, int K, int Lout)
{
  __shared__ __attribute__((aligned(16))) u16 sA[8192];
  __shared__ __attribute__((aligned(16))) u16 sB[(TN == 128) ? 8192 : 4096];

  const int tid  = threadIdx.x;
  const int lane = tid & 63;
  const int wave = tid >> 6;
  const int lr   = lane & 15;
  const int kg   = lane >> 4;

  const int gx  = gridDim.x;
  const int nwg = gx * gridDim.y;
  const int lid = blockIdx.y * gx + blockIdx.x;
  const int q8  = nwg >> 3, r8 = nwg & 7;
  const int xcd = lid & 7, i8 = lid >> 3;
  const int swz = (xcd < r8 ? xcd*(q8+1) : r8*(q8+1) + (xcd - r8)*q8) + i8;
  const int row0 = (swz / gx) * 128;
  const int col0 = (swz % gx) * TN;

  constexpr int MF = (TN == 128) ? 4 : 2;
  const int wr = (TN == 128) ? (wave >> 1) : wave;
  const int wc = (TN == 128) ? (wave & 1) : 0;

  const int ksteps = K >> 5;
  const int zz = (KS > 1) ? (int)blockIdx.z : 0;
  const int t0 = (KS > 1) ? (int)(((long long)ksteps * zz) / KS) : 0;
  const int t1 = (KS > 1) ? (int)(((long long)ksteps * (zz+1)) / KS) : ksteps;

  const char* gA = (const char*)(A + (((size_t)(row0 >> 7) * ksteps) << 13));
  const char* gB = (const char*)(B + (((size_t)(col0 >> 7) * ksteps) << 13));
  const int bhalf = (TN == 64) ? ((col0 & 64) << 6) : 0;   // 0 or 4096 bytes

  char* lA = (char*)sA;
  char* lB = (char*)sB;
  const int wl = (wave << 10) + (lane << 4);
  const int wb = (wave << 10);

  floatx4 acc[MF][4] = {};

  for (int kt = t0; kt < t1; ++kt) {
    {
      const char* ta = gA + ((size_t)kt << 14);
      #pragma unroll
      for (int c = 0; c < 4; ++c)
        gload_lds(ta + (c << 12) + wl, lA + (c << 12) + wb);
    }
    if (TN == 128) {
      const char* tb = gB + ((size_t)kt << 14);
      #pragma unroll
      for (int c = 0; c < 4; ++c)
        gload_lds(tb + (c << 12) + wl, lB + (c << 12) + wb);
    } else {
      const char* tb = gB + ((size_t)kt << 14) + bhalf;
      gload_lds(tb + wl, lB + wb);
      gload_lds(tb + 8192 + wl, lB + 4096 + wb);
    }
    __syncthreads();

    short8 ahf[MF], alf[MF], bhf[4], blf[4];
    #pragma unroll
    for (int f = 0; f < MF; ++f) {
      int row = wr*(MF*16) + f*16 + lr;
      int sw = kg ^ (row & 3) ^ ((row >> 2) & 3);
      int off = (row << 5) + (sw << 3);
      ahf[f] = *(const short8*)&sA[off];
      alf[f] = *(const short8*)&sA[4096 + off];
    }
    #pragma unroll
    for (int n = 0; n < 4; ++n) {
      int row = wc*64 + n*16 + lr;
      int sw = kg ^ (row & 3) ^ ((row >> 2) & 3);
      int off = (row << 5) + (sw << 3);
      bhf[n] = *(const short8*)&sB[off];
      blf[n] = *(const short8*)&sB[((TN == 128) ? 4096 : 2048) + off];
    }
    #pragma unroll
    for (int mf = 0; mf < MF; ++mf)
      #pragma unroll
      for (int nf = 0; nf < 4; ++nf) {
        acc[mf][nf] = __builtin_amdgcn_mfma_f32_16x16x32_bf16(ahf[mf], bhf[nf], acc[mf][nf], 0, 0, 0);
        acc[mf][nf] = __builtin_amdgcn_mfma_f32_16x16x32_bf16(ahf[mf], blf[nf], acc[mf][nf], 0, 0, 0);
        acc[mf][nf] = __builtin_amdgcn_mfma_f32_16x16x32_bf16(alf[mf], bhf[nf], acc[mf][nf], 0, 0, 0);
      }
    __syncthreads();
  }

  if (KS > 1) {
    float* Cp = C + (size_t)zz * ((size_t)M * Nc);
    #pragma unroll
    for (int nf = 0; nf < 4; ++nf) {
      int cN = col0 + wc*64 + nf*16 + lr;
      if (cN >= Nc) continue;
      #pragma unroll
      for (int mf = 0; mf < MF; ++mf)
        #pragma unroll
        for (int i = 0; i < 4; ++i) {
          int rM = row0 + wr*(MF*16) + mf*16 + kg*4 + i;
          if (rM >= M) continue;
          Cp[(size_t)rM * Nc + cN] = acc[mf][nf][i];
        }
    }
  } else {
    #pragma unroll
    for (int nf = 0; nf < 4; ++nf) {
      int cN = col0 + wc*64 + nf*16 + lr;
      if (cN >= Nc) continue;
      #pragma unroll
      for (int mf = 0; mf < MF; ++mf) {
        #pragma unroll
        for (int i = 0; i < 4; ++i) {
          int rM = row0 + wr*(MF*16) + mf*16 + kg*4 + i;
          if (rM >= M) continue;
          float v = acc[mf][nf][i];
          if (EPI & 1) v += bias[cN];
          if (EPI & 4) v = 0.5f * v * (1.f + erff(v * 0.7071067811865476f));
          if (EPI & 2) v += res[(size_t)rM * Nc + cN];
          if (WOUT == 1) {
            u16 hh = f2bf(v);
            size_t o = toff(rM, cN, Nc >> 5);
            Cout[o] = hh; Cout[o + 4096] = f2bf(v - bf2f(hh));
          } else if (WOUT == 2) {
            int b = rM >> 9, ch = rM & 511;
            int fl = ch * Lout + cN;
            int r2 = b * Lout + (fl >> 9);
            int c2 = fl & 511;
            u16 hh = f2bf(v);
            size_t o = toff(r2, c2, 16);
            Cout[o] = hh; Cout[o + 4096] = f2bf(v - bf2f(hh));
          } else {
            C[(size_t)rM * Nc + cN] = v;
          }
        }
      }
    }
  }
}

// ---------------- split-K reduce (fixed order, deterministic) ----------------
__global__ void k_red(const float* __restrict__ p, int parts, size_t stride,
                      const float* __restrict__ res, float* __restrict__ out, size_t n) {
  size_t i = (size_t)blockIdx.x*256 + threadIdx.x;
  if (i >= n) return;
  float s = res ? res[i] : 0.f;
  for (int z = 0; z < parts; ++z) s += p[(size_t)z*stride + i];
  out[i] = s;
}

// ---------------- mode mix (emits tiled bf16 pair) ----------------
__global__ __launch_bounds__(256)
void k_modemix(const float* __restrict__ ftbuf, const float* __restrict__ fr,
               const float* __restrict__ fi, u16* __restrict__ sel, float scale)
{
  int m = blockIdx.x, h = blockIdx.y;
  __shared__ float wr[64][64], wi[64][64];
  __shared__ float qr[BB][64], qi[BB][64];
  int tid = threadIdx.x;
  for (int it = 0; it < 16; ++it) {
    int idx = tid + it*256;
    int e = idx >> 6, o = idx & 63;
    size_t wof = ((((size_t)h*64 + e)*64 + o) << 6) + m;
    wr[e][o] = fr[wof]; wi[e][o] = fi[wof];
  }
  for (int it = 0; it < 4; ++it) {
    int idx = tid + it*256;
    int bb = idx >> 6, e = idx & 63;
    size_t qof = ((size_t)bb*DD + h*64 + e)*128 + m;
    qr[bb][e] = ftbuf[qof]; qi[bb][e] = ftbuf[qof + 64];
  }
  __syncthreads();
  for (int it = 0; it < 4; ++it) {
    int idx = tid + it*256;
    int bb = idx >> 6, o = idx & 63;
    float ar = 0.f, ai = 0.f;
    for (int e = 0; e < 64; ++e) {
      float xr = qr[bb][e], xi = qi[bb][e], yr = wr[e][o], yi = wi[e][o];
      ar += xr*yr - xi*yi;
      ai += xr*yi + xi*yr;
    }
    int row = bb*DD + h*64 + o;
    float vr = ar*scale, vi2 = ai*scale;
    u16 hr = f2bf(vr);
    size_t o1 = toff(row, m, 4);
    sel[o1] = hr; sel[o1 + 4096] = f2bf(vr - bf2f(hr));
    u16 hi2 = f2bf(vi2);
    size_t o2 = toff(row, m + 64, 4);
    sel[o2] = hi2; sel[o2 + 4096] = f2bf(vi2 - bf2f(hi2));
  }
}

// ---------------- cross attention ----------------
__global__ __launch_bounds__(256)
void k_cross_qk(const float* __restrict__ qf, const float* __restrict__ kf,
                float* __restrict__ ab)
{
  int bh = blockIdx.x; int b = bh >> 3, h = bh & 7;
  __shared__ float qr[32][64], qi[32][64], kr[32][64], ki[32][64];
  int tid = threadIdx.x;
  int tx = tid & 15, ty = tid >> 4;
  float ar[4][4] = {}, ai[4][4] = {};
  for (int e0 = 0; e0 < 64; e0 += 32) {
    for (int it = 0; it < 8; ++it) {
      int idx = tid + it*256;
      int e = idx >> 6, x = idx & 63;
      size_t rof = ((size_t)b*DD + h*64 + e0 + e)*128;
      qr[e][x] = qf[rof + x]; qi[e][x] = qf[rof + 64 + x];
      kr[e][x] = kf[rof + x]; ki[e][x] = kf[rof + 64 + x];
    }
    __syncthreads();
    for (int e = 0; e < 32; ++e) {
      float xr[4], xi2[4], yr[4], yi[4];
      #pragma unroll
      for (int i = 0; i < 4; ++i) { xr[i] = qr[e][ty*4+i]; xi2[i] = qi[e][ty*4+i]; }
      #pragma unroll
      for (int j = 0; j < 4; ++j) { yr[j] = kr[e][tx*4+j]; yi[j] = ki[e][tx*4+j]; }
      #pragma unroll
      for (int i = 0; i < 4; ++i)
        #pragma unroll
        for (int j = 0; j < 4; ++j) {
          ar[i][j] += xr[i]*yr[j] - xi2[i]*yi[j];
          ai[i][j] += xr[i]*yi[j] + xi2[i]*yr[j];
        }
    }
    __syncthreads();
  }
  #pragma unroll
  for (int i = 0; i < 4; ++i)
    #pragma unroll
    for (int j = 0; j < 4; ++j) {
      float txv = tanhf(ar[i][j]);
      float tyv = tanf(ai[i][j]);
      float den = 1.f + txv*txv*tyv*tyv;
      float re = txv*(1.f + tyv*tyv) / den;
      float im = tyv*(1.f - txv*txv) / den;
      size_t of = ((size_t)bh*64 + (ty*4+i))*128 + tx*4 + j;
      ab[of] = re; ab[of + 64] = im;
    }
}

__global__ __launch_bounds__(256)
void k_cross_v(const float* __restrict__ ab, const float* __restrict__ kf,
               float* __restrict__ v)
{
  int bh = blockIdx.x; int b = bh >> 3, h = bh & 7;
  __shared__ float ar[64][32], ai[64][32], kr[64][32], ki[64][32];
  int tid = threadIdx.x;
  int tx = tid & 15, ty = tid >> 4;
  float vr[4][4] = {}, vi[4][4] = {};
  for (int y0 = 0; y0 < 64; y0 += 32) {
    for (int it = 0; it < 8; ++it) {
      int idx = tid + it*256;
      int r = idx >> 5, y = idx & 31;
      ar[r][y] = ab[((size_t)bh*64 + r)*128 + y0 + y];
      ai[r][y] = ab[((size_t)bh*64 + r)*128 + 64 + y0 + y];
      kr[r][y] = kf[((size_t)b*DD + h*64 + r)*128 + y0 + y];
      ki[r][y] = kf[((size_t)b*DD + h*64 + r)*128 + 64 + y0 + y];
    }
    __syncthreads();
    for (int y = 0; y < 32; ++y) {
      float er[4], ei[4], xr[4], xi2[4];
      #pragma unroll
      for (int i = 0; i < 4; ++i) { er[i] = kr[ty*4+i][y]; ei[i] = ki[ty*4+i][y]; }
      #pragma unroll
      for (int j = 0; j < 4; ++j) { xr[j] = ar[tx*4+j][y]; xi2[j] = ai[tx*4+j][y]; }
      #pragma unroll
      for (int i = 0; i < 4; ++i)
        #pragma unroll
        for (int j = 0; j < 4; ++j) {
          vr[i][j] += xr[j]*er[i] - xi2[j]*ei[i];
          vi[i][j] += xr[j]*ei[i] + xi2[j]*er[i];
        }
    }
    __syncthreads();
  }
  #pragma unroll
  for (int i = 0; i < 4; ++i)
    #pragma unroll
    for (int j = 0; j < 4; ++j) {
      size_t of = ((size_t)b*DD + h*64 + ty*4 + i)*128 + tx*4 + j;
      v[of] = vr[i][j]; v[of + 64] = vi[i][j];
    }
}

// ---------------- LN + column-mean subtract ----------------
__global__ __launch_bounds__(256)
void k_ln(const float* __restrict__ x, const float* __restrict__ g,
          const float* __restrict__ be, float* __restrict__ out)
{
  int r = blockIdx.x; int tid = threadIdx.x;
  float v1 = x[(size_t)r*DD + tid], v2 = x[(size_t)r*DD + 256 + tid];
  float s = v1 + v2, s2 = v1*v1 + v2*v2;
  #pragma unroll
  for (int off = 32; off; off >>= 1) { s += __shfl_down(s, off, 64); s2 += __shfl_down(s2, off, 64); }
  __shared__ float red[8];
  int wid = tid >> 6, lane = tid & 63;
  if (lane == 0) { red[wid] = s; red[4 + wid] = s2; }
  __syncthreads();
  if (tid == 0) {
    float a = red[0]+red[1]+red[2]+red[3];
    float b2 = red[4]+red[5]+red[6]+red[7];
    float mu = a / 512.f;
    float var = b2 / 512.f - mu*mu;
    red[0] = mu; red[1] = rsqrtf(var + 1e-5f);
  }
  __syncthreads();
  float mu = red[0], inv = red[1];
  out[(size_t)r*DD + tid]       = (v1 - mu)*inv*g[tid]       + be[tid];
  out[(size_t)r*DD + 256 + tid] = (v2 - mu)*inv*g[256 + tid] + be[256 + tid];
}

__global__ void k_colsum_part(const float* __restrict__ x, float* __restrict__ part,
                              int L, int chl, int nch) {
  int d = threadIdx.x;
  int b = blockIdx.x, c = blockIdx.y;
  int l0 = c*chl, l1 = l0 + chl; if (l1 > L) l1 = L;
  float s = 0.f;
  for (int l = l0; l < l1; ++l) s += x[(((size_t)b*L + l) << 9) + d];
  part[((size_t)(b*nch + c) << 9) + d] = s;
}
__global__ void k_colsum_fin(const float* __restrict__ part, float* __restrict__ cm,
                             int nch, float inv) {
  int i = blockIdx.x*256 + threadIdx.x;
  int b = i >> 9, d = i & 511;
  float s = 0.f;
  for (int c = 0; c < nch; ++c) s += part[((size_t)(b*nch + c) << 9) + d];
  cm[i] = s * inv;
}
// subtract col-mean and emit tiled bf16 pair (rows = b*L + l, cols = d)
__global__ void k_csub_pair(const float* __restrict__ x, const float* __restrict__ cm,
                            u16* __restrict__ dst, int L) {
  size_t idx = (size_t)blockIdx.x*256 + threadIdx.x;
  if (idx >= (size_t)BB*L*DD) return;
  int d = (int)(idx & 511);
  int r = (int)(idx >> 9);
  int b = r / L;
  float v = x[idx] - cm[(b << 9) | d];
  u16 hh = f2bf(v);
  size_t o = toff(r, d, 16);
  dst[o] = hh; dst[o + 4096] = f2bf(v - bf2f(hh));
}

// ---------------- series decomp (window 25, edge-clamped) ----------------
template<int ACC>
__global__ void k_decomp(const float* __restrict__ x, float* __restrict__ out,
                         float* __restrict__ tsum, int L)
{
  size_t idx = (size_t)blockIdx.x * 256 + threadIdx.x;
  size_t total = (size_t)BB * L * DD;
  if (idx >= total) return;
  int d = idx & 511;
  size_t rl = idx >> 9;
  int l = (int)(rl % L); int b = (int)(rl / L);
  float s = 0.f;
  for (int j = -12; j <= 12; ++j) {
    int lc = l + j; lc = lc < 0 ? 0 : (lc >= L ? L-1 : lc);
    s += x[(((size_t)b*L + lc) << 9) + d];
  }
  float ma = s * (1.f/25.f);
  out[idx] = x[idx] - ma;
  if (ACC) tsum[idx] += ma;
}

// ---------------- final ----------------
__global__ void k_final(const float* __restrict__ trend, const float* __restrict__ seas,
                        float* __restrict__ out) {
  int idx = blockIdx.x*256 + threadIdx.x;
  if (idx >= BB*LEN_E*NV) return;
  int n = idx % NV; int r = idx / NV; int t = r % LEN_E; int b = r / LEN_E;
  size_t src = ((size_t)b*LEN_D + 360 + t)*NV + n;
  out[idx] = trend[src] + seas[src];
}

// =====================================================================
extern "C" void kernel_launch(void* const* d_in, const int* in_sizes, int n_in,
                              void* d_out, int out_size, void* d_ws, size_t ws_size,
                              hipStream_t stream)
{
  (void)in_sizes; (void)n_in; (void)out_size; (void)ws_size;
  const float* history = (const float*)d_in[0];
  const float* future  = (const float*)d_in[1];
  const float* Wv_enc  = (const float*)d_in[2];
  const float* Wt_enc  = (const float*)d_in[3];
  const float* Wv_dec  = (const float*)d_in[4];
  const float* Wt_dec  = (const float*)d_in[5];
  const float* eWq = (const float*)d_in[6];
  const float* ebq = (const float*)d_in[7];
  const float* efr = (const float*)d_in[8];
  const float* efi = (const float*)d_in[9];
  const float* eWo = (const float*)d_in[10];
  const float* ebo = (const float*)d_in[11];
  const float* eW1 = (const float*)d_in[12];
  const float* eW2 = (const float*)d_in[13];
  const float* g_enc = (const float*)d_in[14];
  const float* b_enc = (const float*)d_in[15];
  const float* dWq = (const float*)d_in[16];
  const float* dbq = (const float*)d_in[17];
  const float* dfr = (const float*)d_in[18];
  const float* dfi = (const float*)d_in[19];
  const float* dWo = (const float*)d_in[20];
  const float* dbo = (const float*)d_in[21];
  const float* cWq = (const float*)d_in[22];
  const float* cbq = (const float*)d_in[23];
  const float* cWk = (const float*)d_in[24];
  const float* cbk = (const float*)d_in[25];
  const float* cfr = (const float*)d_in[26];
  const float* cfi = (const float*)d_in[27];
  const float* cWo = (const float*)d_in[28];
  const float* cbo = (const float*)d_in[29];
  const float* dW1 = (const float*)d_in[30];
  const float* dW2 = (const float*)d_in[31];
  const float* Wtr = (const float*)d_in[32];
  const float* g_dec = (const float*)d_in[33];
  const float* b_dec = (const float*)d_in[34];
  const float* Wp  = (const float*)d_in[35];
  const float* bp  = (const float*)d_in[36];

  float* ws = (float*)d_ws;
  size_t off = 0;
  auto alloc = [&](size_t n) { float* p = ws + off; off += (n + 63) & ~(size_t)63; return p; };

  const size_t SL = 1048576;
  const int CH = 4320;

  float* btrend = alloc((size_t)BB*LEN_D*NV);
  float* bTsum  = alloc((size_t)BB*LEN_D*DD);
  float* bX     = alloc((size_t)BB*LEN_D*DD);
  float* bT     = alloc((size_t)BB*LEN_D*DD);
  float* bencout= alloc((size_t)BB*LEN_E*DD);
  float* bseas  = alloc((size_t)BB*LEN_D*NV);
  float* bseasF = bseas;
  float* R      = alloc((size_t)11600000);
  float* SB     = alloc((size_t)2*SL + 128);
  float* WceS   = alloc((size_t)512*992);
  float* WcdS   = alloc((size_t)512*992);
  float* WtrcS  = alloc((size_t)384*1536);
  float* D720S  = alloc((size_t)128*736);
  float* D1080S = alloc((size_t)128*1088);
  float* I720S  = alloc((size_t)768*128);
  float* I1080S = alloc((size_t)1152*128);
  float* bxme   = alloc((size_t)BB*LEN_E*4);
  float* bxmd   = alloc((size_t)BB*LEN_D*4);
  float* bmean  = alloc((size_t)BB*NV);
  float* bpart  = alloc((size_t)BB*9*DD);
  float* bcm    = alloc((size_t)BB*DD);
  float* bmsp   = alloc((size_t)BB*10*NV);

  float* bxe = bT;   // prep alias (dead before T written)

  auto U = [](float* p) { return (u16*)p; };

  auto splitP = [&](const float* src, float* dst, int M, int K) {
    dim3 g((K + 255)/256, M);
    k_split_plain<<<g,256,0,stream>>>(src, U(dst), K, K);
  };
  auto splitC = [&](const float* src, float* dst, int r0, int Mc, int Lc, int Din,
                    int K, int Kp) {
    dim3 g((Kp + 255)/256, Mc);
    k_split_conv<<<g,256,0,stream>>>(src, U(dst), r0, Lc, Din, K, Kp);
  };
  auto splitT = [&](const float* src, float* dst, int Lc, int Kp) {
    dim3 g(Kp/32, 16, BB), b(32, 8);
    k_split_tr<<<g,b,0,stream>>>(src, U(dst), Lc, Kp);
  };
  auto red = [&](const float* p, int parts, size_t stride, const float* res,
                 float* out, size_t n) {
    k_red<<<(int)((n + 255)/256),256,0,stream>>>(p, parts, stride, res, out, n);
  };

  auto decomp = [&](const float* in, float* out, int L, bool acc) {
    size_t tot = (size_t)BB * L * DD;
    int g = (int)((tot + 255)/256);
    if (acc) k_decomp<1><<<g,256,0,stream>>>(in, out, bTsum, L);
    else     k_decomp<0><<<g,256,0,stream>>>(in, out, nullptr, L);
  };

  // FFN: out = in + gelu(in@W1.T)@W2.T ; GEMM2 split-K=2, fp32 partials in scratch
  float* SA2 = R + 2230016;   // hidden tiled pair: 4352x2048 = 8.91M floats
  auto ffn = [&](const float* in, float* out, const float* W1, const float* W2,
                 int M, float* scratch) {
    splitP(W1, SB, DFF2, DD);
    splitP(W2, SB + SL, DD, DFF2);
    for (int r0 = 0; r0 < M; r0 += CH) {
      int mc = M - r0; if (mc > CH) mc = CH;
      splitP(in + (size_t)r0*DD, R, mc, DD);
      k_mg<128,4,1,1><<<dim3(16,(mc+127)/128,1),256,0,stream>>>(
          U(R), U(SB), nullptr, nullptr, nullptr, U(SA2), mc, DFF2, DD, 0);
      k_mg<64,0,0,2><<<dim3(8,(mc+127)/128,2),256,0,stream>>>(
          U(SA2), U(SB+SL), nullptr, nullptr, scratch, nullptr, mc, DD, DFF2, 0);
      red(scratch, 2, (size_t)mc*DD, in + (size_t)r0*DD, out + (size_t)r0*DD, (size_t)mc*DD);
    }
  };

  // X += fourier_self(X); T = fp32 temp + DFT partial scratch
  auto fourier_self = [&](float* X, float* T, int L, int KpL, float* DLS, float* ILS,
                          const float* Wq, const float* bq, const float* fr, const float* fi,
                          const float* Wo, const float* bo) {
    int M = BB * L;
    size_t MN8 = (size_t)8192*128;
    float* bqf   = R + 9*SL;
    float* bselp = R + 10*SL;
    splitP(X, R, M, DD);
    splitP(Wq, SB, DD, DD);
    k_mg<128,1,0,1><<<dim3(4,(M+127)/128,1),256,0,stream>>>(
        U(R), U(SB), bq, nullptr, T, nullptr, M, DD, DD, 0);
    splitT(T, R, L, KpL);
    k_mg<64,0,0,4><<<dim3(2,64,4),256,0,stream>>>(
        U(R), U(DLS), nullptr, nullptr, T, nullptr, BB*DD, 128, KpL, 0);
    red(T, 4, MN8, nullptr, bqf, MN8);
    k_modemix<<<dim3(64,8),256,0,stream>>>(bqf, fr, fi, U(bselp), 1.0f);
    k_mg<128,0,2,1><<<dim3((L+127)/128,64,1),256,0,stream>>>(   // irfft -> pair @R
        U(bselp), U(ILS), nullptr, nullptr, nullptr, U(R), BB*DD, L, 128, L);
    splitP(Wo, SB, DD, DD);
    k_mg<128,3,0,1><<<dim3(4,(M+127)/128,1),256,0,stream>>>(
        U(R), U(SB), bo, X, X, nullptr, M, DD, DD, 0);
  };

  auto myln_pair = [&](const float* in, float* tmp, float* pairdst,
                       const float* g, const float* b, int L) {
    k_ln<<<BB*L,256,0,stream>>>(in, g, b, tmp);
    int chl = L / 9;
    k_colsum_part<<<dim3(BB,9),512,0,stream>>>(tmp, bpart, L, chl, 9);
    k_colsum_fin<<<32,256,0,stream>>>(bpart, bcm, 9, 1.f/(float)L);
    size_t n = (size_t)BB*L*DD;
    k_csub_pair<<<(int)((n+255)/256),256,0,stream>>>(tmp, bcm, U(pairdst), L);
  };

  // ---------------- prep ----------------
  k_extract_x<<<(BB*LEN_E*NV + 255)/256,256,0,stream>>>(history, bxe);
  k_marks_enc<<<(BB*LEN_E*4 + 255)/256,256,0,stream>>>(history, bxme);
  k_marks_dec<<<(BB*LEN_D*4 + 255)/256,256,0,stream>>>(future, bxme, bxmd);
  k_ms_part<<<dim3(BB,10),384,0,stream>>>(bxe, bmsp, 72, 10);
  k_ms_fin<<<(BB*NV + 255)/256,256,0,stream>>>(bmsp, bmean, 10);
  k_init_decomp<<<(BB*LEN_D*NV + 255)/256,256,0,stream>>>(bxe, bmean, bseas, btrend);
  k_build_wconvS<<<dim3(4,512),256,0,stream>>>(Wv_enc, U(WceS));
  k_build_wconvS<<<dim3(4,512),256,0,stream>>>(Wv_dec, U(WcdS));
  k_build_wtrcS<<<dim3(6,321),256,0,stream>>>(Wtr, U(WtrcS));
  k_build_dftS<<<dim3(3,128),256,0,stream>>>(U(D720S), LEN_E, 736);
  k_build_dftS<<<dim3(5,128),256,0,stream>>>(U(D1080S), LEN_D, 1088);
  k_build_irS<<<dim3(1,LEN_E),128,0,stream>>>(U(I720S), LEN_E);
  k_build_irS<<<dim3(1,LEN_D),128,0,stream>>>(U(I1080S), LEN_D);

  // ---------------- encoder ----------------
  int ME = BB * LEN_E;
  for (int r0 = 0; r0 < ME; r0 += 5760) {
    splitC(bxe, R, r0, 5760, LEN_E, NV, 963, 992);
    k_mg<128,0,0,2><<<dim3(4,45,2),256,0,stream>>>(
        U(R), U(WceS), nullptr, nullptr, bencout, nullptr, 5760, DD, 992, 0);
    red(bencout, 2, (size_t)5760*DD, nullptr, bX + (size_t)r0*DD, (size_t)5760*DD);
  }
  k_marks_add<<<(ME*DD + 255)/256,256,0,stream>>>(bX, bxme, Wt_enc, ME);

  float *X = bX, *T = bT;
  for (int i = 0; i < 2; ++i) {
    fourier_self(X, T, LEN_E, 736, D720S, I720S,
                 eWq + (size_t)i*DD*DD, ebq + (size_t)i*DD,
                 efr + (size_t)i*HHN*64*64*64, efi + (size_t)i*HHN*64*64*64,
                 eWo + (size_t)i*DD*DD, ebo + (size_t)i*DD);
    decomp(X, T, LEN_E, false);
    ffn(T, X, eW1 + (size_t)i*DFF2*DD, eW2 + (size_t)i*DD*DFF2, ME, bencout);
    decomp(X, T, LEN_E, false);
    { float* tmp = X; X = T; T = tmp; }
  }
  myln_pair(X, T, bencout, g_enc, b_enc, LEN_E);   // bencout = tiled pair (ME,512)

  // ---------------- decoder ----------------
  int MD = BB * LEN_D;
  for (int r0 = 0; r0 < MD; r0 += 8640) {
    splitC(bseas, R, r0, 8640, LEN_D, NV, 963, 992);
    k_mg<128,0,0,2><<<dim3(4,68,2),256,0,stream>>>(
        U(R), U(WcdS), nullptr, nullptr, T, nullptr, 8640, DD, 992, 0);
    red(T, 2, (size_t)8640*DD, nullptr, X + (size_t)r0*DD, (size_t)8640*DD);
  }
  k_marks_add<<<(MD*DD + 255)/256,256,0,stream>>>(X, bxmd, Wt_dec, MD);

  fourier_self(X, T, LEN_D, 1088, D1080S, I1080S, dWq, dbq, dfr, dfi, dWo, dbo);

  k_zero<<<(BB*LEN_D*DD + 255)/256,256,0,stream>>>(bTsum, BB*LEN_D*DD);
  decomp(X, T, LEN_D, true);          // x -> T, t1 acc

  // cross attention
  {
    size_t MN8 = (size_t)8192*128;
    float* bkf = R + 9*SL;
    float* bqf = R + 10*SL;
    splitP(cWk, SB, DD, DD);
    k_mg<128,1,0,1><<<dim3(4,90,1),256,0,stream>>>(
        U(bencout), U(SB), cbk, nullptr, X, nullptr, ME, DD, DD, 0);
    splitT(X, R, LEN_E, 736);
    k_mg<64,0,0,4><<<dim3(2,64,4),256,0,stream>>>(
        U(R), U(D720S), nullptr, nullptr, X, nullptr, BB*DD, 128, 736, 0);
    red(X, 4, MN8, nullptr, bkf, MN8);
    splitP(T, R, MD, DD);
    splitP(cWq, SB, DD, DD);
    k_mg<128,1,0,1><<<dim3(4,135,1),256,0,stream>>>(
        U(R), U(SB), cbq, nullptr, X, nullptr, MD, DD, DD, 0);
    splitT(X, R, LEN_D, 1088);
    k_mg<64,0,0,4><<<dim3(2,64,4),256,0,stream>>>(
        U(R), U(D1080S), nullptr, nullptr, X, nullptr, BB*DD, 128, 1088, 0);
    red(X, 4, MN8, nullptr, bqf, MN8);
    float* ba = R;
    float* bv = R + SL;
    float* bselp = R + 2*SL;
    k_cross_qk<<<BB*HHN,256,0,stream>>>(bqf, bkf, ba);
    k_cross_v<<<BB*HHN,256,0,stream>>>(ba, bkf, bv);
    k_modemix<<<dim3(64,8),256,0,stream>>>(bv, cfr, cfi, U(bselp), 1.0f/262144.0f);
    k_mg<128,0,2,1><<<dim3(9,64,1),256,0,stream>>>(        // irfft -> pair @X
        U(bselp), U(I1080S), nullptr, nullptr, nullptr, U(X), BB*DD, LEN_D, 128, LEN_D);
    splitP(cWo, SB, DD, DD);
    k_mg<128,3,0,1><<<dim3(4,135,1),256,0,stream>>>(
        U(X), U(SB), cbo, T, T, nullptr, MD, DD, DD, 0);
  }

  decomp(T, X, LEN_D, true);          // x -> X, t2 acc
  ffn(X, T, dW1, dW2, MD, bencout);   // T = x + FFN(x)
  decomp(T, X, LEN_D, true);          // x -> X, t3 acc

  myln_pair(X, T, R, g_dec, b_dec, LEN_D);   // pair @R (MD,512)
  splitP(Wp, SB, NV, DD);
  k_mg<64,1,0,1><<<dim3(6,135,1),256,0,stream>>>(
      U(R), U(SB), bp, nullptr, bseasF, nullptr, MD, NV, DD, 0);

  for (int r0 = 0; r0 < MD; r0 += 5760) {
    splitC(bTsum, R, r0, 5760, LEN_D, DD, 1536, 1536);
    k_mg<64,0,0,2><<<dim3(6,45,2),256,0,stream>>>(
        U(R), U(WtrcS), nullptr, nullptr, bX, nullptr, 5760, NV, 1536, 0);
    red(bX, 2, (size_t)5760*NV, btrend + (size_t)r0*NV, btrend + (size_t)r0*NV,
        (size_t)5760*NV);
  }

  k_final<<<(BB*LEN_E*NV + 255)/256,256,0,stream>>>(btrend, bseasF, (float*)d_out);
}

// Round 10
// 2689.317 us; speedup vs baseline: 5.2964x; 1.0630x over previous
//
#include <hip/hip_runtime.h>
#include <math.h>

#define BB 16
#define DD 512
#define HHN 8
#define LEN_E 720
#define LEN_D 1080
#define NV 321
#define DFF2 2048

typedef __attribute__((ext_vector_type(8))) short short8;
typedef __attribute__((ext_vector_type(4))) float floatx4;
typedef unsigned short u16;

__device__ __forceinline__ u16 f2bf(float v) {
  unsigned u = __builtin_bit_cast(unsigned, v);
  u += 0x7FFFu + ((u >> 16) & 1u);
  return (u16)(u >> 16);
}
__device__ __forceinline__ float bf2f(u16 h) {
  unsigned u = ((unsigned)h) << 16;
  return __builtin_bit_cast(float, u);
}

// element offset (u16) of (r,k) in tiled pair buffer; lo at +4096.
// tile = 128 rows x 32 cols, 8192 u16 (hi 4096 + lo 4096), XOR-swizzled slots.
__device__ __forceinline__ size_t toff(int r, int k, int ktn) {
  int rt = r >> 7, rr = r & 127;
  int kt = k >> 5, kk = k & 31;
  int sw = (kk >> 3) ^ (rr & 3) ^ ((rr >> 2) & 3);
  return (((size_t)(rt * ktn + kt)) << 13) + (rr << 5) + (sw << 3) + (kk & 7);
}

__device__ __forceinline__ void gload_lds(const void* g, void* l) {
  __builtin_amdgcn_global_load_lds(
      (const __attribute__((address_space(1))) unsigned int*)g,
      (__attribute__((address_space(3))) unsigned int*)l, 16, 0, 0);
}

// ---------------- prep kernels ----------------
__global__ void k_extract_x(const float* __restrict__ hist, float* __restrict__ xe) {
  int idx = blockIdx.x * 256 + threadIdx.x;
  if (idx >= BB*LEN_E*NV) return;
  xe[idx] = hist[(size_t)idx * 5];
}

__global__ void k_marks_enc(const float* __restrict__ hist, float* __restrict__ xme) {
  int idx = blockIdx.x * 256 + threadIdx.x;
  if (idx >= BB*LEN_E*4) return;
  int f = idx & 3;
  int r = idx >> 2;
  xme[idx] = hist[((size_t)r * NV) * 5 + 1 + f];
}

__global__ void k_marks_dec(const float* __restrict__ fut, const float* __restrict__ xme,
                            float* __restrict__ xmd) {
  int idx = blockIdx.x * 256 + threadIdx.x;
  if (idx >= BB*LEN_D*4) return;
  int f = idx & 3;
  int r = idx >> 2;
  int t = r % LEN_D, b = r / LEN_D;
  float v;
  if (t < 360) v = xme[((b*LEN_E) + 360 + t)*4 + f];
  else v = fut[(((size_t)(b*LEN_E + (t-360))) * NV) * 5 + 1 + f];
  xmd[idx] = v;
}

__global__ void k_ms_part(const float* __restrict__ xe, float* __restrict__ part,
                          int chl, int nch) {
  int n = threadIdx.x;
  if (n >= NV) return;
  int b = blockIdx.x, c = blockIdx.y;
  int l0 = c*chl, l1 = l0 + chl; if (l1 > LEN_E) l1 = LEN_E;
  float s = 0.f;
  for (int l = l0; l < l1; ++l) s += xe[((size_t)b*LEN_E + l)*NV + n];
  part[((size_t)b*nch + c)*NV + n] = s;
}
__global__ void k_ms_fin(const float* __restrict__ part, float* __restrict__ mb, int nch) {
  int i = blockIdx.x*256 + threadIdx.x;
  if (i >= BB*NV) return;
  int b = i / NV, n = i % NV;
  float s = 0.f;
  for (int c = 0; c < nch; ++c) s += part[((size_t)b*nch + c)*NV + n];
  mb[i] = s * (1.f/(float)LEN_E);
}

__global__ void k_init_decomp(const float* __restrict__ xe, const float* __restrict__ mb,
                              float* __restrict__ seas, float* __restrict__ trend) {
  int idx = blockIdx.x * 256 + threadIdx.x;
  if (idx >= BB*LEN_D*NV) return;
  int n = idx % NV; int r = idx / NV; int t = r % LEN_D; int b = r / LEN_D;
  if (t < 360) {
    int l = 360 + t;
    float s = 0.f;
    for (int j = -12; j <= 12; ++j) {
      int lc = l + j; if (lc > LEN_E-1) lc = LEN_E-1; if (lc < 0) lc = 0;
      s += xe[((size_t)b*LEN_E + lc)*NV + n];
    }
    float ma = s * (1.f/25.f);
    trend[idx] = ma;
    seas[idx]  = xe[((size_t)b*LEN_E + l)*NV + n] - ma;
  } else {
    trend[idx] = mb[b*NV + n];
    seas[idx]  = 0.f;
  }
}

__global__ void k_marks_add(float* __restrict__ X, const float* __restrict__ xm,
                            const float* __restrict__ Wt, int M) {
  int idx = blockIdx.x*256 + threadIdx.x;
  if (idx >= M*DD) return;
  int d = idx & 511, r = idx >> 9;
  const float* m4 = xm + (size_t)r*4;
  const float* w4 = Wt + (size_t)d*4;
  X[idx] += m4[0]*w4[0] + m4[1]*w4[1] + m4[2]*w4[2] + m4[3]*w4[3];
}

// ---------------- split builders (tiled pair output) ----------------
__global__ void k_split_plain(const float* __restrict__ src, u16* __restrict__ dst,
                              int K, int Kp) {
  int col = blockIdx.x*256 + threadIdx.x;
  if (col >= Kp) return;
  int r = blockIdx.y;
  float v = (col < K) ? src[(size_t)r*K + col] : 0.f;
  u16 hh = f2bf(v);
  size_t o = toff(r, col, Kp >> 5);
  dst[o] = hh; dst[o + 4096] = f2bf(v - bf2f(hh));
}

__global__ void k_split_conv(const float* __restrict__ src, u16* __restrict__ dst,
                             int r0, int Lc, int Din, int K, int Kp) {
  int col = blockIdx.x*256 + threadIdx.x;
  if (col >= Kp) return;
  int rr = blockIdx.y;
  int r = r0 + rr;
  int b = r / Lc, t = r - b*Lc;
  float v = 0.f;
  if (col < K) {
    int c = (col >= 2*Din) ? 2 : ((col >= Din) ? 1 : 0);
    int n = col - c*Din;
    int tt = t + c - 1;
    if (tt < 0) tt = Lc - 1; else if (tt >= Lc) tt = 0;
    v = src[((size_t)(b*Lc + tt))*Din + n];
  }
  u16 hh = f2bf(v);
  size_t o = toff(rr, col, Kp >> 5);
  dst[o] = hh; dst[o + 4096] = f2bf(v - bf2f(hh));
}

__global__ void k_split_tr(const float* __restrict__ src, u16* __restrict__ dst,
                           int Lc, int Kp) {
  __shared__ float t[32][33];
  int b = blockIdx.z;
  int l0 = blockIdx.x*32, c0 = blockIdx.y*32;
  int lx = threadIdx.x, ly = threadIdx.y;   // (32,8)
  #pragma unroll
  for (int i = 0; i < 4; ++i) {
    int ll = l0 + ly + i*8;
    t[ly + i*8][lx] = (ll < Lc) ? src[((size_t)b*Lc + ll)*DD + c0 + lx] : 0.f;
  }
  __syncthreads();
  int ktn = Kp >> 5;
  #pragma unroll
  for (int i = 0; i < 4; ++i) {
    int ch = c0 + ly + i*8;
    int ll = l0 + lx;
    float v = t[lx][ly + i*8];
    u16 hh = f2bf(v);
    size_t o = toff(b*DD + ch, ll, ktn);
    dst[o] = hh; dst[o + 4096] = f2bf(v - bf2f(hh));
  }
}

__global__ void k_build_wconvS(const float* __restrict__ Wv, u16* __restrict__ dst) {
  int col = blockIdx.x*256 + threadIdx.x;
  if (col >= 992) return;
  int d = blockIdx.y;
  float v = 0.f;
  if (col < 963) {
    int c = (col >= 642) ? 2 : ((col >= 321) ? 1 : 0);
    int n = col - c*321;
    v = Wv[(size_t)d*963 + n*3 + c];
  }
  u16 hh = f2bf(v);
  size_t o = toff(d, col, 31);
  dst[o] = hh; dst[o + 4096] = f2bf(v - bf2f(hh));
}

__global__ void k_build_wtrcS(const float* __restrict__ Wtr, u16* __restrict__ dst) {
  int col = blockIdx.x*256 + threadIdx.x;
  if (col >= 1536) return;
  int n = blockIdx.y;
  int c = col >> 9, d = col & 511;
  float v = Wtr[(size_t)n*1536 + d*3 + c];
  u16 hh = f2bf(v);
  size_t o = toff(n, col, 48);
  dst[o] = hh; dst[o + 4096] = f2bf(v - bf2f(hh));
}

__global__ void k_build_dftS(u16* __restrict__ dst, int L, int Kp) {
  int col = blockIdx.x*256 + threadIdx.x;
  if (col >= Kp) return;
  int mr = blockIdx.y;
  float v = 0.f;
  if (col < L) {
    int m = mr & 63;
    int ph = (m * col) % L;
    float th = 6.2831853071795864f * ((float)ph / (float)L);
    v = (mr < 64) ? cosf(th) : -sinf(th);
  }
  u16 hh = f2bf(v);
  size_t o = toff(mr, col, Kp >> 5);
  dst[o] = hh; dst[o + 4096] = f2bf(v - bf2f(hh));
}

__global__ void k_build_irS(u16* __restrict__ dst, int L) {
  int k = threadIdx.x;   // 0..127
  int ll = blockIdx.y;
  int m = k & 63;
  int ph = (m * ll) % L;
  float th = 6.2831853071795864f * ((float)ph / (float)L);
  float v;
  if (k < 64) v = (m == 0) ? (1.f/(float)L) : (2.f/(float)L) * cosf(th);
  else        v = (m == 0) ? 0.f            : -(2.f/(float)L) * sinf(th);
  u16 hh = f2bf(v);
  size_t o = toff(ll, k, 4);
  dst[o] = hh; dst[o + 4096] = f2bf(v - bf2f(hh));
}

// ---------------- MFMA GEMM: global_load_lds staging of pre-tiled operands ----
template<int TN, int EPI, int WOUT, int KS>
__global__ __launch_bounds__(256)
void k_mg(const u16* __restrict__ A, const u16* __restrict__ B,
          const float* __restrict__ bias, const float* __restrict__ res,
          float* __restrict__ C, u16* __restrict__ Cout,
          int M, int Nc, int K, int Lout)
{
  __shared__ __attribute__((aligned(16))) u16 sA[8192];
  __shared__ __attribute__((aligned(16))) u16 sB[(TN == 128) ? 8192 : 4096];

  const int tid  = threadIdx.x;
  const int lane = tid & 63;
  const int wave = tid >> 6;
  const int lr   = lane & 15;
  const int kg   = lane >> 4;

  const int gx  = gridDim.x;
  const int nwg = gx * gridDim.y;
  const int lid = blockIdx.y * gx + blockIdx.x;
  const int q8  = nwg >> 3, r8 = nwg & 7;
  const int xcd = lid & 7, i8 = lid >> 3;
  const int swz = (xcd < r8 ? xcd*(q8+1) : r8*(q8+1) + (xcd - r8)*q8) + i8;
  const int row0 = (swz / gx) * 128;
  const int col0 = (swz % gx) * TN;

  constexpr int MF = (TN == 128) ? 4 : 2;
  const int wr = (TN == 128) ? (wave >> 1) : wave;
  const int wc = (TN == 128) ? (wave & 1) : 0;

  const int ksteps = K >> 5;
  const int zz = (KS > 1) ? (int)blockIdx.z : 0;
  const int t0 = (KS > 1) ? (int)(((long long)ksteps * zz) / KS) : 0;
  const int t1 = (KS > 1) ? (int)(((long long)ksteps * (zz+1)) / KS) : ksteps;

  const char* gA = (const char*)(A + (((size_t)(row0 >> 7) * ksteps) << 13));
  const char* gB = (const char*)(B + (((size_t)(col0 >> 7) * ksteps) << 13));
  const int bhalf = (TN == 64) ? ((col0 & 64) << 6) : 0;   // 0 or 4096 bytes

  char* lA = (char*)sA;
  char* lB = (char*)sB;
  const int wl = (wave << 10) + (lane << 4);
  const int wb = (wave << 10);

  floatx4 acc[MF][4] = {};

  for (int kt = t0; kt < t1; ++kt) {
    {
      const char* ta = gA + ((size_t)kt << 14);
      #pragma unroll
      for (int c = 0; c < 4; ++c)
        gload_lds(ta + (c << 12) + wl, lA + (c << 12) + wb);
    }
    if (TN == 128) {
      const char* tb = gB + ((size_t)kt << 14);
      #pragma unroll
      for (int c = 0; c < 4; ++c)
        gload_lds(tb + (c << 12) + wl, lB + (c << 12) + wb);
    } else {
      const char* tb = gB + ((size_t)kt << 14) + bhalf;
      gload_lds(tb + wl, lB + wb);
      gload_lds(tb + 8192 + wl, lB + 4096 + wb);
    }
    __syncthreads();

    short8 ahf[MF], alf[MF], bhf[4], blf[4];
    #pragma unroll
    for (int f = 0; f < MF; ++f) {
      int row = wr*(MF*16) + f*16 + lr;
      int sw = kg ^ (row & 3) ^ ((row >> 2) & 3);
      int off = (row << 5) + (sw << 3);
      ahf[f] = *(const short8*)&sA[off];
      alf[f] = *(const short8*)&sA[4096 + off];
    }
    #pragma unroll
    for (int n = 0; n < 4; ++n) {
      int row = wc*64 + n*16 + lr;
      int sw = kg ^ (row & 3) ^ ((row >> 2) & 3);
      int off = (row << 5) + (sw << 3);
      bhf[n] = *(const short8*)&sB[off];
      blf[n] = *(const short8*)&sB[((TN == 128) ? 4096 : 2048) + off];
    }
    #pragma unroll
    for (int mf = 0; mf < MF; ++mf)
      #pragma unroll
      for (int nf = 0; nf < 4; ++nf) {
        acc[mf][nf] = __builtin_amdgcn_mfma_f32_16x16x32_bf16(ahf[mf], bhf[nf], acc[mf][nf], 0, 0, 0);
        acc[mf][nf] = __builtin_amdgcn_mfma_f32_16x16x32_bf16(ahf[mf], blf[nf], acc[mf][nf], 0, 0, 0);
        acc[mf][nf] = __builtin_amdgcn_mfma_f32_16x16x32_bf16(alf[mf], bhf[nf], acc[mf][nf], 0, 0, 0);
      }
    __syncthreads();
  }

  if (KS > 1) {
    float* Cp = C + (size_t)zz * ((size_t)M * Nc);
    #pragma unroll
    for (int nf = 0; nf < 4; ++nf) {
      int cN = col0 + wc*64 + nf*16 + lr;
      if (cN >= Nc) continue;
      #pragma unroll
      for (int mf = 0; mf < MF; ++mf)
        #pragma unroll
        for (int i = 0; i < 4; ++i) {
          int rM = row0 + wr*(MF*16) + mf*16 + kg*4 + i;
          if (rM >= M) continue;
          Cp[(size_t)rM * Nc + cN] = acc[mf][nf][i];
        }
    }
  } else {
    #pragma unroll
    for (int nf = 0; nf < 4; ++nf) {
      int cN = col0 + wc*64 + nf*16 + lr;
      if (cN >= Nc) continue;
      #pragma unroll
      for (int mf = 0; mf < MF; ++mf) {
        #pragma unroll
        for (int i = 0; i < 4; ++i) {
          int rM = row0 + wr*(MF*16) + mf*16 + kg*4 + i;
          if (rM >= M) continue;
          float v = acc[mf][nf][i];
          if (EPI & 1) v += bias[cN];
          if (EPI & 4) v = 0.5f * v * (1.f + erff(v * 0.7071067811865476f));
          if (EPI & 2) v += res[(size_t)rM * Nc + cN];
          if (WOUT == 1) {
            u16 hh = f2bf(v);
            size_t o = toff(rM, cN, Nc >> 5);
            Cout[o] = hh; Cout[o + 4096] = f2bf(v - bf2f(hh));
          } else if (WOUT == 2) {
            int b = rM >> 9, ch = rM & 511;
            int fl = ch * Lout + cN;
            int r2 = b * Lout + (fl >> 9);
            int c2 = fl & 511;
            u16 hh = f2bf(v);
            size_t o = toff(r2, c2, 16);
            Cout[o] = hh; Cout[o + 4096] = f2bf(v - bf2f(hh));
          } else {
            C[(size_t)rM * Nc + cN] = v;
          }
        }
      }
    }
  }
}

// ---------------- split-K reduce (fixed order, deterministic) ----------------
__global__ void k_red(const float* __restrict__ p, int parts, size_t stride,
                      const float* __restrict__ res, float* __restrict__ out, size_t n) {
  size_t i = (size_t)blockIdx.x*256 + threadIdx.x;
  if (i >= n) return;
  float s = res ? res[i] : 0.f;
  for (int z = 0; z < parts; ++z) s += p[(size_t)z*stride + i];
  out[i] = s;
}

// ---------------- mode mix (emits tiled bf16 pair) ----------------
__global__ __launch_bounds__(256)
void k_modemix(const float* __restrict__ ftbuf, const float* __restrict__ fr,
               const float* __restrict__ fi, u16* __restrict__ sel, float scale)
{
  int m = blockIdx.x, h = blockIdx.y;
  __shared__ float wr[64][64], wi[64][64];
  __shared__ float qr[BB][64], qi[BB][64];
  int tid = threadIdx.x;
  for (int it = 0; it < 16; ++it) {
    int idx = tid + it*256;
    int e = idx >> 6, o = idx & 63;
    size_t wof = ((((size_t)h*64 + e)*64 + o) << 6) + m;
    wr[e][o] = fr[wof]; wi[e][o] = fi[wof];
  }
  for (int it = 0; it < 4; ++it) {
    int idx = tid + it*256;
    int bb = idx >> 6, e = idx & 63;
    size_t qof = ((size_t)bb*DD + h*64 + e)*128 + m;
    qr[bb][e] = ftbuf[qof]; qi[bb][e] = ftbuf[qof + 64];
  }
  __syncthreads();
  for (int it = 0; it < 4; ++it) {
    int idx = tid + it*256;
    int bb = idx >> 6, o = idx & 63;
    float ar = 0.f, ai = 0.f;
    for (int e = 0; e < 64; ++e) {
      float xr = qr[bb][e], xi = qi[bb][e], yr = wr[e][o], yi = wi[e][o];
      ar += xr*yr - xi*yi;
      ai += xr*yi + xi*yr;
    }
    int row = bb*DD + h*64 + o;
    float vr = ar*scale, vi2 = ai*scale;
    u16 hr = f2bf(vr);
    size_t o1 = toff(row, m, 4);
    sel[o1] = hr; sel[o1 + 4096] = f2bf(vr - bf2f(hr));
    u16 hi2 = f2bf(vi2);
    size_t o2 = toff(row, m + 64, 4);
    sel[o2] = hi2; sel[o2 + 4096] = f2bf(vi2 - bf2f(hi2));
  }
}

// ---------------- cross attention ----------------
__global__ __launch_bounds__(256)
void k_cross_qk(const float* __restrict__ qf, const float* __restrict__ kf,
                float* __restrict__ ab)
{
  int bh = blockIdx.x; int b = bh >> 3, h = bh & 7;
  __shared__ float qr[32][64], qi[32][64], kr[32][64], ki[32][64];
  int tid = threadIdx.x;
  int tx = tid & 15, ty = tid >> 4;
  float ar[4][4] = {}, ai[4][4] = {};
  for (int e0 = 0; e0 < 64; e0 += 32) {
    for (int it = 0; it < 8; ++it) {
      int idx = tid + it*256;
      int e = idx >> 6, x = idx & 63;
      size_t rof = ((size_t)b*DD + h*64 + e0 + e)*128;
      qr[e][x] = qf[rof + x]; qi[e][x] = qf[rof + 64 + x];
      kr[e][x] = kf[rof + x]; ki[e][x] = kf[rof + 64 + x];
    }
    __syncthreads();
    for (int e = 0; e < 32; ++e) {
      float xr[4], xi2[4], yr[4], yi[4];
      #pragma unroll
      for (int i = 0; i < 4; ++i) { xr[i] = qr[e][ty*4+i]; xi2[i] = qi[e][ty*4+i]; }
      #pragma unroll
      for (int j = 0; j < 4; ++j) { yr[j] = kr[e][tx*4+j]; yi[j] = ki[e][tx*4+j]; }
      #pragma unroll
      for (int i = 0; i < 4; ++i)
        #pragma unroll
        for (int j = 0; j < 4; ++j) {
          ar[i][j] += xr[i]*yr[j] - xi2[i]*yi[j];
          ai[i][j] += xr[i]*yi[j] + xi2[i]*yr[j];
        }
    }
    __syncthreads();
  }
  #pragma unroll
  for (int i = 0; i < 4; ++i)
    #pragma unroll
    for (int j = 0; j < 4; ++j) {
      float txv = tanhf(ar[i][j]);
      float tyv = tanf(ai[i][j]);
      float den = 1.f + txv*txv*tyv*tyv;
      float re = txv*(1.f + tyv*tyv) / den;
      float im = tyv*(1.f - txv*txv) / den;
      size_t of = ((size_t)bh*64 + (ty*4+i))*128 + tx*4 + j;
      ab[of] = re; ab[of + 64] = im;
    }
}

__global__ __launch_bounds__(256)
void k_cross_v(const float* __restrict__ ab, const float* __restrict__ kf,
               float* __restrict__ v)
{
  int bh = blockIdx.x; int b = bh >> 3, h = bh & 7;
  __shared__ float ar[64][32], ai[64][32], kr[64][32], ki[64][32];
  int tid = threadIdx.x;
  int tx = tid & 15, ty = tid >> 4;
  float vr[4][4] = {}, vi[4][4] = {};
  for (int y0 = 0; y0 < 64; y0 += 32) {
    for (int it = 0; it < 8; ++it) {
      int idx = tid + it*256;
      int r = idx >> 5, y = idx & 31;
      ar[r][y] = ab[((size_t)bh*64 + r)*128 + y0 + y];
      ai[r][y] = ab[((size_t)bh*64 + r)*128 + 64 + y0 + y];
      kr[r][y] = kf[((size_t)b*DD + h*64 + r)*128 + y0 + y];
      ki[r][y] = kf[((size_t)b*DD + h*64 + r)*128 + 64 + y0 + y];
    }
    __syncthreads();
    for (int y = 0; y < 32; ++y) {
      float er[4], ei[4], xr[4], xi2[4];
      #pragma unroll
      for (int i = 0; i < 4; ++i) { er[i] = kr[ty*4+i][y]; ei[i] = ki[ty*4+i][y]; }
      #pragma unroll
      for (int j = 0; j < 4; ++j) { xr[j] = ar[tx*4+j][y]; xi2[j] = ai[tx*4+j][y]; }
      #pragma unroll
      for (int i = 0; i < 4; ++i)
        #pragma unroll
        for (int j = 0; j < 4; ++j) {
          vr[i][j] += xr[j]*er[i] - xi2[j]*ei[i];
          vi[i][j] += xr[j]*ei[i] + xi2[j]*er[i];
        }
    }
    __syncthreads();
  }
  #pragma unroll
  for (int i = 0; i < 4; ++i)
    #pragma unroll
    for (int j = 0; j < 4; ++j) {
      size_t of = ((size_t)b*DD + h*64 + ty*4 + i)*128 + tx*4 + j;
      v[of] = vr[i][j]; v[of + 64] = vi[i][j];
    }
}

// ---------------- LN + column-mean subtract ----------------
__global__ __launch_bounds__(256)
void k_ln(const float* __restrict__ x, const float* __restrict__ g,
          const float* __restrict__ be, float* __restrict__ out)
{
  int r = blockIdx.x; int tid = threadIdx.x;
  float v1 = x[(size_t)r*DD + tid], v2 = x[(size_t)r*DD + 256 + tid];
  float s = v1 + v2, s2 = v1*v1 + v2*v2;
  #pragma unroll
  for (int off = 32; off; off >>= 1) { s += __shfl_down(s, off, 64); s2 += __shfl_down(s2, off, 64); }
  __shared__ float red[8];
  int wid = tid >> 6, lane = tid & 63;
  if (lane == 0) { red[wid] = s; red[4 + wid] = s2; }
  __syncthreads();
  if (tid == 0) {
    float a = red[0]+red[1]+red[2]+red[3];
    float b2 = red[4]+red[5]+red[6]+red[7];
    float mu = a / 512.f;
    float var = b2 / 512.f - mu*mu;
    red[0] = mu; red[1] = rsqrtf(var + 1e-5f);
  }
  __syncthreads();
  float mu = red[0], inv = red[1];
  out[(size_t)r*DD + tid]       = (v1 - mu)*inv*g[tid]       + be[tid];
  out[(size_t)r*DD + 256 + tid] = (v2 - mu)*inv*g[256 + tid] + be[256 + tid];
}

__global__ void k_colsum_part(const float* __restrict__ x, float* __restrict__ part,
                              int L, int chl, int nch) {
  int d = threadIdx.x;
  int b = blockIdx.x, c = blockIdx.y;
  int l0 = c*chl, l1 = l0 + chl; if (l1 > L) l1 = L;
  float s = 0.f;
  for (int l = l0; l < l1; ++l) s += x[(((size_t)b*L + l) << 9) + d];
  part[((size_t)(b*nch + c) << 9) + d] = s;
}
__global__ void k_colsum_fin(const float* __restrict__ part, float* __restrict__ cm,
                             int nch, float inv) {
  int i = blockIdx.x*256 + threadIdx.x;
  int b = i >> 9, d = i & 511;
  float s = 0.f;
  for (int c = 0; c < nch; ++c) s += part[((size_t)(b*nch + c) << 9) + d];
  cm[i] = s * inv;
}
__global__ void k_csub_pair(const float* __restrict__ x, const float* __restrict__ cm,
                            u16* __restrict__ dst, int L) {
  size_t idx = (size_t)blockIdx.x*256 + threadIdx.x;
  if (idx >= (size_t)BB*L*DD) return;
  int d = (int)(idx & 511);
  int r = (int)(idx >> 9);
  int b = r / L;
  float v = x[idx] - cm[(b << 9) | d];
  u16 hh = f2bf(v);
  size_t o = toff(r, d, 16);
  dst[o] = hh; dst[o + 4096] = f2bf(v - bf2f(hh));
}

// ---------------- series decomp: sliding-window running sum ----------------
// thread = (b, d); each processes chl consecutive l values.
// ACC: 0 none; 1 tsum += ma; 2 tsum = ma (first accumulation, no read).
template<int ACC>
__global__ __launch_bounds__(512)
void k_decomp(const float* __restrict__ x, float* __restrict__ out,
              float* __restrict__ tsum, int L, int chl)
{
  int d = threadIdx.x;            // 512
  int b = blockIdx.x;
  int l0 = blockIdx.y * chl;
  int l1 = l0 + chl; if (l1 > L) l1 = L;
  const float* xb = x + (((size_t)b*L) << 9) + d;
  float s = 0.f;
  #pragma unroll
  for (int j = -12; j <= 12; ++j) {
    int lc = l0 + j; lc = lc < 0 ? 0 : (lc >= L ? L-1 : lc);
    s += xb[(size_t)lc << 9];
  }
  for (int l = l0; l < l1; ++l) {
    size_t o = (((size_t)(b*L + l)) << 9) + d;
    float ma = s * (1.f/25.f);
    out[o] = xb[(size_t)l << 9] - ma;
    if (ACC == 1) tsum[o] += ma;
    if (ACC == 2) tsum[o] = ma;
    int la = l + 13; if (la >= L) la = L - 1;
    int lr = l - 12; if (lr < 0) lr = 0;
    s += xb[(size_t)la << 9] - xb[(size_t)lr << 9];
  }
}

// ---------------- final ----------------
__global__ void k_final(const float* __restrict__ trend, const float* __restrict__ seas,
                        float* __restrict__ out) {
  int idx = blockIdx.x*256 + threadIdx.x;
  if (idx >= BB*LEN_E*NV) return;
  int n = idx % NV; int r = idx / NV; int t = r % LEN_E; int b = r / LEN_E;
  size_t src = ((size_t)b*LEN_D + 360 + t)*NV + n;
  out[idx] = trend[src] + seas[src];
}

// =====================================================================
extern "C" void kernel_launch(void* const* d_in, const int* in_sizes, int n_in,
                              void* d_out, int out_size, void* d_ws, size_t ws_size,
                              hipStream_t stream)
{
  (void)in_sizes; (void)n_in; (void)out_size; (void)ws_size;
  const float* history = (const float*)d_in[0];
  const float* future  = (const float*)d_in[1];
  const float* Wv_enc  = (const float*)d_in[2];
  const float* Wt_enc  = (const float*)d_in[3];
  const float* Wv_dec  = (const float*)d_in[4];
  const float* Wt_dec  = (const float*)d_in[5];
  const float* eWq = (const float*)d_in[6];
  const float* ebq = (const float*)d_in[7];
  const float* efr = (const float*)d_in[8];
  const float* efi = (const float*)d_in[9];
  const float* eWo = (const float*)d_in[10];
  const float* ebo = (const float*)d_in[11];
  const float* eW1 = (const float*)d_in[12];
  const float* eW2 = (const float*)d_in[13];
  const float* g_enc = (const float*)d_in[14];
  const float* b_enc = (const float*)d_in[15];
  const float* dWq = (const float*)d_in[16];
  const float* dbq = (const float*)d_in[17];
  const float* dfr = (const float*)d_in[18];
  const float* dfi = (const float*)d_in[19];
  const float* dWo = (const float*)d_in[20];
  const float* dbo = (const float*)d_in[21];
  const float* cWq = (const float*)d_in[22];
  const float* cbq = (const float*)d_in[23];
  const float* cWk = (const float*)d_in[24];
  const float* cbk = (const float*)d_in[25];
  const float* cfr = (const float*)d_in[26];
  const float* cfi = (const float*)d_in[27];
  const float* cWo = (const float*)d_in[28];
  const float* cbo = (const float*)d_in[29];
  const float* dW1 = (const float*)d_in[30];
  const float* dW2 = (const float*)d_in[31];
  const float* Wtr = (const float*)d_in[32];
  const float* g_dec = (const float*)d_in[33];
  const float* b_dec = (const float*)d_in[34];
  const float* Wp  = (const float*)d_in[35];
  const float* bp  = (const float*)d_in[36];

  float* ws = (float*)d_ws;
  size_t off = 0;
  auto alloc = [&](size_t n) { float* p = ws + off; off += (n + 63) & ~(size_t)63; return p; };

  const size_t SL = 1048576;
  const int CH = 4320;

  float* btrend = alloc((size_t)BB*LEN_D*NV);
  float* bTsum  = alloc((size_t)BB*LEN_D*DD);
  float* bX     = alloc((size_t)BB*LEN_D*DD);
  float* bT     = alloc((size_t)BB*LEN_D*DD);
  float* bencout= alloc((size_t)BB*LEN_E*DD);
  float* bseas  = alloc((size_t)BB*LEN_D*NV);
  float* bseasF = bseas;
  float* R      = alloc((size_t)11600000);
  float* SB     = alloc((size_t)2*SL + 128);
  float* WceS   = alloc((size_t)512*992);
  float* WcdS   = alloc((size_t)512*992);
  float* WtrcS  = alloc((size_t)384*1536);
  float* D720S  = alloc((size_t)128*736);
  float* D1080S = alloc((size_t)128*1088);
  float* I720S  = alloc((size_t)768*128);
  float* I1080S = alloc((size_t)1152*128);
  float* bxme   = alloc((size_t)BB*LEN_E*4);
  float* bxmd   = alloc((size_t)BB*LEN_D*4);
  float* bmean  = alloc((size_t)BB*NV);
  float* bpart  = alloc((size_t)BB*9*DD);
  float* bcm    = alloc((size_t)BB*DD);
  float* bmsp   = alloc((size_t)BB*10*NV);

  float* bxe = bT;   // prep alias (dead before T written)

  auto U = [](float* p) { return (u16*)p; };

  auto splitP = [&](const float* src, float* dst, int M, int K) {
    dim3 g((K + 255)/256, M);
    k_split_plain<<<g,256,0,stream>>>(src, U(dst), K, K);
  };
  auto splitC = [&](const float* src, float* dst, int r0, int Mc, int Lc, int Din,
                    int K, int Kp) {
    dim3 g((Kp + 255)/256, Mc);
    k_split_conv<<<g,256,0,stream>>>(src, U(dst), r0, Lc, Din, K, Kp);
  };
  auto splitT = [&](const float* src, float* dst, int Lc, int Kp) {
    dim3 g(Kp/32, 16, BB), b(32, 8);
    k_split_tr<<<g,b,0,stream>>>(src, U(dst), Lc, Kp);
  };
  auto red = [&](const float* p, int parts, size_t stride, const float* res,
                 float* out, size_t n) {
    k_red<<<(int)((n + 255)/256),256,0,stream>>>(p, parts, stride, res, out, n);
  };

  // decomp: acc 0=no tsum, 1=tsum+=, 2=tsum=
  auto decomp = [&](const float* in, float* out, int L, int acc) {
    int chl = 45;
    int nch = (L + chl - 1) / chl;
    dim3 g(BB, nch);
    if (acc == 1)      k_decomp<1><<<g,512,0,stream>>>(in, out, bTsum, L, chl);
    else if (acc == 2) k_decomp<2><<<g,512,0,stream>>>(in, out, bTsum, L, chl);
    else               k_decomp<0><<<g,512,0,stream>>>(in, out, nullptr, L, chl);
  };

  // FFN: out = in + gelu(in@W1.T)@W2.T ; GEMM2 split-K=2, fp32 partials in scratch
  float* SA2 = R + 2230016;   // hidden tiled pair
  auto ffn = [&](const float* in, float* out, const float* W1, const float* W2,
                 int M, float* scratch) {
    splitP(W1, SB, DFF2, DD);
    splitP(W2, SB + SL, DD, DFF2);
    for (int r0 = 0; r0 < M; r0 += CH) {
      int mc = M - r0; if (mc > CH) mc = CH;
      splitP(in + (size_t)r0*DD, R, mc, DD);
      k_mg<128,4,1,1><<<dim3(16,(mc+127)/128,1),256,0,stream>>>(
          U(R), U(SB), nullptr, nullptr, nullptr, U(SA2), mc, DFF2, DD, 0);
      k_mg<64,0,0,2><<<dim3(8,(mc+127)/128,2),256,0,stream>>>(
          U(SA2), U(SB+SL), nullptr, nullptr, scratch, nullptr, mc, DD, DFF2, 0);
      red(scratch, 2, (size_t)mc*DD, in + (size_t)r0*DD, out + (size_t)r0*DD, (size_t)mc*DD);
    }
  };

  // X += fourier_self(X); T = fp32 temp + DFT partial scratch
  auto fourier_self = [&](float* X, float* T, int L, int KpL, float* DLS, float* ILS,
                          const float* Wq, const float* bq, const float* fr, const float* fi,
                          const float* Wo, const float* bo) {
    int M = BB * L;
    size_t MN8 = (size_t)8192*128;
    float* bqf   = R + 9*SL;
    float* bselp = R + 10*SL;
    splitP(X, R, M, DD);
    splitP(Wq, SB, DD, DD);
    k_mg<128,1,0,1><<<dim3(4,(M+127)/128,1),256,0,stream>>>(
        U(R), U(SB), bq, nullptr, T, nullptr, M, DD, DD, 0);
    splitT(T, R, L, KpL);
    k_mg<64,0,0,4><<<dim3(2,64,4),256,0,stream>>>(
        U(R), U(DLS), nullptr, nullptr, T, nullptr, BB*DD, 128, KpL, 0);
    red(T, 4, MN8, nullptr, bqf, MN8);
    k_modemix<<<dim3(64,8),256,0,stream>>>(bqf, fr, fi, U(bselp), 1.0f);
    k_mg<128,0,2,1><<<dim3((L+127)/128,64,1),256,0,stream>>>(   // irfft -> pair @R
        U(bselp), U(ILS), nullptr, nullptr, nullptr, U(R), BB*DD, L, 128, L);
    splitP(Wo, SB, DD, DD);
    k_mg<128,3,0,1><<<dim3(4,(M+127)/128,1),256,0,stream>>>(
        U(R), U(SB), bo, X, X, nullptr, M, DD, DD, 0);
  };

  auto myln_pair = [&](const float* in, float* tmp, float* pairdst,
                       const float* g, const float* b, int L) {
    k_ln<<<BB*L,256,0,stream>>>(in, g, b, tmp);
    int chl = L / 9;
    k_colsum_part<<<dim3(BB,9),512,0,stream>>>(tmp, bpart, L, chl, 9);
    k_colsum_fin<<<32,256,0,stream>>>(bpart, bcm, 9, 1.f/(float)L);
    size_t n = (size_t)BB*L*DD;
    k_csub_pair<<<(int)((n+255)/256),256,0,stream>>>(tmp, bcm, U(pairdst), L);
  };

  // ---------------- prep ----------------
  k_extract_x<<<(BB*LEN_E*NV + 255)/256,256,0,stream>>>(history, bxe);
  k_marks_enc<<<(BB*LEN_E*4 + 255)/256,256,0,stream>>>(history, bxme);
  k_marks_dec<<<(BB*LEN_D*4 + 255)/256,256,0,stream>>>(future, bxme, bxmd);
  k_ms_part<<<dim3(BB,10),384,0,stream>>>(bxe, bmsp, 72, 10);
  k_ms_fin<<<(BB*NV + 255)/256,256,0,stream>>>(bmsp, bmean, 10);
  k_init_decomp<<<(BB*LEN_D*NV + 255)/256,256,0,stream>>>(bxe, bmean, bseas, btrend);
  k_build_wconvS<<<dim3(4,512),256,0,stream>>>(Wv_enc, U(WceS));
  k_build_wconvS<<<dim3(4,512),256,0,stream>>>(Wv_dec, U(WcdS));
  k_build_wtrcS<<<dim3(6,321),256,0,stream>>>(Wtr, U(WtrcS));
  k_build_dftS<<<dim3(3,128),256,0,stream>>>(U(D720S), LEN_E, 736);
  k_build_dftS<<<dim3(5,128),256,0,stream>>>(U(D1080S), LEN_D, 1088);
  k_build_irS<<<dim3(1,LEN_E),128,0,stream>>>(U(I720S), LEN_E);
  k_build_irS<<<dim3(1,LEN_D),128,0,stream>>>(U(I1080S), LEN_D);

  // ---------------- encoder ----------------
  int ME = BB * LEN_E;
  for (int r0 = 0; r0 < ME; r0 += 5760) {
    splitC(bxe, R, r0, 5760, LEN_E, NV, 963, 992);
    k_mg<128,0,0,2><<<dim3(4,45,2),256,0,stream>>>(
        U(R), U(WceS), nullptr, nullptr, bencout, nullptr, 5760, DD, 992, 0);
    red(bencout, 2, (size_t)5760*DD, nullptr, bX + (size_t)r0*DD, (size_t)5760*DD);
  }
  k_marks_add<<<(ME*DD + 255)/256,256,0,stream>>>(bX, bxme, Wt_enc, ME);

  float *X = bX, *T = bT;
  for (int i = 0; i < 2; ++i) {
    fourier_self(X, T, LEN_E, 736, D720S, I720S,
                 eWq + (size_t)i*DD*DD, ebq + (size_t)i*DD,
                 efr + (size_t)i*HHN*64*64*64, efi + (size_t)i*HHN*64*64*64,
                 eWo + (size_t)i*DD*DD, ebo + (size_t)i*DD);
    decomp(X, T, LEN_E, 0);
    ffn(T, X, eW1 + (size_t)i*DFF2*DD, eW2 + (size_t)i*DD*DFF2, ME, bencout);
    decomp(X, T, LEN_E, 0);
    { float* tmp = X; X = T; T = tmp; }
  }
  myln_pair(X, T, bencout, g_enc, b_enc, LEN_E);   // bencout = tiled pair (ME,512)

  // ---------------- decoder ----------------
  int MD = BB * LEN_D;
  for (int r0 = 0; r0 < MD; r0 += 8640) {
    splitC(bseas, R, r0, 8640, LEN_D, NV, 963, 992);
    k_mg<128,0,0,2><<<dim3(4,68,2),256,0,stream>>>(
        U(R), U(WcdS), nullptr, nullptr, T, nullptr, 8640, DD, 992, 0);
    red(T, 2, (size_t)8640*DD, nullptr, X + (size_t)r0*DD, (size_t)8640*DD);
  }
  k_marks_add<<<(MD*DD + 255)/256,256,0,stream>>>(X, bxmd, Wt_dec, MD);

  fourier_self(X, T, LEN_D, 1088, D1080S, I1080S, dWq, dbq, dfr, dfi, dWo, dbo);

  decomp(X, T, LEN_D, 2);             // x -> T, tsum = t1 (first write)

  // cross attention
  {
    size_t MN8 = (size_t)8192*128;
    float* bkf = R + 9*SL;
    float* bqf = R + 10*SL;
    splitP(cWk, SB, DD, DD);
    k_mg<128,1,0,1><<<dim3(4,90,1),256,0,stream>>>(
        U(bencout), U(SB), cbk, nullptr, X, nullptr, ME, DD, DD, 0);
    splitT(X, R, LEN_E, 736);
    k_mg<64,0,0,4><<<dim3(2,64,4),256,0,stream>>>(
        U(R), U(D720S), nullptr, nullptr, X, nullptr, BB*DD, 128, 736, 0);
    red(X, 4, MN8, nullptr, bkf, MN8);
    splitP(T, R, MD, DD);
    splitP(cWq, SB, DD, DD);
    k_mg<128,1,0,1><<<dim3(4,135,1),256,0,stream>>>(
        U(R), U(SB), cbq, nullptr, X, nullptr, MD, DD, DD, 0);
    splitT(X, R, LEN_D, 1088);
    k_mg<64,0,0,4><<<dim3(2,64,4),256,0,stream>>>(
        U(R), U(D1080S), nullptr, nullptr, X, nullptr, BB*DD, 128, 1088, 0);
    red(X, 4, MN8, nullptr, bqf, MN8);
    float* ba = R;
    float* bv = R + SL;
    float* bselp = R + 2*SL;
    k_cross_qk<<<BB*HHN,256,0,stream>>>(bqf, bkf, ba);
    k_cross_v<<<BB*HHN,256,0,stream>>>(ba, bkf, bv);
    k_modemix<<<dim3(64,8),256,0,stream>>>(bv, cfr, cfi, U(bselp), 1.0f/262144.0f);
    k_mg<128,0,2,1><<<dim3(9,64,1),256,0,stream>>>(        // irfft -> pair @X
        U(bselp), U(I1080S), nullptr, nullptr, nullptr, U(X), BB*DD, LEN_D, 128, LEN_D);
    splitP(cWo, SB, DD, DD);
    k_mg<128,3,0,1><<<dim3(4,135,1),256,0,stream>>>(
        U(X), U(SB), cbo, T, T, nullptr, MD, DD, DD, 0);
  }

  decomp(T, X, LEN_D, 1);             // x -> X, t2 acc
  ffn(X, T, dW1, dW2, MD, bencout);   // T = x + FFN(x)
  decomp(T, X, LEN_D, 1);             // x -> X, t3 acc

  myln_pair(X, T, R, g_dec, b_dec, LEN_D);   // pair @R (MD,512)
  splitP(Wp, SB, NV, DD);
  k_mg<64,1,0,1><<<dim3(6,135,1),256,0,stream>>>(
      U(R), U(SB), bp, nullptr, bseasF, nullptr, MD, NV, DD, 0);

  for (int r0 = 0; r0 < MD; r0 += 5760) {
    splitC(bTsum, R, r0, 5760, LEN_D, DD, 1536, 1536);
    k_mg<64,0,0,2><<<dim3(6,45,2),256,0,stream>>>(
        U(R), U(WtrcS), nullptr, nullptr, bX, nullptr, 5760, NV, 1536, 0);
    red(bX, 2, (size_t)5760*NV, btrend + (size_t)r0*NV, btrend + (size_t)r0*NV,
        (size_t)5760*NV);
  }

  k_final<<<(BB*LEN_E*NV + 255)/256,256,0,stream>>>(btrend, bseasF, (float*)d_out);
}

// Round 11
// 2620.009 us; speedup vs baseline: 5.4365x; 1.0265x over previous
//
#include <hip/hip_runtime.h>
#include <math.h>

#define BB 16
#define DD 512
#define HHN 8
#define LEN_E 720
#define LEN_D 1080
#define NV 321
#define DFF2 2048

typedef __attribute__((ext_vector_type(8))) short short8;
typedef __attribute__((ext_vector_type(4))) float floatx4;
typedef unsigned short u16;

__device__ __forceinline__ u16 f2bf(float v) {
  unsigned u = __builtin_bit_cast(unsigned, v);
  u += 0x7FFFu + ((u >> 16) & 1u);
  return (u16)(u >> 16);
}
__device__ __forceinline__ float bf2f(u16 h) {
  unsigned u = ((unsigned)h) << 16;
  return __builtin_bit_cast(float, u);
}

// element offset (u16) of (r,k) in tiled pair buffer; lo at +4096.
// tile = 128 rows x 32 cols, 8192 u16 (hi 4096 + lo 4096), XOR-swizzled slots.
__device__ __forceinline__ size_t toff(int r, int k, int ktn) {
  int rt = r >> 7, rr = r & 127;
  int kt = k >> 5, kk = k & 31;
  int sw = (kk >> 3) ^ (rr & 3) ^ ((rr >> 2) & 3);
  return (((size_t)(rt * ktn + kt)) << 13) + (rr << 5) + (sw << 3) + (kk & 7);
}

__device__ __forceinline__ void gload_lds(const void* g, void* l) {
  __builtin_amdgcn_global_load_lds(
      (const __attribute__((address_space(1))) unsigned int*)g,
      (__attribute__((address_space(3))) unsigned int*)l, 16, 0, 0);
}

// ---------------- prep kernels ----------------
__global__ void k_extract_x(const float* __restrict__ hist, float* __restrict__ xe) {
  int idx = blockIdx.x * 256 + threadIdx.x;
  if (idx >= BB*LEN_E*NV) return;
  xe[idx] = hist[(size_t)idx * 5];
}

__global__ void k_marks_enc(const float* __restrict__ hist, float* __restrict__ xme) {
  int idx = blockIdx.x * 256 + threadIdx.x;
  if (idx >= BB*LEN_E*4) return;
  int f = idx & 3;
  int r = idx >> 2;
  xme[idx] = hist[((size_t)r * NV) * 5 + 1 + f];
}

__global__ void k_marks_dec(const float* __restrict__ fut, const float* __restrict__ xme,
                            float* __restrict__ xmd) {
  int idx = blockIdx.x * 256 + threadIdx.x;
  if (idx >= BB*LEN_D*4) return;
  int f = idx & 3;
  int r = idx >> 2;
  int t = r % LEN_D, b = r / LEN_D;
  float v;
  if (t < 360) v = xme[((b*LEN_E) + 360 + t)*4 + f];
  else v = fut[(((size_t)(b*LEN_E + (t-360))) * NV) * 5 + 1 + f];
  xmd[idx] = v;
}

__global__ void k_ms_part(const float* __restrict__ xe, float* __restrict__ part,
                          int chl, int nch) {
  int n = threadIdx.x;
  if (n >= NV) return;
  int b = blockIdx.x, c = blockIdx.y;
  int l0 = c*chl, l1 = l0 + chl; if (l1 > LEN_E) l1 = LEN_E;
  float s = 0.f;
  for (int l = l0; l < l1; ++l) s += xe[((size_t)b*LEN_E + l)*NV + n];
  part[((size_t)b*nch + c)*NV + n] = s;
}
__global__ void k_ms_fin(const float* __restrict__ part, float* __restrict__ mb, int nch) {
  int i = blockIdx.x*256 + threadIdx.x;
  if (i >= BB*NV) return;
  int b = i / NV, n = i % NV;
  float s = 0.f;
  for (int c = 0; c < nch; ++c) s += part[((size_t)b*nch + c)*NV + n];
  mb[i] = s * (1.f/(float)LEN_E);
}

__global__ void k_init_decomp(const float* __restrict__ xe, const float* __restrict__ mb,
                              float* __restrict__ seas, float* __restrict__ trend) {
  int idx = blockIdx.x * 256 + threadIdx.x;
  if (idx >= BB*LEN_D*NV) return;
  int n = idx % NV; int r = idx / NV; int t = r % LEN_D; int b = r / LEN_D;
  if (t < 360) {
    int l = 360 + t;
    float s = 0.f;
    for (int j = -12; j <= 12; ++j) {
      int lc = l + j; if (lc > LEN_E-1) lc = LEN_E-1; if (lc < 0) lc = 0;
      s += xe[((size_t)b*LEN_E + lc)*NV + n];
    }
    float ma = s * (1.f/25.f);
    trend[idx] = ma;
    seas[idx]  = xe[((size_t)b*LEN_E + l)*NV + n] - ma;
  } else {
    trend[idx] = mb[b*NV + n];
    seas[idx]  = 0.f;
  }
}

__global__ void k_marks_add(float* __restrict__ X, const float* __restrict__ xm,
                            const float* __restrict__ Wt, int M) {
  int idx = blockIdx.x*256 + threadIdx.x;
  if (idx >= M*DD) return;
  int d = idx & 511, r = idx >> 9;
  const float* m4 = xm + (size_t)r*4;
  const float* w4 = Wt + (size_t)d*4;
  X[idx] += m4[0]*w4[0] + m4[1]*w4[1] + m4[2]*w4[2] + m4[3]*w4[3];
}

// ---------------- split builders (tiled pair output) ----------------
__global__ void k_split_plain(const float* __restrict__ src, u16* __restrict__ dst,
                              int K, int Kp) {
  int col = blockIdx.x*256 + threadIdx.x;
  if (col >= Kp) return;
  int r = blockIdx.y;
  float v = (col < K) ? src[(size_t)r*K + col] : 0.f;
  u16 hh = f2bf(v);
  size_t o = toff(r, col, Kp >> 5);
  dst[o] = hh; dst[o + 4096] = f2bf(v - bf2f(hh));
}

__global__ void k_split_conv(const float* __restrict__ src, u16* __restrict__ dst,
                             int r0, int Lc, int Din, int K, int Kp) {
  int col = blockIdx.x*256 + threadIdx.x;
  if (col >= Kp) return;
  int rr = blockIdx.y;
  int r = r0 + rr;
  int b = r / Lc, t = r - b*Lc;
  float v = 0.f;
  if (col < K) {
    int c = (col >= 2*Din) ? 2 : ((col >= Din) ? 1 : 0);
    int n = col - c*Din;
    int tt = t + c - 1;
    if (tt < 0) tt = Lc - 1; else if (tt >= Lc) tt = 0;
    v = src[((size_t)(b*Lc + tt))*Din + n];
  }
  u16 hh = f2bf(v);
  size_t o = toff(rr, col, Kp >> 5);
  dst[o] = hh; dst[o + 4096] = f2bf(v - bf2f(hh));
}

__global__ void k_split_tr(const float* __restrict__ src, u16* __restrict__ dst,
                           int Lc, int Kp) {
  __shared__ float t[32][33];
  int b = blockIdx.z;
  int l0 = blockIdx.x*32, c0 = blockIdx.y*32;
  int lx = threadIdx.x, ly = threadIdx.y;   // (32,8)
  #pragma unroll
  for (int i = 0; i < 4; ++i) {
    int ll = l0 + ly + i*8;
    t[ly + i*8][lx] = (ll < Lc) ? src[((size_t)b*Lc + ll)*DD + c0 + lx] : 0.f;
  }
  __syncthreads();
  int ktn = Kp >> 5;
  #pragma unroll
  for (int i = 0; i < 4; ++i) {
    int ch = c0 + ly + i*8;
    int ll = l0 + lx;
    float v = t[lx][ly + i*8];
    u16 hh = f2bf(v);
    size_t o = toff(b*DD + ch, ll, ktn);
    dst[o] = hh; dst[o + 4096] = f2bf(v - bf2f(hh));
  }
}

__global__ void k_build_wconvS(const float* __restrict__ Wv, u16* __restrict__ dst) {
  int col = blockIdx.x*256 + threadIdx.x;
  if (col >= 992) return;
  int d = blockIdx.y;
  float v = 0.f;
  if (col < 963) {
    int c = (col >= 642) ? 2 : ((col >= 321) ? 1 : 0);
    int n = col - c*321;
    v = Wv[(size_t)d*963 + n*3 + c];
  }
  u16 hh = f2bf(v);
  size_t o = toff(d, col, 31);
  dst[o] = hh; dst[o + 4096] = f2bf(v - bf2f(hh));
}

__global__ void k_build_wtrcS(const float* __restrict__ Wtr, u16* __restrict__ dst) {
  int col = blockIdx.x*256 + threadIdx.x;
  if (col >= 1536) return;
  int n = blockIdx.y;
  int c = col >> 9, d = col & 511;
  float v = Wtr[(size_t)n*1536 + d*3 + c];
  u16 hh = f2bf(v);
  size_t o = toff(n, col, 48);
  dst[o] = hh; dst[o + 4096] = f2bf(v - bf2f(hh));
}

__global__ void k_build_dftS(u16* __restrict__ dst, int L, int Kp) {
  int col = blockIdx.x*256 + threadIdx.x;
  if (col >= Kp) return;
  int mr = blockIdx.y;
  float v = 0.f;
  if (col < L) {
    int m = mr & 63;
    int ph = (m * col) % L;
    float th = 6.2831853071795864f * ((float)ph / (float)L);
    v = (mr < 64) ? cosf(th) : -sinf(th);
  }
  u16 hh = f2bf(v);
  size_t o = toff(mr, col, Kp >> 5);
  dst[o] = hh; dst[o + 4096] = f2bf(v - bf2f(hh));
}

__global__ void k_build_irS(u16* __restrict__ dst, int L) {
  int k = threadIdx.x;   // 0..127
  int ll = blockIdx.y;
  int m = k & 63;
  int ph = (m * ll) % L;
  float th = 6.2831853071795864f * ((float)ph / (float)L);
  float v;
  if (k < 64) v = (m == 0) ? (1.f/(float)L) : (2.f/(float)L) * cosf(th);
  else        v = (m == 0) ? 0.f            : -(2.f/(float)L) * sinf(th);
  u16 hh = f2bf(v);
  size_t o = toff(ll, k, 4);
  dst[o] = hh; dst[o + 4096] = f2bf(v - bf2f(hh));
}

// ---------------- MFMA GEMM: global_load_lds staging of pre-tiled operands ----
template<int TN, int EPI, int WOUT, int KS>
__global__ __launch_bounds__(256)
void k_mg(const u16* __restrict__ A, const u16* __restrict__ B,
          const float* __restrict__ bias, const float* __restrict__ res,
          float* __restrict__ C, u16* __restrict__ Cout,
          int M, int Nc, int K, int Lout)
{
  __shared__ __attribute__((aligned(16))) u16 sA[8192];
  __shared__ __attribute__((aligned(16))) u16 sB[(TN == 128) ? 8192 : 4096];

  const int tid  = threadIdx.x;
  const int lane = tid & 63;
  const int wave = tid >> 6;
  const int lr   = lane & 15;
  const int kg   = lane >> 4;

  const int gx  = gridDim.x;
  const int nwg = gx * gridDim.y;
  const int lid = blockIdx.y * gx + blockIdx.x;
  const int q8  = nwg >> 3, r8 = nwg & 7;
  const int xcd = lid & 7, i8 = lid >> 3;
  const int swz = (xcd < r8 ? xcd*(q8+1) : r8*(q8+1) + (xcd - r8)*q8) + i8;
  const int row0 = (swz / gx) * 128;
  const int col0 = (swz % gx) * TN;

  constexpr int MF = (TN == 128) ? 4 : 2;
  const int wr = (TN == 128) ? (wave >> 1) : wave;
  const int wc = (TN == 128) ? (wave & 1) : 0;

  const int ksteps = K >> 5;
  const int zz = (KS > 1) ? (int)blockIdx.z : 0;
  const int t0 = (KS > 1) ? (int)(((long long)ksteps * zz) / KS) : 0;
  const int t1 = (KS > 1) ? (int)(((long long)ksteps * (zz+1)) / KS) : ksteps;

  const char* gA = (const char*)(A + (((size_t)(row0 >> 7) * ksteps) << 13));
  const char* gB = (const char*)(B + (((size_t)(col0 >> 7) * ksteps) << 13));
  const int bhalf = (TN == 64) ? ((col0 & 64) << 6) : 0;   // 0 or 4096 bytes

  char* lA = (char*)sA;
  char* lB = (char*)sB;
  const int wl = (wave << 10) + (lane << 4);
  const int wb = (wave << 10);

  floatx4 acc[MF][4] = {};

  for (int kt = t0; kt < t1; ++kt) {
    {
      const char* ta = gA + ((size_t)kt << 14);
      #pragma unroll
      for (int c = 0; c < 4; ++c)
        gload_lds(ta + (c << 12) + wl, lA + (c << 12) + wb);
    }
    if (TN == 128) {
      const char* tb = gB + ((size_t)kt << 14);
      #pragma unroll
      for (int c = 0; c < 4; ++c)
        gload_lds(tb + (c << 12) + wl, lB + (c << 12) + wb);
    } else {
      const char* tb = gB + ((size_t)kt << 14) + bhalf;
      gload_lds(tb + wl, lB + wb);
      gload_lds(tb + 8192 + wl, lB + 4096 + wb);
    }
    __syncthreads();

    short8 ahf[MF], alf[MF], bhf[4], blf[4];
    #pragma unroll
    for (int f = 0; f < MF; ++f) {
      int row = wr*(MF*16) + f*16 + lr;
      int sw = kg ^ (row & 3) ^ ((row >> 2) & 3);
      int off = (row << 5) + (sw << 3);
      ahf[f] = *(const short8*)&sA[off];
      alf[f] = *(const short8*)&sA[4096 + off];
    }
    #pragma unroll
    for (int n = 0; n < 4; ++n) {
      int row = wc*64 + n*16 + lr;
      int sw = kg ^ (row & 3) ^ ((row >> 2) & 3);
      int off = (row << 5) + (sw << 3);
      bhf[n] = *(const short8*)&sB[off];
      blf[n] = *(const short8*)&sB[((TN == 128) ? 4096 : 2048) + off];
    }
    #pragma unroll
    for (int mf = 0; mf < MF; ++mf)
      #pragma unroll
      for (int nf = 0; nf < 4; ++nf) {
        acc[mf][nf] = __builtin_amdgcn_mfma_f32_16x16x32_bf16(ahf[mf], bhf[nf], acc[mf][nf], 0, 0, 0);
        acc[mf][nf] = __builtin_amdgcn_mfma_f32_16x16x32_bf16(ahf[mf], blf[nf], acc[mf][nf], 0, 0, 0);
        acc[mf][nf] = __builtin_amdgcn_mfma_f32_16x16x32_bf16(alf[mf], bhf[nf], acc[mf][nf], 0, 0, 0);
      }
    __syncthreads();
  }

  if (KS > 1) {
    float* Cp = C + (size_t)zz * ((size_t)M * Nc);
    #pragma unroll
    for (int nf = 0; nf < 4; ++nf) {
      int cN = col0 + wc*64 + nf*16 + lr;
      if (cN >= Nc) continue;
      #pragma unroll
      for (int mf = 0; mf < MF; ++mf)
        #pragma unroll
        for (int i = 0; i < 4; ++i) {
          int rM = row0 + wr*(MF*16) + mf*16 + kg*4 + i;
          if (rM >= M) continue;
          Cp[(size_t)rM * Nc + cN] = acc[mf][nf][i];
        }
    }
  } else {
    #pragma unroll
    for (int nf = 0; nf < 4; ++nf) {
      int cN = col0 + wc*64 + nf*16 + lr;
      if (cN >= Nc) continue;
      #pragma unroll
      for (int mf = 0; mf < MF; ++mf) {
        #pragma unroll
        for (int i = 0; i < 4; ++i) {
          int rM = row0 + wr*(MF*16) + mf*16 + kg*4 + i;
          if (rM >= M) continue;
          float v = acc[mf][nf][i];
          if (EPI & 1) v += bias[cN];
          if (EPI & 4) v = 0.5f * v * (1.f + erff(v * 0.7071067811865476f));
          if (EPI & 2) v += res[(size_t)rM * Nc + cN];
          if (WOUT == 1) {
            u16 hh = f2bf(v);
            size_t o = toff(rM, cN, Nc >> 5);
            Cout[o] = hh; Cout[o + 4096] = f2bf(v - bf2f(hh));
          } else if (WOUT == 2) {
            int b = rM >> 9, ch = rM & 511;
            int fl = ch * Lout + cN;
            int r2 = b * Lout + (fl >> 9);
            int c2 = fl & 511;
            u16 hh = f2bf(v);
            size_t o = toff(r2, c2, 16);
            Cout[o] = hh; Cout[o + 4096] = f2bf(v - bf2f(hh));
          } else {
            C[(size_t)rM * Nc + cN] = v;
          }
        }
      }
    }
  }
}

// ---------------- split-K reduce (fixed order, deterministic) ----------------
__global__ void k_red(const float* __restrict__ p, int parts, size_t stride,
                      const float* __restrict__ res, float* __restrict__ out, size_t n) {
  size_t i = (size_t)blockIdx.x*256 + threadIdx.x;
  if (i >= n) return;
  float s = res ? res[i] : 0.f;
  for (int z = 0; z < parts; ++z) s += p[(size_t)z*stride + i];
  out[i] = s;
}

// ---------------- mode mix: m-coalesced, emits tiled bf16 pair ----------------
// block: (o4 = blockIdx.x 0..15 -> o = o4*4 + (tid>>6), h = blockIdx.y, bhalf = blockIdx.z)
// thread: m = tid & 63. All fr/fi/ftbuf reads are 64-lane contiguous runs.
__global__ __launch_bounds__(256)
void k_modemix(const float* __restrict__ ftbuf, const float* __restrict__ fr,
               const float* __restrict__ fi, u16* __restrict__ sel, float scale)
{
  int tid = threadIdx.x;
  int m = tid & 63, ol = tid >> 6;
  int h = blockIdx.y, o = blockIdx.x*4 + ol;
  int b0 = blockIdx.z * 8;
  float accr[8] = {}, acci[8] = {};
  const float* fb = ftbuf + (((size_t)b0*DD + h*64)*128) + m;   // + b*65536 + e*128; im +64
  size_t wof = ((((size_t)h*64)*64 + o) << 6) + m;              // + e*4096
  for (int e = 0; e < 64; ++e) {
    float wr = fr[wof];
    float wi = fi[wof];
    const float* fe = fb + e*128;
    #pragma unroll
    for (int b = 0; b < 8; ++b) {
      float xr = fe[(size_t)b*65536];
      float xi = fe[(size_t)b*65536 + 64];
      accr[b] += xr*wr - xi*wi;
      acci[b] += xr*wi + xi*wr;
    }
    wof += 4096;
  }
  #pragma unroll
  for (int b = 0; b < 8; ++b) {
    int row = (b0 + b)*DD + h*64 + o;
    float vr = accr[b]*scale, vi2 = acci[b]*scale;
    u16 hr = f2bf(vr);
    size_t o1 = toff(row, m, 4);
    sel[o1] = hr; sel[o1 + 4096] = f2bf(vr - bf2f(hr));
    u16 hi2 = f2bf(vi2);
    size_t o2 = toff(row, m + 64, 4);
    sel[o2] = hi2; sel[o2 + 4096] = f2bf(vi2 - bf2f(hi2));
  }
}

// ---------------- cross attention ----------------
__global__ __launch_bounds__(256)
void k_cross_qk(const float* __restrict__ qf, const float* __restrict__ kf,
                float* __restrict__ ab)
{
  int bh = blockIdx.x; int b = bh >> 3, h = bh & 7;
  __shared__ float qr[32][64], qi[32][64], kr[32][64], ki[32][64];
  int tid = threadIdx.x;
  int tx = tid & 15, ty = tid >> 4;
  float ar[4][4] = {}, ai[4][4] = {};
  for (int e0 = 0; e0 < 64; e0 += 32) {
    for (int it = 0; it < 8; ++it) {
      int idx = tid + it*256;
      int e = idx >> 6, x = idx & 63;
      size_t rof = ((size_t)b*DD + h*64 + e0 + e)*128;
      qr[e][x] = qf[rof + x]; qi[e][x] = qf[rof + 64 + x];
      kr[e][x] = kf[rof + x]; ki[e][x] = kf[rof + 64 + x];
    }
    __syncthreads();
    for (int e = 0; e < 32; ++e) {
      float xr[4], xi2[4], yr[4], yi[4];
      #pragma unroll
      for (int i = 0; i < 4; ++i) { xr[i] = qr[e][ty*4+i]; xi2[i] = qi[e][ty*4+i]; }
      #pragma unroll
      for (int j = 0; j < 4; ++j) { yr[j] = kr[e][tx*4+j]; yi[j] = ki[e][tx*4+j]; }
      #pragma unroll
      for (int i = 0; i < 4; ++i)
        #pragma unroll
        for (int j = 0; j < 4; ++j) {
          ar[i][j] += xr[i]*yr[j] - xi2[i]*yi[j];
          ai[i][j] += xr[i]*yi[j] + xi2[i]*yr[j];
        }
    }
    __syncthreads();
  }
  #pragma unroll
  for (int i = 0; i < 4; ++i)
    #pragma unroll
    for (int j = 0; j < 4; ++j) {
      float txv = tanhf(ar[i][j]);
      float tyv = tanf(ai[i][j]);
      float den = 1.f + txv*txv*tyv*tyv;
      float re = txv*(1.f + tyv*tyv) / den;
      float im = tyv*(1.f - txv*txv) / den;
      size_t of = ((size_t)bh*64 + (ty*4+i))*128 + tx*4 + j;
      ab[of] = re; ab[of + 64] = im;
    }
}

__global__ __launch_bounds__(256)
void k_cross_v(const float* __restrict__ ab, const float* __restrict__ kf,
               float* __restrict__ v)
{
  int bh = blockIdx.x; int b = bh >> 3, h = bh & 7;
  __shared__ float ar[64][32], ai[64][32], kr[64][32], ki[64][32];
  int tid = threadIdx.x;
  int tx = tid & 15, ty = tid >> 4;
  float vr[4][4] = {}, vi[4][4] = {};
  for (int y0 = 0; y0 < 64; y0 += 32) {
    for (int it = 0; it < 8; ++it) {
      int idx = tid + it*256;
      int r = idx >> 5, y = idx & 31;
      ar[r][y] = ab[((size_t)bh*64 + r)*128 + y0 + y];
      ai[r][y] = ab[((size_t)bh*64 + r)*128 + 64 + y0 + y];
      kr[r][y] = kf[((size_t)b*DD + h*64 + r)*128 + y0 + y];
      ki[r][y] = kf[((size_t)b*DD + h*64 + r)*128 + 64 + y0 + y];
    }
    __syncthreads();
    for (int y = 0; y < 32; ++y) {
      float er[4], ei[4], xr[4], xi2[4];
      #pragma unroll
      for (int i = 0; i < 4; ++i) { er[i] = kr[ty*4+i][y]; ei[i] = ki[ty*4+i][y]; }
      #pragma unroll
      for (int j = 0; j < 4; ++j) { xr[j] = ar[tx*4+j][y]; xi2[j] = ai[tx*4+j][y]; }
      #pragma unroll
      for (int i = 0; i < 4; ++i)
        #pragma unroll
        for (int j = 0; j < 4; ++j) {
          vr[i][j] += xr[j]*er[i] - xi2[j]*ei[i];
          vi[i][j] += xr[j]*ei[i] + xi2[j]*er[i];
        }
    }
    __syncthreads();
  }
  #pragma unroll
  for (int i = 0; i < 4; ++i)
    #pragma unroll
    for (int j = 0; j < 4; ++j) {
      size_t of = ((size_t)b*DD + h*64 + ty*4 + i)*128 + tx*4 + j;
      v[of] = vr[i][j]; v[of + 64] = vi[i][j];
    }
}

// ---------------- LN + column-mean subtract ----------------
__global__ __launch_bounds__(256)
void k_ln(const float* __restrict__ x, const float* __restrict__ g,
          const float* __restrict__ be, float* __restrict__ out)
{
  int r = blockIdx.x; int tid = threadIdx.x;
  float v1 = x[(size_t)r*DD + tid], v2 = x[(size_t)r*DD + 256 + tid];
  float s = v1 + v2, s2 = v1*v1 + v2*v2;
  #pragma unroll
  for (int off = 32; off; off >>= 1) { s += __shfl_down(s, off, 64); s2 += __shfl_down(s2, off, 64); }
  __shared__ float red[8];
  int wid = tid >> 6, lane = tid & 63;
  if (lane == 0) { red[wid] = s; red[4 + wid] = s2; }
  __syncthreads();
  if (tid == 0) {
    float a = red[0]+red[1]+red[2]+red[3];
    float b2 = red[4]+red[5]+red[6]+red[7];
    float mu = a / 512.f;
    float var = b2 / 512.f - mu*mu;
    red[0] = mu; red[1] = rsqrtf(var + 1e-5f);
  }
  __syncthreads();
  float mu = red[0], inv = red[1];
  out[(size_t)r*DD + tid]       = (v1 - mu)*inv*g[tid]       + be[tid];
  out[(size_t)r*DD + 256 + tid] = (v2 - mu)*inv*g[256 + tid] + be[256 + tid];
}

__global__ void k_colsum_part(const float* __restrict__ x, float* __restrict__ part,
                              int L, int chl, int nch) {
  int d = threadIdx.x;
  int b = blockIdx.x, c = blockIdx.y;
  int l0 = c*chl, l1 = l0 + chl; if (l1 > L) l1 = L;
  float s = 0.f;
  for (int l = l0; l < l1; ++l) s += x[(((size_t)b*L + l) << 9) + d];
  part[((size_t)(b*nch + c) << 9) + d] = s;
}
__global__ void k_colsum_fin(const float* __restrict__ part, float* __restrict__ cm,
                             int nch, float inv) {
  int i = blockIdx.x*256 + threadIdx.x;
  int b = i >> 9, d = i & 511;
  float s = 0.f;
  for (int c = 0; c < nch; ++c) s += part[((size_t)(b*nch + c) << 9) + d];
  cm[i] = s * inv;
}
__global__ void k_csub_pair(const float* __restrict__ x, const float* __restrict__ cm,
                            u16* __restrict__ dst, int L) {
  size_t idx = (size_t)blockIdx.x*256 + threadIdx.x;
  if (idx >= (size_t)BB*L*DD) return;
  int d = (int)(idx & 511);
  int r = (int)(idx >> 9);
  int b = r / L;
  float v = x[idx] - cm[(b << 9) | d];
  u16 hh = f2bf(v);
  size_t o = toff(r, d, 16);
  dst[o] = hh; dst[o + 4096] = f2bf(v - bf2f(hh));
}

// ---------------- series decomp: sliding-window running sum ----------------
template<int ACC>
__global__ __launch_bounds__(512)
void k_decomp(const float* __restrict__ x, float* __restrict__ out,
              float* __restrict__ tsum, int L, int chl)
{
  int d = threadIdx.x;            // 512
  int b = blockIdx.x;
  int l0 = blockIdx.y * chl;
  int l1 = l0 + chl; if (l1 > L) l1 = L;
  const float* xb = x + (((size_t)b*L) << 9) + d;
  float s = 0.f;
  #pragma unroll
  for (int j = -12; j <= 12; ++j) {
    int lc = l0 + j; lc = lc < 0 ? 0 : (lc >= L ? L-1 : lc);
    s += xb[(size_t)lc << 9];
  }
  for (int l = l0; l < l1; ++l) {
    size_t o = (((size_t)(b*L + l)) << 9) + d;
    float ma = s * (1.f/25.f);
    out[o] = xb[(size_t)l << 9] - ma;
    if (ACC == 1) tsum[o] += ma;
    if (ACC == 2) tsum[o] = ma;
    int la = l + 13; if (la >= L) la = L - 1;
    int lr = l - 12; if (lr < 0) lr = 0;
    s += xb[(size_t)la << 9] - xb[(size_t)lr << 9];
  }
}

// ---------------- final ----------------
__global__ void k_final(const float* __restrict__ trend, const float* __restrict__ seas,
                        float* __restrict__ out) {
  int idx = blockIdx.x*256 + threadIdx.x;
  if (idx >= BB*LEN_E*NV) return;
  int n = idx % NV; int r = idx / NV; int t = r % LEN_E; int b = r / LEN_E;
  size_t src = ((size_t)b*LEN_D + 360 + t)*NV + n;
  out[idx] = trend[src] + seas[src];
}

// =====================================================================
extern "C" void kernel_launch(void* const* d_in, const int* in_sizes, int n_in,
                              void* d_out, int out_size, void* d_ws, size_t ws_size,
                              hipStream_t stream)
{
  (void)in_sizes; (void)n_in; (void)out_size; (void)ws_size;
  const float* history = (const float*)d_in[0];
  const float* future  = (const float*)d_in[1];
  const float* Wv_enc  = (const float*)d_in[2];
  const float* Wt_enc  = (const float*)d_in[3];
  const float* Wv_dec  = (const float*)d_in[4];
  const float* Wt_dec  = (const float*)d_in[5];
  const float* eWq = (const float*)d_in[6];
  const float* ebq = (const float*)d_in[7];
  const float* efr = (const float*)d_in[8];
  const float* efi = (const float*)d_in[9];
  const float* eWo = (const float*)d_in[10];
  const float* ebo = (const float*)d_in[11];
  const float* eW1 = (const float*)d_in[12];
  const float* eW2 = (const float*)d_in[13];
  const float* g_enc = (const float*)d_in[14];
  const float* b_enc = (const float*)d_in[15];
  const float* dWq = (const float*)d_in[16];
  const float* dbq = (const float*)d_in[17];
  const float* dfr = (const float*)d_in[18];
  const float* dfi = (const float*)d_in[19];
  const float* dWo = (const float*)d_in[20];
  const float* dbo = (const float*)d_in[21];
  const float* cWq = (const float*)d_in[22];
  const float* cbq = (const float*)d_in[23];
  const float* cWk = (const float*)d_in[24];
  const float* cbk = (const float*)d_in[25];
  const float* cfr = (const float*)d_in[26];
  const float* cfi = (const float*)d_in[27];
  const float* cWo = (const float*)d_in[28];
  const float* cbo = (const float*)d_in[29];
  const float* dW1 = (const float*)d_in[30];
  const float* dW2 = (const float*)d_in[31];
  const float* Wtr = (const float*)d_in[32];
  const float* g_dec = (const float*)d_in[33];
  const float* b_dec = (const float*)d_in[34];
  const float* Wp  = (const float*)d_in[35];
  const float* bp  = (const float*)d_in[36];

  float* ws = (float*)d_ws;
  size_t off = 0;
  auto alloc = [&](size_t n) { float* p = ws + off; off += (n + 63) & ~(size_t)63; return p; };

  const size_t SL = 1048576;
  const int CH = 4320;

  float* btrend = alloc((size_t)BB*LEN_D*NV);
  float* bTsum  = alloc((size_t)BB*LEN_D*DD);
  float* bX     = alloc((size_t)BB*LEN_D*DD);
  float* bT     = alloc((size_t)BB*LEN_D*DD);
  float* bencout= alloc((size_t)BB*LEN_E*DD);
  float* bseas  = alloc((size_t)BB*LEN_D*NV);
  float* bseasF = bseas;
  float* R      = alloc((size_t)11600000);
  float* SB     = alloc((size_t)2*SL + 128);
  float* WceS   = alloc((size_t)512*992);
  float* WcdS   = alloc((size_t)512*992);
  float* WtrcS  = alloc((size_t)384*1536);
  float* D720S  = alloc((size_t)128*736);
  float* D1080S = alloc((size_t)128*1088);
  float* I720S  = alloc((size_t)768*128);
  float* I1080S = alloc((size_t)1152*128);
  float* bxme   = alloc((size_t)BB*LEN_E*4);
  float* bxmd   = alloc((size_t)BB*LEN_D*4);
  float* bmean  = alloc((size_t)BB*NV);
  float* bpart  = alloc((size_t)BB*9*DD);
  float* bcm    = alloc((size_t)BB*DD);
  float* bmsp   = alloc((size_t)BB*10*NV);

  float* bxe = bT;   // prep alias (dead before T written)

  auto U = [](float* p) { return (u16*)p; };

  auto splitP = [&](const float* src, float* dst, int M, int K) {
    dim3 g((K + 255)/256, M);
    k_split_plain<<<g,256,0,stream>>>(src, U(dst), K, K);
  };
  auto splitC = [&](const float* src, float* dst, int r0, int Mc, int Lc, int Din,
                    int K, int Kp) {
    dim3 g((Kp + 255)/256, Mc);
    k_split_conv<<<g,256,0,stream>>>(src, U(dst), r0, Lc, Din, K, Kp);
  };
  auto splitT = [&](const float* src, float* dst, int Lc, int Kp) {
    dim3 g(Kp/32, 16, BB), b(32, 8);
    k_split_tr<<<g,b,0,stream>>>(src, U(dst), Lc, Kp);
  };
  auto red = [&](const float* p, int parts, size_t stride, const float* res,
                 float* out, size_t n) {
    k_red<<<(int)((n + 255)/256),256,0,stream>>>(p, parts, stride, res, out, n);
  };

  auto decomp = [&](const float* in, float* out, int L, int acc) {
    int chl = 45;
    int nch = (L + chl - 1) / chl;
    dim3 g(BB, nch);
    if (acc == 1)      k_decomp<1><<<g,512,0,stream>>>(in, out, bTsum, L, chl);
    else if (acc == 2) k_decomp<2><<<g,512,0,stream>>>(in, out, bTsum, L, chl);
    else               k_decomp<0><<<g,512,0,stream>>>(in, out, nullptr, L, chl);
  };

  // FFN: out = in + gelu(in@W1.T)@W2.T ; GEMM2 split-K=2, fp32 partials in scratch
  float* SA2 = R + 2230016;   // hidden tiled pair
  auto ffn = [&](const float* in, float* out, const float* W1, const float* W2,
                 int M, float* scratch) {
    splitP(W1, SB, DFF2, DD);
    splitP(W2, SB + SL, DD, DFF2);
    for (int r0 = 0; r0 < M; r0 += CH) {
      int mc = M - r0; if (mc > CH) mc = CH;
      splitP(in + (size_t)r0*DD, R, mc, DD);
      k_mg<128,4,1,1><<<dim3(16,(mc+127)/128,1),256,0,stream>>>(
          U(R), U(SB), nullptr, nullptr, nullptr, U(SA2), mc, DFF2, DD, 0);
      k_mg<64,0,0,2><<<dim3(8,(mc+127)/128,2),256,0,stream>>>(
          U(SA2), U(SB+SL), nullptr, nullptr, scratch, nullptr, mc, DD, DFF2, 0);
      red(scratch, 2, (size_t)mc*DD, in + (size_t)r0*DD, out + (size_t)r0*DD, (size_t)mc*DD);
    }
  };

  // X += fourier_self(X); T = fp32 temp + DFT partial scratch
  auto fourier_self = [&](float* X, float* T, int L, int KpL, float* DLS, float* ILS,
                          const float* Wq, const float* bq, const float* fr, const float* fi,
                          const float* Wo, const float* bo) {
    int M = BB * L;
    size_t MN8 = (size_t)8192*128;
    float* bqf   = R + 9*SL;
    float* bselp = R + 10*SL;
    splitP(X, R, M, DD);
    splitP(Wq, SB, DD, DD);
    k_mg<128,1,0,1><<<dim3(4,(M+127)/128,1),256,0,stream>>>(
        U(R), U(SB), bq, nullptr, T, nullptr, M, DD, DD, 0);
    splitT(T, R, L, KpL);
    k_mg<64,0,0,4><<<dim3(2,64,4),256,0,stream>>>(
        U(R), U(DLS), nullptr, nullptr, T, nullptr, BB*DD, 128, KpL, 0);
    red(T, 4, MN8, nullptr, bqf, MN8);
    k_modemix<<<dim3(16,8,2),256,0,stream>>>(bqf, fr, fi, U(bselp), 1.0f);
    k_mg<128,0,2,1><<<dim3((L+127)/128,64,1),256,0,stream>>>(   // irfft -> pair @R
        U(bselp), U(ILS), nullptr, nullptr, nullptr, U(R), BB*DD, L, 128, L);
    splitP(Wo, SB, DD, DD);
    k_mg<128,3,0,1><<<dim3(4,(M+127)/128,1),256,0,stream>>>(
        U(R), U(SB), bo, X, X, nullptr, M, DD, DD, 0);
  };

  auto myln_pair = [&](const float* in, float* tmp, float* pairdst,
                       const float* g, const float* b, int L) {
    k_ln<<<BB*L,256,0,stream>>>(in, g, b, tmp);
    int chl = L / 9;
    k_colsum_part<<<dim3(BB,9),512,0,stream>>>(tmp, bpart, L, chl, 9);
    k_colsum_fin<<<32,256,0,stream>>>(bpart, bcm, 9, 1.f/(float)L);
    size_t n = (size_t)BB*L*DD;
    k_csub_pair<<<(int)((n+255)/256),256,0,stream>>>(tmp, bcm, U(pairdst), L);
  };

  // ---------------- prep ----------------
  k_extract_x<<<(BB*LEN_E*NV + 255)/256,256,0,stream>>>(history, bxe);
  k_marks_enc<<<(BB*LEN_E*4 + 255)/256,256,0,stream>>>(history, bxme);
  k_marks_dec<<<(BB*LEN_D*4 + 255)/256,256,0,stream>>>(future, bxme, bxmd);
  k_ms_part<<<dim3(BB,10),384,0,stream>>>(bxe, bmsp, 72, 10);
  k_ms_fin<<<(BB*NV + 255)/256,256,0,stream>>>(bmsp, bmean, 10);
  k_init_decomp<<<(BB*LEN_D*NV + 255)/256,256,0,stream>>>(bxe, bmean, bseas, btrend);
  k_build_wconvS<<<dim3(4,512),256,0,stream>>>(Wv_enc, U(WceS));
  k_build_wconvS<<<dim3(4,512),256,0,stream>>>(Wv_dec, U(WcdS));
  k_build_wtrcS<<<dim3(6,321),256,0,stream>>>(Wtr, U(WtrcS));
  k_build_dftS<<<dim3(3,128),256,0,stream>>>(U(D720S), LEN_E, 736);
  k_build_dftS<<<dim3(5,128),256,0,stream>>>(U(D1080S), LEN_D, 1088);
  k_build_irS<<<dim3(1,LEN_E),128,0,stream>>>(U(I720S), LEN_E);
  k_build_irS<<<dim3(1,LEN_D),128,0,stream>>>(U(I1080S), LEN_D);

  // ---------------- encoder ----------------
  int ME = BB * LEN_E;
  for (int r0 = 0; r0 < ME; r0 += 5760) {
    splitC(bxe, R, r0, 5760, LEN_E, NV, 963, 992);
    k_mg<128,0,0,2><<<dim3(4,45,2),256,0,stream>>>(
        U(R), U(WceS), nullptr, nullptr, bencout, nullptr, 5760, DD, 992, 0);
    red(bencout, 2, (size_t)5760*DD, nullptr, bX + (size_t)r0*DD, (size_t)5760*DD);
  }
  k_marks_add<<<(ME*DD + 255)/256,256,0,stream>>>(bX, bxme, Wt_enc, ME);

  float *X = bX, *T = bT;
  for (int i = 0; i < 2; ++i) {
    fourier_self(X, T, LEN_E, 736, D720S, I720S,
                 eWq + (size_t)i*DD*DD, ebq + (size_t)i*DD,
                 efr + (size_t)i*HHN*64*64*64, efi + (size_t)i*HHN*64*64*64,
                 eWo + (size_t)i*DD*DD, ebo + (size_t)i*DD);
    decomp(X, T, LEN_E, 0);
    ffn(T, X, eW1 + (size_t)i*DFF2*DD, eW2 + (size_t)i*DD*DFF2, ME, bencout);
    decomp(X, T, LEN_E, 0);
    { float* tmp = X; X = T; T = tmp; }
  }
  myln_pair(X, T, bencout, g_enc, b_enc, LEN_E);   // bencout = tiled pair (ME,512)

  // ---------------- decoder ----------------
  int MD = BB * LEN_D;
  for (int r0 = 0; r0 < MD; r0 += 8640) {
    splitC(bseas, R, r0, 8640, LEN_D, NV, 963, 992);
    k_mg<128,0,0,2><<<dim3(4,68,2),256,0,stream>>>(
        U(R), U(WcdS), nullptr, nullptr, T, nullptr, 8640, DD, 992, 0);
    red(T, 2, (size_t)8640*DD, nullptr, X + (size_t)r0*DD, (size_t)8640*DD);
  }
  k_marks_add<<<(MD*DD + 255)/256,256,0,stream>>>(X, bxmd, Wt_dec, MD);

  fourier_self(X, T, LEN_D, 1088, D1080S, I1080S, dWq, dbq, dfr, dfi, dWo, dbo);

  decomp(X, T, LEN_D, 2);             // x -> T, tsum = t1 (first write)

  // cross attention
  {
    size_t MN8 = (size_t)8192*128;
    float* bkf = R + 9*SL;
    float* bqf = R + 10*SL;
    splitP(cWk, SB, DD, DD);
    k_mg<128,1,0,1><<<dim3(4,90,1),256,0,stream>>>(
        U(bencout), U(SB), cbk, nullptr, X, nullptr, ME, DD, DD, 0);
    splitT(X, R, LEN_E, 736);
    k_mg<64,0,0,4><<<dim3(2,64,4),256,0,stream>>>(
        U(R), U(D720S), nullptr, nullptr, X, nullptr, BB*DD, 128, 736, 0);
    red(X, 4, MN8, nullptr, bkf, MN8);
    splitP(T, R, MD, DD);
    splitP(cWq, SB, DD, DD);
    k_mg<128,1,0,1><<<dim3(4,135,1),256,0,stream>>>(
        U(R), U(SB), cbq, nullptr, X, nullptr, MD, DD, DD, 0);
    splitT(X, R, LEN_D, 1088);
    k_mg<64,0,0,4><<<dim3(2,64,4),256,0,stream>>>(
        U(R), U(D1080S), nullptr, nullptr, X, nullptr, BB*DD, 128, 1088, 0);
    red(X, 4, MN8, nullptr, bqf, MN8);
    float* ba = R;
    float* bv = R + SL;
    float* bselp = R + 2*SL;
    k_cross_qk<<<BB*HHN,256,0,stream>>>(bqf, bkf, ba);
    k_cross_v<<<BB*HHN,256,0,stream>>>(ba, bkf, bv);
    k_modemix<<<dim3(16,8,2),256,0,stream>>>(bv, cfr, cfi, U(bselp), 1.0f/262144.0f);
    k_mg<128,0,2,1><<<dim3(9,64,1),256,0,stream>>>(        // irfft -> pair @X
        U(bselp), U(I1080S), nullptr, nullptr, nullptr, U(X), BB*DD, LEN_D, 128, LEN_D);
    splitP(cWo, SB, DD, DD);
    k_mg<128,3,0,1><<<dim3(4,135,1),256,0,stream>>>(
        U(X), U(SB), cbo, T, T, nullptr, MD, DD, DD, 0);
  }

  decomp(T, X, LEN_D, 1);             // x -> X, t2 acc
  ffn(X, T, dW1, dW2, MD, bencout);   // T = x + FFN(x)
  decomp(T, X, LEN_D, 1);             // x -> X, t3 acc

  myln_pair(X, T, R, g_dec, b_dec, LEN_D);   // pair @R (MD,512)
  splitP(Wp, SB, NV, DD);
  k_mg<64,1,0,1><<<dim3(6,135,1),256,0,stream>>>(
      U(R), U(SB), bp, nullptr, bseasF, nullptr, MD, NV, DD, 0);

  for (int r0 = 0; r0 < MD; r0 += 5760) {
    splitC(bTsum, R, r0, 5760, LEN_D, DD, 1536, 1536);
    k_mg<64,0,0,2><<<dim3(6,45,2),256,0,stream>>>(
        U(R), U(WtrcS), nullptr, nullptr, bX, nullptr, 5760, NV, 1536, 0);
    red(bX, 2, (size_t)5760*NV, btrend + (size_t)r0*NV, btrend + (size_t)r0*NV,
        (size_t)5760*NV);
  }

  k_final<<<(BB*LEN_E*NV + 255)/256,256,0,stream>>>(btrend, bseasF, (float*)d_out);
}